// Round 6
// baseline (456.305 us; speedup 1.0000x reference)
//
#include <hip/hip_runtime.h>
#include <stdint.h>

#define S_LEN 2048
#define BATCH 4
#define HID   2048
#define HD    128
#define NKV   4
#define KVLD  1024          // combined K|V projection row stride (2*NKV*HD)
#define MTOT  (BATCH*S_LEN) // 8192
#define NQT   (S_LEN/128)   // 16 q-tiles (128 rows) per (b,h)
#define QSCALE 0.08838834764831845f

typedef float    f32x4  __attribute__((ext_vector_type(4)));
typedef __bf16   bf16x8 __attribute__((ext_vector_type(8)));
typedef __bf16   bf16x4 __attribute__((ext_vector_type(4)));
typedef unsigned u32x4  __attribute__((ext_vector_type(4)));

// async global->LDS, 16B per lane. LDS dest = wave-uniform base + lane*16.
__device__ __forceinline__ void gld16(const void* g, void* l) {
    __builtin_amdgcn_global_load_lds(
        (const __attribute__((address_space(1))) void*)g,
        (__attribute__((address_space(3))) void*)l, 16, 0, 0);
}

// pack two f32 -> u32 of 2 bf16 (element 0 in low half)
__device__ __forceinline__ unsigned pk2(float x, float y) {
    union { __bf16 h[2]; unsigned u; } t;
    t.h[0] = (__bf16)x; t.h[1] = (__bf16)y;
    return t.u;
}

// ---------------- fp32 -> bf16 bulk convert (8 elems/thread) ----------------
__global__ void k_conv_x(const float* __restrict__ in, __bf16* __restrict__ out) {
    int i = blockIdx.x * blockDim.x + threadIdx.x;
    f32x4 a = ((const f32x4*)in)[2 * i];
    f32x4 b = ((const f32x4*)in)[2 * i + 1];
    bf16x8 o;
    o[0] = (__bf16)a[0]; o[1] = (__bf16)a[1]; o[2] = (__bf16)a[2]; o[3] = (__bf16)a[3];
    o[4] = (__bf16)b[0]; o[5] = (__bf16)b[1]; o[6] = (__bf16)b[2]; o[7] = (__bf16)b[3];
    ((bf16x8*)out)[i] = o;
}

// ------------- W [K][N] fp32 -> Wt [N][K] bf16 (64x64 LDS tiles) ------------
__global__ void k_transpose_w(const float* __restrict__ in, __bf16* __restrict__ out,
                              int K, int N) {
    __shared__ float tile[64][65];
    int k0 = blockIdx.x * 64, n0 = blockIdx.y * 64;
    for (int e = threadIdx.x; e < 4096; e += 256) {
        int r = e >> 6, c = e & 63;
        tile[r][c] = in[(size_t)(k0 + r) * N + n0 + c];
    }
    __syncthreads();
    for (int e = threadIdx.x; e < 4096; e += 256) {
        int r = e >> 6, c = e & 63;
        out[(size_t)(n0 + r) * K + k0 + c] = (__bf16)tile[c][r];
    }
}

// -------- V slice of kvbuf [8192][1024] -> vt [16 planes][128 d][2048 s] ----
__global__ void k_transpose_v(const __bf16* __restrict__ kv, __bf16* __restrict__ vt) {
    __shared__ __bf16 tile[64][65];
    int plane = blockIdx.z;          // b*NKV + kvh
    int b = plane >> 2, kvh = plane & 3;
    int s0 = blockIdx.x * 64, d0 = blockIdx.y * 64;
    const __bf16* src = kv + (size_t)(b * S_LEN + s0) * KVLD + NKV * HD + kvh * HD + d0;
    for (int e = threadIdx.x; e < 4096; e += 256) {
        int r = e >> 6, c = e & 63;            // r: s offset, c: d offset
        tile[r][c] = src[(size_t)r * KVLD + c];
    }
    __syncthreads();
    __bf16* dst = vt + (size_t)plane * HD * S_LEN + (size_t)d0 * S_LEN + s0;
    for (int e = threadIdx.x; e < 4096; e += 256) {
        int r = e >> 6, c = e & 63;            // r: d offset, c: s offset
        dst[(size_t)r * S_LEN + c] = tile[c][r];
    }
}

// ------------- 3-ring deep-pipelined GEMM (T3/T4: counted vmcnt) ------------
// C[M][N] = A[M][K] * Bt[N][K]^T. BM=256, BN=128, BK=64, 8 waves (2Mx4N),
// wave tile 128x32. LDS ring of 3 K-tile buffers (144 KB, 1 block/CU).
// Invariant entering tile t: slot t%3 ready, slot (t+1)%3's 6 loads issued.
// Barrier = s_waitcnt vmcnt(6) + raw s_barrier -> t+2's loads stay in flight
// across the barrier (never drain to 0 in the main loop).
// QKV mode: N=3072 output routed to qbuf (rope+scale) / kv (rope for k).
template <bool QKV>
__global__ __launch_bounds__(512) void k_gemm3(const __bf16* __restrict__ A,
                                               const __bf16* __restrict__ Bt,
                                               float* __restrict__ outf,
                                               __bf16* __restrict__ qbuf,
                                               __bf16* __restrict__ kvbuf,
                                               const float* __restrict__ cosp,
                                               const float* __restrict__ sinp,
                                               int N, int K) {
    __shared__ __bf16 As[3][256 * 64];   // 96 KB
    __shared__ __bf16 Bs[3][128 * 64];   // 48 KB
    const int tid = threadIdx.x, lane = tid & 63, wave = tid >> 6;
    const int wm = wave >> 2, wn = wave & 3;
    const int m0 = blockIdx.x * 256, n0 = blockIdx.y * 128;
    const int lo = lane & 15, hi = lane >> 4;
    const int NKT = K >> 6;
    f32x4 acc[8][2] = {};

    const int srow8 = wave * 8 + (lane >> 3);  // staging row (+ r*64)
    const int sp    = lane & 7;                // physical 16B chunk

    auto STAGE = [&](int s, int t) {
        const int kt = t * 64;
#pragma unroll
        for (int r = 0; r < 4; r++) {          // A tile 256x64: 4 calls
            int row = r * 64 + srow8;
            int c = sp ^ (row & 7);            // inverse-swizzled source chunk
            gld16(A + (size_t)(m0 + row) * K + kt + c * 8,
                  &As[s][(r * 64 + wave * 8) * 64]);
        }
#pragma unroll
        for (int r = 0; r < 2; r++) {          // B tile 128x64: 2 calls
            int row = r * 64 + srow8;
            int c = sp ^ (row & 7);
            gld16(Bt + (size_t)(n0 + row) * K + kt + c * 8,
                  &Bs[s][(r * 64 + wave * 8) * 64]);
        }
    };

    STAGE(0, 0);
    STAGE(1, 1);
    asm volatile("s_waitcnt vmcnt(6)" ::: "memory");  // tile 0 landed
    __builtin_amdgcn_s_barrier();
    __builtin_amdgcn_sched_barrier(0);

#pragma unroll 1
    for (int t = 0; t < NKT; t++) {
        const int s = t % 3;
        if (t + 2 < NKT) STAGE((t + 2) % 3, t + 2);   // issue BEFORE compute

        const __bf16* as = &As[s][0];
        const __bf16* bs = &Bs[s][0];
        bf16x8 af[8][2], bf[2][2];
#pragma unroll
        for (int i = 0; i < 8; i++) {
            int row = wm * 128 + i * 16 + lo;
#pragma unroll
            for (int ks = 0; ks < 2; ks++) {
                int pp = (ks * 4 + hi) ^ (row & 7);
                af[i][ks] = *(const bf16x8*)&as[row * 64 + pp * 8];
            }
        }
#pragma unroll
        for (int j = 0; j < 2; j++) {
            int row = wn * 32 + j * 16 + lo;
#pragma unroll
            for (int ks = 0; ks < 2; ks++) {
                int pp = (ks * 4 + hi) ^ (row & 7);
                bf[j][ks] = *(const bf16x8*)&bs[row * 64 + pp * 8];
            }
        }
        __builtin_amdgcn_s_setprio(1);
#pragma unroll
        for (int ks = 0; ks < 2; ks++)
#pragma unroll
            for (int i = 0; i < 8; i++)
#pragma unroll
                for (int j = 0; j < 2; j++)
                    acc[i][j] = __builtin_amdgcn_mfma_f32_16x16x32_bf16(
                        af[i][ks], bf[j][ks], acc[i][j], 0, 0, 0);
        __builtin_amdgcn_s_setprio(0);

        if (t + 2 < NKT) {          // steady state: t+2's 6 loads stay in flight
            asm volatile("s_waitcnt vmcnt(6)" ::: "memory");
            __builtin_amdgcn_s_barrier();
            __builtin_amdgcn_sched_barrier(0);
        } else if (t + 1 < NKT) {   // epilogue drain for the last resident tile
            asm volatile("s_waitcnt vmcnt(0)" ::: "memory");
            __builtin_amdgcn_s_barrier();
            __builtin_amdgcn_sched_barrier(0);
        }
    }

    // ---------------- epilogue (registers only, no barrier needed) ----------
    if (QKV) {
        const float sgn = (lo & 1) ? 1.f : -1.f;
#pragma unroll
        for (int i = 0; i < 8; i++) {
#pragma unroll
            for (int j = 0; j < 2; j++) {
                int rowb = m0 + wm * 128 + i * 16 + hi * 4;
                int colb = n0 + wn * 32 + j * 16;
                int col = colb + lo;
                bool isQ = colb < 2048;
                bool doRope = colb < 2560;
                int d = col & (HD - 1);
#pragma unroll
                for (int r = 0; r < 4; r++) {
                    float a = acc[i][j][r];
                    float pv = __shfl_xor(a, 1, 64);
                    if (doRope) {
                        int ss = (rowb + r) & (S_LEN - 1);
                        float c = cosp[ss * HD + d], sn = sinp[ss * HD + d];
                        a = a * c + sgn * pv * sn;
                        if (isQ) a *= QSCALE;
                    }
                    if (isQ) qbuf[(size_t)(rowb + r) * HID + col] = (__bf16)a;
                    else     kvbuf[(size_t)(rowb + r) * KVLD + (col - 2048)] = (__bf16)a;
                }
            }
        }
    } else {
#pragma unroll
        for (int i = 0; i < 8; i++) {
#pragma unroll
            for (int j = 0; j < 2; j++) {
                int rowb = m0 + wm * 128 + i * 16 + hi * 4;
                int col = n0 + wn * 32 + j * 16 + lo;
#pragma unroll
                for (int r = 0; r < 4; r++)
                    outf[(size_t)(rowb + r) * N + col] = acc[i][j][r];
            }
        }
    }
}

// ----------------------------- flash attention ------------------------------
// grid (pair=8, head=16, batch=4); block = 512 threads = 8 waves x 16 q-rows.
// Swapped QK^T: lane holds 16 kv-scores for q=lane&15; softmax in-lane + 2 shfl.
// P stays IN REGISTERS: PV B-frag built via pack + 6 shfl_xor per 32-kv chunk.
// K and V both double-buffered; ONE barrier per kv-tile.
// LDS: K 2x16K + V 2x16K = 64 KB. Epilogue reuses Ks[0] as transpose scratch.
__global__ __launch_bounds__(512) void k_attn(const __bf16* __restrict__ qb,
                                              const __bf16* __restrict__ kb,
                                              const __bf16* __restrict__ vtb,
                                              __bf16* __restrict__ ob) {
    __shared__ __bf16 Ks[2][64 * 128];   // [kv][d], XOR-swizzled rows
    __shared__ __bf16 Vs[2][128 * 64];   // [d][kv], XOR-swizzled rows
    const int tid = threadIdx.x, lane = tid & 63, wave = tid >> 6;
    const int pair = blockIdx.x, h = blockIdx.y, b = blockIdx.z;
    const int kvh = h >> 2;
    const int lo = lane & 15, hi = lane >> 4;
    char* PsW = (char*)&Ks[0][0] + wave * 2048;   // epilogue scratch only

    const __bf16* kbb = kb + kvh * HD + (size_t)b * S_LEN * KVLD;
    const __bf16* vbb = vtb + (size_t)(b * NKV + kvh) * HD * S_LEN;

    const int krow_s = wave * 4 + (lane >> 4);  // + r*32
    const int kp_s   = lane & 15;
    const int vrow_s = wave * 8 + (lane >> 3);  // + r*64
    const int vp_s   = lane & 7;

    auto STAGE_K = [&](int buf, int t) {
#pragma unroll
        for (int r = 0; r < 2; r++) {
            int row = r * 32 + krow_s;
            int c = kp_s ^ (row & 7);
            gld16(kbb + (size_t)(t * 64 + row) * KVLD + c * 8,
                  &Ks[buf][(r * 32 + wave * 4) * 128]);
        }
    };
    auto STAGE_V = [&](int buf, int t) {
#pragma unroll
        for (int r = 0; r < 2; r++) {
            int row = r * 64 + vrow_s;
            int c = vp_s ^ (row & 7);
            gld16(vbb + (size_t)row * S_LEN + t * 64 + c * 8,
                  &Vs[buf][(r * 64 + wave * 8) * 64]);
        }
    };

#pragma unroll 1
    for (int pi = 0; pi < 2; pi++) {
        const int qt = pi ? (NQT - 1 - pair) : pair;   // 128-row q-tile index
        const int nkv = 2 * qt + 2;                    // kv tiles of 64 rows

        __syncthreads();   // protect Ks[0] (epilogue scratch) before restaging

        // Q fragments (q pre-scaled by 1/sqrt(HD) in GEMM epilogue); q-row = lo
        const int qrow = qt * 128 + wave * 16 + lo;
        const __bf16* qptr = qb + (size_t)(b * S_LEN + qrow) * HID + h * HD;
        bf16x8 qa[4];
#pragma unroll
        for (int kf = 0; kf < 4; kf++) qa[kf] = *(const bf16x8*)(qptr + kf * 32 + hi * 8);

        f32x4 o[8] = {};                 // O^T: o[dt][r] = O[q=lo][d=dt*16+hi*4+r]
        float Mr = -3e30f, Lr = 0.f;

        int cur = 0;
        STAGE_K(0, 0);
        STAGE_V(0, 0);
        __syncthreads();

#pragma unroll 1
        for (int t = 0; t < nkv; t++) {
            if (t < nkv - 1) { STAGE_K(cur ^ 1, t + 1); STAGE_V(cur ^ 1, t + 1); }

            // S^T = K Q^T: sc[nt][r] = S[kv=t*64+nt*16+hi*4+r][q=lo]
            f32x4 sc[4];
            __builtin_amdgcn_s_setprio(1);
#pragma unroll
            for (int nt = 0; nt < 4; nt++) {
                f32x4 s4 = {0.f, 0.f, 0.f, 0.f};
#pragma unroll
                for (int kf = 0; kf < 4; kf++) {
                    int row = nt * 16 + lo;
                    int pp = (kf * 4 + hi) ^ (row & 7);
                    bf16x8 kf8 = *(const bf16x8*)&Ks[cur][row * 128 + pp * 8];
                    s4 = __builtin_amdgcn_mfma_f32_16x16x32_bf16(kf8, qa[kf], s4, 0, 0, 0);
                }
                sc[nt] = s4;
            }
            __builtin_amdgcn_s_setprio(0);

            if (t >= 2 * qt) { // causal mask on q-range-overlapping tiles
                int qg = qt * 128 + wave * 16 + lo;
#pragma unroll
                for (int nt = 0; nt < 4; nt++)
#pragma unroll
                    for (int r = 0; r < 4; r++) {
                        int kg = t * 64 + nt * 16 + hi * 4 + r;
                        if (kg > qg) sc[nt][r] = -1e30f;
                    }
            }
            // online softmax, in-lane + 2 shfl; T13 defer-max (thr=8)
            float mloc = sc[0][0];
#pragma unroll
            for (int nt = 0; nt < 4; nt++)
#pragma unroll
                for (int r = 0; r < 4; r++) mloc = fmaxf(mloc, sc[nt][r]);
            mloc = fmaxf(mloc, __shfl_xor(mloc, 16, 64));
            mloc = fmaxf(mloc, __shfl_xor(mloc, 32, 64));
            float mn = (mloc <= Mr + 8.f) ? Mr : mloc;
            float sum = 0.f;
#pragma unroll
            for (int nt = 0; nt < 4; nt++)
#pragma unroll
                for (int r = 0; r < 4; r++) {
                    float e = __expf(sc[nt][r] - mn);
                    sc[nt][r] = e;
                    sum += e;
                }
            sum += __shfl_xor(sum, 16, 64);
            sum += __shfl_xor(sum, 32, 64);
            if (mn != Mr) {
                float scl = __expf(Mr - mn);
                Lr = Lr * scl + sum;
                Mr = mn;
#pragma unroll
                for (int dt = 0; dt < 8; dt++) o[dt] *= scl;
            } else {
                Lr += sum;
            }
            // In-register P -> PV B-fragments. Lane holds P[kv=nt*16+hi*4+r][q=lo];
            // B-frag for chunk c needs P[kv=c*32+hi*8+j][q=lo], j=0..7:
            // a 4-lane redistribution among {lo, lo+16k}. pack + xor32 + xor16.
            bf16x8 pf[2];
#pragma unroll
            for (int c = 0; c < 2; c++) {
                unsigned a0 = pk2(sc[2 * c][0], sc[2 * c][1]);
                unsigned a1 = pk2(sc[2 * c][2], sc[2 * c][3]);
                unsigned b0 = pk2(sc[2 * c + 1][0], sc[2 * c + 1][1]);
                unsigned b1 = pk2(sc[2 * c + 1][2], sc[2 * c + 1][3]);
                unsigned ra0 = __shfl_xor((int)a0, 32, 64);
                unsigned ra1 = __shfl_xor((int)a1, 32, 64);
                unsigned rb0 = __shfl_xor((int)b0, 32, 64);
                unsigned rb1 = __shfl_xor((int)b1, 32, 64);
                unsigned x0 = (hi < 2) ? ((hi & 1) ? a0 : ra0) : ((hi & 1) ? rb0 : b0);
                unsigned x1 = (hi < 2) ? ((hi & 1) ? a1 : ra1) : ((hi & 1) ? rb1 : b1);
                unsigned y0 = __shfl_xor((int)x0, 16, 64);
                unsigned y1 = __shfl_xor((int)x1, 16, 64);
                u32x4 fv;
                fv[0] = (hi == 0) ? a0 : (hi == 2) ? rb0 : y0;
                fv[1] = (hi == 0) ? a1 : (hi == 2) ? rb1 : y1;
                fv[2] = (hi == 1) ? ra0 : (hi == 3) ? b0 : y0;
                fv[3] = (hi == 1) ? ra1 : (hi == 3) ? b1 : y1;
                pf[c] = __builtin_bit_cast(bf16x8, fv);
            }
            // O^T += V^T P
            __builtin_amdgcn_s_setprio(1);
#pragma unroll
            for (int dt = 0; dt < 8; dt++) {
                int rowd = dt * 16 + lo;
#pragma unroll
                for (int c = 0; c < 2; c++) {
                    int ch = c * 4 + hi;
                    bf16x8 vv = *(const bf16x8*)&Vs[cur][rowd * 64 + (ch ^ (rowd & 7)) * 8];
                    o[dt] = __builtin_amdgcn_mfma_f32_16x16x32_bf16(vv, pf[c], o[dt], 0, 0, 0);
                }
            }
            __builtin_amdgcn_s_setprio(0);
            __syncthreads();  // drains prefetch; protects both bufs before reuse
            cur ^= 1;
        }
        // epilogue: O^T -> scratch (Ks[0] area) -> coalesced bf16x8 stores
        float rl = 1.0f / Lr;
        const int qe = lane >> 2, c4 = lane & 3;
#pragma unroll
        for (int h2 = 0; h2 < 2; h2++) {
#pragma unroll
            for (int dt4 = 0; dt4 < 4; dt4++) {
                bf16x4 w;
#pragma unroll
                for (int r = 0; r < 4; r++) w[r] = (__bf16)(o[h2 * 4 + dt4][r] * rl);
                *(bf16x4*)(PsW + lo * 128 + ((dt4 * 32 + hi * 8) ^ ((lo & 7) << 4))) = w;
            }
            asm volatile("s_waitcnt lgkmcnt(0)" ::: "memory");
            __builtin_amdgcn_sched_barrier(0);
#pragma unroll
            for (int s2 = 0; s2 < 2; s2++) {
                int ch = c4 + s2 * 4;
                bf16x8 v = *(const bf16x8*)(PsW + qe * 128 + ((ch * 16) ^ ((qe & 7) << 4)));
                int qg = qt * 128 + wave * 16 + qe;
                int col = h * HD + h2 * 64 + ch * 8;
                *(bf16x8*)&ob[(size_t)(b * S_LEN + qg) * HID + col] = v;
            }
        }
    }
}

// ----------------------------------- host -----------------------------------
extern "C" void kernel_launch(void* const* d_in, const int* in_sizes, int n_in,
                              void* d_out, int out_size, void* d_ws, size_t ws_size,
                              hipStream_t stream) {
    (void)in_sizes; (void)n_in; (void)out_size; (void)ws_size;
    const float* x    = (const float*)d_in[0];
    const float* cosp = (const float*)d_in[1];
    const float* sinp = (const float*)d_in[2];
    const float* Wq   = (const float*)d_in[3];
    const float* Wk   = (const float*)d_in[4];
    const float* Wv   = (const float*)d_in[5];
    const float* Wo   = (const float*)d_in[6];
    float* out = (float*)d_out;

    char* ws = (char*)d_ws;
    __bf16* xb   = (__bf16*)(ws);                 // [8192][2048]        32 MB
    __bf16* wqt  = (__bf16*)(ws + 33554432);      // [2048][2048]         8 MB
    __bf16* wkvt = (__bf16*)(ws + 41943040);      // [1024][2048] (k|v)   4 MB  (contiguous with wqt -> [3072][2048])
    __bf16* wot  = (__bf16*)(ws + 46137344);      // [2048][2048]         8 MB
    __bf16* qbuf = (__bf16*)(ws + 54525952);      // [8192][2048]        32 MB
    __bf16* kv   = (__bf16*)(ws + 88080384);      // [8192][1024]        16 MB
    __bf16* vtb  = (__bf16*)(ws + 104857600);     // [16][128][2048]      8 MB
    __bf16* aob  = xb;                            // reuse xb after QKV GEMM

    k_conv_x<<<MTOT * HID / 8 / 256, 256, 0, stream>>>(x, xb);
    { dim3 g(32, 32); k_transpose_w<<<g, 256, 0, stream>>>(Wq, wqt, HID, HID); }
    { dim3 g(32, 8);  k_transpose_w<<<g, 256, 0, stream>>>(Wk, wkvt, HID, NKV * HD); }
    { dim3 g(32, 8);  k_transpose_w<<<g, 256, 0, stream>>>(Wv, wkvt + (size_t)512 * HID, HID, NKV * HD); }
    { dim3 g(32, 32); k_transpose_w<<<g, 256, 0, stream>>>(Wo, wot, HID, HID); }

    { dim3 g(MTOT / 256, 3072 / 128);
      k_gemm3<true><<<g, 512, 0, stream>>>(xb, wqt, nullptr, qbuf, kv, cosp, sinp, 3072, HID); }

    { dim3 g(S_LEN / 64, HD / 64, 16); k_transpose_v<<<g, 256, 0, stream>>>(kv, vtb); }
    { dim3 g(NQT / 2, 16, BATCH);      k_attn<<<g, 512, 0, stream>>>(qbuf, kv, vtb, aob); }

    { dim3 g(MTOT / 256, HID / 128);
      k_gemm3<false><<<g, 512, 0, stream>>>(aob, wot, out, nullptr, nullptr, nullptr, nullptr, HID, HID); }
}

// Round 7
// 416.758 us; speedup vs baseline: 1.0949x; 1.0949x over previous
//
#include <hip/hip_runtime.h>
#include <stdint.h>

#define S_LEN 2048
#define BATCH 4
#define HID   2048
#define HD    128
#define NKV   4
#define KVLD  1024          // combined K|V projection row stride (2*NKV*HD)
#define MTOT  (BATCH*S_LEN) // 8192
#define NQT   (S_LEN/128)   // 16 q-tiles (128 rows) per (b,h)
#define QSCALE 0.08838834764831845f

typedef float    f32x4  __attribute__((ext_vector_type(4)));
typedef __bf16   bf16x8 __attribute__((ext_vector_type(8)));
typedef __bf16   bf16x4 __attribute__((ext_vector_type(4)));
typedef unsigned u32x4  __attribute__((ext_vector_type(4)));

// async global->LDS, 16B per lane. LDS dest = wave-uniform base + lane*16.
__device__ __forceinline__ void gld16(const void* g, void* l) {
    __builtin_amdgcn_global_load_lds(
        (const __attribute__((address_space(1))) void*)g,
        (__attribute__((address_space(3))) void*)l, 16, 0, 0);
}

// pack two f32 -> u32 of 2 bf16 (element 0 in low half)
__device__ __forceinline__ unsigned pk2(float x, float y) {
    union { __bf16 h[2]; unsigned u; } t;
    t.h[0] = (__bf16)x; t.h[1] = (__bf16)y;
    return t.u;
}

// ---------------- fp32 -> bf16 bulk convert (8 elems/thread) ----------------
__global__ void k_conv_x(const float* __restrict__ in, __bf16* __restrict__ out) {
    int i = blockIdx.x * blockDim.x + threadIdx.x;
    f32x4 a = ((const f32x4*)in)[2 * i];
    f32x4 b = ((const f32x4*)in)[2 * i + 1];
    bf16x8 o;
    o[0] = (__bf16)a[0]; o[1] = (__bf16)a[1]; o[2] = (__bf16)a[2]; o[3] = (__bf16)a[3];
    o[4] = (__bf16)b[0]; o[5] = (__bf16)b[1]; o[6] = (__bf16)b[2]; o[7] = (__bf16)b[3];
    ((bf16x8*)out)[i] = o;
}

// ------------- W [K][N] fp32 -> Wt [N][K] bf16 (64x64 LDS tiles) ------------
__global__ void k_transpose_w(const float* __restrict__ in, __bf16* __restrict__ out,
                              int K, int N) {
    __shared__ float tile[64][65];
    int k0 = blockIdx.x * 64, n0 = blockIdx.y * 64;
    for (int e = threadIdx.x; e < 4096; e += 256) {
        int r = e >> 6, c = e & 63;
        tile[r][c] = in[(size_t)(k0 + r) * N + n0 + c];
    }
    __syncthreads();
    for (int e = threadIdx.x; e < 4096; e += 256) {
        int r = e >> 6, c = e & 63;
        out[(size_t)(n0 + r) * K + k0 + c] = (__bf16)tile[c][r];
    }
}

// -------- V slice of kvbuf [8192][1024] -> vt [16 planes][128 d][2048 s] ----
__global__ void k_transpose_v(const __bf16* __restrict__ kv, __bf16* __restrict__ vt) {
    __shared__ __bf16 tile[64][65];
    int plane = blockIdx.z;          // b*NKV + kvh
    int b = plane >> 2, kvh = plane & 3;
    int s0 = blockIdx.x * 64, d0 = blockIdx.y * 64;
    const __bf16* src = kv + (size_t)(b * S_LEN + s0) * KVLD + NKV * HD + kvh * HD + d0;
    for (int e = threadIdx.x; e < 4096; e += 256) {
        int r = e >> 6, c = e & 63;            // r: s offset, c: d offset
        tile[r][c] = src[(size_t)r * KVLD + c];
    }
    __syncthreads();
    __bf16* dst = vt + (size_t)plane * HD * S_LEN + (size_t)d0 * S_LEN + s0;
    for (int e = threadIdx.x; e < 4096; e += 256) {
        int r = e >> 6, c = e & 63;            // r: d offset, c: s offset
        dst[(size_t)r * S_LEN + c] = tile[c][r];
    }
}

// ---- merged QKV GEMM: C[8192][3072] = xb * [wqt|wkvt]^T, RoPE fused --------
// Compute: R5 structure (128x128 tile, BK=64, 4 waves, XOR-swizzled LDS).
// Epilogue: C-tile -> LDS (padded [128][132], reuses As/Bs space) -> per-thread
// 8-wide row chunks: local rope (no shfl), f32x4 cos/sin loads, bf16x8 stores.
// cols [0,2048) -> q (rope+scale); [2048,2560) -> k (rope); [2560,3072) -> v.
__global__ __launch_bounds__(256) void k_gemm_qkv(const __bf16* __restrict__ A,
                                                  const __bf16* __restrict__ Bt,
                                                  __bf16* __restrict__ qbuf,
                                                  __bf16* __restrict__ kvbuf,
                                                  const float* __restrict__ cosp,
                                                  const float* __restrict__ sinp) {
    __shared__ __align__(16) char smem[33792];      // 128*132*2 epilogue / As+Bs
    __bf16* As = (__bf16*)smem;                     // [128*64]
    __bf16* Bs = (__bf16*)(smem + 16384);           // [128*64]
    const int tid = threadIdx.x, lane = tid & 63, wave = tid >> 6;
    const int wm = wave >> 1, wn = wave & 1;
    const int m0 = blockIdx.x * 128, n0 = blockIdx.y * 128;
    const int lo = lane & 15, hi = lane >> 4;
    f32x4 acc[4][4] = {};

    const int srow = wave * 8 + (lane >> 3); // staging row (+ r*32)
    const int sp   = lane & 7;               // physical 16B chunk

    for (int kt = 0; kt < HID; kt += 64) {
#pragma unroll
        for (int r = 0; r < 4; r++) {        // A tile
            int row = r * 32 + srow;
            int c = sp ^ (row & 7);
            gld16(A + (size_t)(m0 + row) * HID + kt + c * 8, &As[(r * 32 + wave * 8) * 64]);
        }
#pragma unroll
        for (int r = 0; r < 4; r++) {        // B tile
            int row = r * 32 + srow;
            int c = sp ^ (row & 7);
            gld16(Bt + (size_t)(n0 + row) * HID + kt + c * 8, &Bs[(r * 32 + wave * 8) * 64]);
        }
        __syncthreads();
#pragma unroll
        for (int ks = 0; ks < 2; ks++) {
            bf16x8 af[4], bfr[4];
#pragma unroll
            for (int mt = 0; mt < 4; mt++) {
                int row = wm * 64 + mt * 16 + lo;
                int pp = (ks * 4 + hi) ^ (row & 7);
                af[mt] = *(const bf16x8*)&As[row * 64 + pp * 8];
            }
#pragma unroll
            for (int nt = 0; nt < 4; nt++) {
                int row = wn * 64 + nt * 16 + lo;
                int pp = (ks * 4 + hi) ^ (row & 7);
                bfr[nt] = *(const bf16x8*)&Bs[row * 64 + pp * 8];
            }
#pragma unroll
            for (int mt = 0; mt < 4; mt++)
#pragma unroll
                for (int nt = 0; nt < 4; nt++)
                    acc[mt][nt] = __builtin_amdgcn_mfma_f32_16x16x32_bf16(
                        af[mt], bfr[nt], acc[mt][nt], 0, 0, 0);
        }
        __syncthreads();
    }

    // ---- epilogue: stage C (bf16) in LDS, then vectorized rope + stores ----
    __bf16* Cs = (__bf16*)smem;                     // [128][132]
#pragma unroll
    for (int mt = 0; mt < 4; mt++)
#pragma unroll
        for (int nt = 0; nt < 4; nt++) {
            int rl = wm * 64 + mt * 16 + hi * 4;
            int cl = wn * 64 + nt * 16 + lo;
#pragma unroll
            for (int r = 0; r < 4; r++)
                Cs[(rl + r) * 132 + cl] = (__bf16)acc[mt][nt][r];
        }
    __syncthreads();

    const int crow = tid >> 4;           // 0..15 (+16 per rep)
    const int cch  = tid & 15;           // 8-col chunk within the 128-col tile
    const int colg = n0 + cch * 8;
    const bool isQ = colg < 2048;
    const bool doRope = colg < 2560;     // q and k columns
    const int d0 = colg & (HD - 1);
#pragma unroll
    for (int rep = 0; rep < 8; rep++) {
        int row = rep * 16 + crow;
        int rowg = m0 + row;
        bf16x8 v = *(const bf16x8*)&Cs[row * 132 + cch * 8];
        float f[8];
#pragma unroll
        for (int j = 0; j < 8; j++) f[j] = (float)v[j];
        if (doRope) {
            int s = rowg & (S_LEN - 1);
            f32x4 c0 = *(const f32x4*)&cosp[s * HD + d0];
            f32x4 c1 = *(const f32x4*)&cosp[s * HD + d0 + 4];
            f32x4 s0 = *(const f32x4*)&sinp[s * HD + d0];
            f32x4 s1 = *(const f32x4*)&sinp[s * HD + d0 + 4];
            float cc[8] = {c0[0], c0[1], c0[2], c0[3], c1[0], c1[1], c1[2], c1[3]};
            float ss[8] = {s0[0], s0[1], s0[2], s0[3], s1[0], s1[1], s1[2], s1[3]};
#pragma unroll
            for (int p = 0; p < 4; p++) {
                float e0 = f[2 * p], e1 = f[2 * p + 1];
                f[2 * p]     = e0 * cc[2 * p]     - e1 * ss[2 * p];
                f[2 * p + 1] = e1 * cc[2 * p + 1] + e0 * ss[2 * p + 1];
            }
            if (isQ) {
#pragma unroll
                for (int j = 0; j < 8; j++) f[j] *= QSCALE;
            }
        }
        bf16x8 o;
#pragma unroll
        for (int j = 0; j < 8; j++) o[j] = (__bf16)f[j];
        if (isQ) *(bf16x8*)&qbuf[(size_t)rowg * HID + colg] = o;
        else     *(bf16x8*)&kvbuf[(size_t)rowg * KVLD + (colg - 2048)] = o;
    }
}

// --------------- GEMM: C[M][N] = A[M][K] * Bt[N][K]^T  (bf16 MFMA) ----------
// R5 structure, untouched (measured ~890 TF class for O-proj).
template <bool OUTF32>
__global__ __launch_bounds__(256) void k_gemm(const __bf16* __restrict__ A,
                                              const __bf16* __restrict__ Bt,
                                              void* __restrict__ Cp,
                                              int M, int N, int K) {
    (void)M;
    __shared__ __bf16 As[128 * 64];
    __shared__ __bf16 Bs[128 * 64];
    const int tid = threadIdx.x, lane = tid & 63, wave = tid >> 6;
    const int wm = wave >> 1, wn = wave & 1;
    const int m0 = blockIdx.x * 128, n0 = blockIdx.y * 128;
    const int lo = lane & 15, hi = lane >> 4;
    f32x4 acc[4][4] = {};

    const int srow = wave * 8 + (lane >> 3);
    const int sp   = lane & 7;

    for (int kt = 0; kt < K; kt += 64) {
#pragma unroll
        for (int r = 0; r < 4; r++) {
            int row = r * 32 + srow;
            int c = sp ^ (row & 7);
            gld16(A + (size_t)(m0 + row) * K + kt + c * 8, &As[(r * 32 + wave * 8) * 64]);
        }
#pragma unroll
        for (int r = 0; r < 4; r++) {
            int row = r * 32 + srow;
            int c = sp ^ (row & 7);
            gld16(Bt + (size_t)(n0 + row) * K + kt + c * 8, &Bs[(r * 32 + wave * 8) * 64]);
        }
        __syncthreads();
#pragma unroll
        for (int ks = 0; ks < 2; ks++) {
            bf16x8 af[4], bfr[4];
#pragma unroll
            for (int mt = 0; mt < 4; mt++) {
                int row = wm * 64 + mt * 16 + lo;
                int pp = (ks * 4 + hi) ^ (row & 7);
                af[mt] = *(const bf16x8*)&As[row * 64 + pp * 8];
            }
#pragma unroll
            for (int nt = 0; nt < 4; nt++) {
                int row = wn * 64 + nt * 16 + lo;
                int pp = (ks * 4 + hi) ^ (row & 7);
                bfr[nt] = *(const bf16x8*)&Bs[row * 64 + pp * 8];
            }
#pragma unroll
            for (int mt = 0; mt < 4; mt++)
#pragma unroll
                for (int nt = 0; nt < 4; nt++)
                    acc[mt][nt] = __builtin_amdgcn_mfma_f32_16x16x32_bf16(
                        af[mt], bfr[nt], acc[mt][nt], 0, 0, 0);
        }
        __syncthreads();
    }
#pragma unroll
    for (int mt = 0; mt < 4; mt++) {
#pragma unroll
        for (int nt = 0; nt < 4; nt++) {
            int row = m0 + wm * 64 + mt * 16 + hi * 4;
            int col = n0 + wn * 64 + nt * 16 + lo;
#pragma unroll
            for (int r = 0; r < 4; r++) {
                if (OUTF32)
                    ((float*)Cp)[(size_t)(row + r) * N + col] = acc[mt][nt][r];
                else
                    ((__bf16*)Cp)[(size_t)(row + r) * N + col] = (__bf16)acc[mt][nt][r];
            }
        }
    }
}

// ----------------------------- flash attention ------------------------------
// grid (pair=8, head=16, batch=4); block = 512 threads = 8 waves x 16 q-rows.
// Swapped QK^T: lane holds 16 kv-scores for q=lane&15; softmax in-lane + 2 shfl.
// P stays IN REGISTERS: PV B-frag built via pack + 6 shfl_xor per 32-kv chunk.
// K and V both double-buffered; ONE barrier per kv-tile.
// LDS: K 2x16K + V 2x16K = 64 KB. Epilogue reuses Ks[0] as transpose scratch.
__global__ __launch_bounds__(512) void k_attn(const __bf16* __restrict__ qb,
                                              const __bf16* __restrict__ kb,
                                              const __bf16* __restrict__ vtb,
                                              __bf16* __restrict__ ob) {
    __shared__ __bf16 Ks[2][64 * 128];   // [kv][d], XOR-swizzled rows
    __shared__ __bf16 Vs[2][128 * 64];   // [d][kv], XOR-swizzled rows
    const int tid = threadIdx.x, lane = tid & 63, wave = tid >> 6;
    const int pair = blockIdx.x, h = blockIdx.y, b = blockIdx.z;
    const int kvh = h >> 2;
    const int lo = lane & 15, hi = lane >> 4;
    char* PsW = (char*)&Ks[0][0] + wave * 2048;   // epilogue scratch only

    const __bf16* kbb = kb + kvh * HD + (size_t)b * S_LEN * KVLD;
    const __bf16* vbb = vtb + (size_t)(b * NKV + kvh) * HD * S_LEN;

    const int krow_s = wave * 4 + (lane >> 4);  // + r*32
    const int kp_s   = lane & 15;
    const int vrow_s = wave * 8 + (lane >> 3);  // + r*64
    const int vp_s   = lane & 7;

    auto STAGE_K = [&](int buf, int t) {
#pragma unroll
        for (int r = 0; r < 2; r++) {
            int row = r * 32 + krow_s;
            int c = kp_s ^ (row & 7);
            gld16(kbb + (size_t)(t * 64 + row) * KVLD + c * 8,
                  &Ks[buf][(r * 32 + wave * 4) * 128]);
        }
    };
    auto STAGE_V = [&](int buf, int t) {
#pragma unroll
        for (int r = 0; r < 2; r++) {
            int row = r * 64 + vrow_s;
            int c = vp_s ^ (row & 7);
            gld16(vbb + (size_t)row * S_LEN + t * 64 + c * 8,
                  &Vs[buf][(r * 64 + wave * 8) * 64]);
        }
    };

#pragma unroll 1
    for (int pi = 0; pi < 2; pi++) {
        const int qt = pi ? (NQT - 1 - pair) : pair;   // 128-row q-tile index
        const int nkv = 2 * qt + 2;                    // kv tiles of 64 rows

        __syncthreads();   // protect Ks[0] (epilogue scratch) before restaging

        // Q fragments (q pre-scaled by 1/sqrt(HD) in GEMM epilogue); q-row = lo
        const int qrow = qt * 128 + wave * 16 + lo;
        const __bf16* qptr = qb + (size_t)(b * S_LEN + qrow) * HID + h * HD;
        bf16x8 qa[4];
#pragma unroll
        for (int kf = 0; kf < 4; kf++) qa[kf] = *(const bf16x8*)(qptr + kf * 32 + hi * 8);

        f32x4 o[8] = {};                 // O^T: o[dt][r] = O[q=lo][d=dt*16+hi*4+r]
        float Mr = -3e30f, Lr = 0.f;

        int cur = 0;
        STAGE_K(0, 0);
        STAGE_V(0, 0);
        __syncthreads();

#pragma unroll 1
        for (int t = 0; t < nkv; t++) {
            if (t < nkv - 1) { STAGE_K(cur ^ 1, t + 1); STAGE_V(cur ^ 1, t + 1); }

            // S^T = K Q^T: sc[nt][r] = S[kv=t*64+nt*16+hi*4+r][q=lo]
            f32x4 sc[4];
            __builtin_amdgcn_s_setprio(1);
#pragma unroll
            for (int nt = 0; nt < 4; nt++) {
                f32x4 s4 = {0.f, 0.f, 0.f, 0.f};
#pragma unroll
                for (int kf = 0; kf < 4; kf++) {
                    int row = nt * 16 + lo;
                    int pp = (kf * 4 + hi) ^ (row & 7);
                    bf16x8 kf8 = *(const bf16x8*)&Ks[cur][row * 128 + pp * 8];
                    s4 = __builtin_amdgcn_mfma_f32_16x16x32_bf16(kf8, qa[kf], s4, 0, 0, 0);
                }
                sc[nt] = s4;
            }
            __builtin_amdgcn_s_setprio(0);

            if (t >= 2 * qt) { // causal mask on q-range-overlapping tiles
                int qg = qt * 128 + wave * 16 + lo;
#pragma unroll
                for (int nt = 0; nt < 4; nt++)
#pragma unroll
                    for (int r = 0; r < 4; r++) {
                        int kg = t * 64 + nt * 16 + hi * 4 + r;
                        if (kg > qg) sc[nt][r] = -1e30f;
                    }
            }
            // online softmax, in-lane + 2 shfl; T13 defer-max (thr=8)
            float mloc = sc[0][0];
#pragma unroll
            for (int nt = 0; nt < 4; nt++)
#pragma unroll
                for (int r = 0; r < 4; r++) mloc = fmaxf(mloc, sc[nt][r]);
            mloc = fmaxf(mloc, __shfl_xor(mloc, 16, 64));
            mloc = fmaxf(mloc, __shfl_xor(mloc, 32, 64));
            float mn = (mloc <= Mr + 8.f) ? Mr : mloc;
            float sum = 0.f;
#pragma unroll
            for (int nt = 0; nt < 4; nt++)
#pragma unroll
                for (int r = 0; r < 4; r++) {
                    float e = __expf(sc[nt][r] - mn);
                    sc[nt][r] = e;
                    sum += e;
                }
            sum += __shfl_xor(sum, 16, 64);
            sum += __shfl_xor(sum, 32, 64);
            if (mn != Mr) {
                float scl = __expf(Mr - mn);
                Lr = Lr * scl + sum;
                Mr = mn;
#pragma unroll
                for (int dt = 0; dt < 8; dt++) o[dt] *= scl;
            } else {
                Lr += sum;
            }
            // In-register P -> PV B-fragments. Lane holds P[kv=nt*16+hi*4+r][q=lo];
            // B-frag for chunk c needs P[kv=c*32+hi*8+j][q=lo], j=0..7:
            // a 4-lane redistribution among {lo, lo+16k}. pack + xor32 + xor16.
            bf16x8 pf[2];
#pragma unroll
            for (int c = 0; c < 2; c++) {
                unsigned a0 = pk2(sc[2 * c][0], sc[2 * c][1]);
                unsigned a1 = pk2(sc[2 * c][2], sc[2 * c][3]);
                unsigned b0 = pk2(sc[2 * c + 1][0], sc[2 * c + 1][1]);
                unsigned b1 = pk2(sc[2 * c + 1][2], sc[2 * c + 1][3]);
                unsigned ra0 = __shfl_xor((int)a0, 32, 64);
                unsigned ra1 = __shfl_xor((int)a1, 32, 64);
                unsigned rb0 = __shfl_xor((int)b0, 32, 64);
                unsigned rb1 = __shfl_xor((int)b1, 32, 64);
                unsigned x0 = (hi < 2) ? ((hi & 1) ? a0 : ra0) : ((hi & 1) ? rb0 : b0);
                unsigned x1 = (hi < 2) ? ((hi & 1) ? a1 : ra1) : ((hi & 1) ? rb1 : b1);
                unsigned y0 = __shfl_xor((int)x0, 16, 64);
                unsigned y1 = __shfl_xor((int)x1, 16, 64);
                u32x4 fv;
                fv[0] = (hi == 0) ? a0 : (hi == 2) ? rb0 : y0;
                fv[1] = (hi == 0) ? a1 : (hi == 2) ? rb1 : y1;
                fv[2] = (hi == 1) ? ra0 : (hi == 3) ? b0 : y0;
                fv[3] = (hi == 1) ? ra1 : (hi == 3) ? b1 : y1;
                pf[c] = __builtin_bit_cast(bf16x8, fv);
            }
            // O^T += V^T P
            __builtin_amdgcn_s_setprio(1);
#pragma unroll
            for (int dt = 0; dt < 8; dt++) {
                int rowd = dt * 16 + lo;
#pragma unroll
                for (int c = 0; c < 2; c++) {
                    int ch = c * 4 + hi;
                    bf16x8 vv = *(const bf16x8*)&Vs[cur][rowd * 64 + (ch ^ (rowd & 7)) * 8];
                    o[dt] = __builtin_amdgcn_mfma_f32_16x16x32_bf16(vv, pf[c], o[dt], 0, 0, 0);
                }
            }
            __builtin_amdgcn_s_setprio(0);
            __syncthreads();  // drains prefetch; protects both bufs before reuse
            cur ^= 1;
        }
        // epilogue: O^T -> scratch (Ks[0] area) -> coalesced bf16x8 stores
        float rl = 1.0f / Lr;
        const int qe = lane >> 2, c4 = lane & 3;
#pragma unroll
        for (int h2 = 0; h2 < 2; h2++) {
#pragma unroll
            for (int dt4 = 0; dt4 < 4; dt4++) {
                bf16x4 w;
#pragma unroll
                for (int r = 0; r < 4; r++) w[r] = (__bf16)(o[h2 * 4 + dt4][r] * rl);
                *(bf16x4*)(PsW + lo * 128 + ((dt4 * 32 + hi * 8) ^ ((lo & 7) << 4))) = w;
            }
            asm volatile("s_waitcnt lgkmcnt(0)" ::: "memory");
            __builtin_amdgcn_sched_barrier(0);
#pragma unroll
            for (int s2 = 0; s2 < 2; s2++) {
                int ch = c4 + s2 * 4;
                bf16x8 v = *(const bf16x8*)(PsW + qe * 128 + ((ch * 16) ^ ((qe & 7) << 4)));
                int qg = qt * 128 + wave * 16 + qe;
                int col = h * HD + h2 * 64 + ch * 8;
                *(bf16x8*)&ob[(size_t)(b * S_LEN + qg) * HID + col] = v;
            }
        }
    }
}

// ----------------------------------- host -----------------------------------
extern "C" void kernel_launch(void* const* d_in, const int* in_sizes, int n_in,
                              void* d_out, int out_size, void* d_ws, size_t ws_size,
                              hipStream_t stream) {
    (void)in_sizes; (void)n_in; (void)out_size; (void)ws_size;
    const float* x    = (const float*)d_in[0];
    const float* cosp = (const float*)d_in[1];
    const float* sinp = (const float*)d_in[2];
    const float* Wq   = (const float*)d_in[3];
    const float* Wk   = (const float*)d_in[4];
    const float* Wv   = (const float*)d_in[5];
    const float* Wo   = (const float*)d_in[6];
    float* out = (float*)d_out;

    char* ws = (char*)d_ws;
    __bf16* xb   = (__bf16*)(ws);                 // [8192][2048]        32 MB
    __bf16* wqt  = (__bf16*)(ws + 33554432);      // [2048][2048]         8 MB
    __bf16* wkvt = (__bf16*)(ws + 41943040);      // [1024][2048] (k|v)   4 MB  (contiguous with wqt -> [3072][2048])
    __bf16* wot  = (__bf16*)(ws + 46137344);      // [2048][2048]         8 MB
    __bf16* qbuf = (__bf16*)(ws + 54525952);      // [8192][2048]        32 MB
    __bf16* kv   = (__bf16*)(ws + 88080384);      // [8192][1024]        16 MB
    __bf16* vtb  = (__bf16*)(ws + 104857600);     // [16][128][2048]      8 MB
    __bf16* aob  = xb;                            // reuse xb after QKV GEMM

    k_conv_x<<<MTOT * HID / 8 / 256, 256, 0, stream>>>(x, xb);
    { dim3 g(32, 32); k_transpose_w<<<g, 256, 0, stream>>>(Wq, wqt, HID, HID); }
    { dim3 g(32, 8);  k_transpose_w<<<g, 256, 0, stream>>>(Wk, wkvt, HID, NKV * HD); }
    { dim3 g(32, 8);  k_transpose_w<<<g, 256, 0, stream>>>(Wv, wkvt + (size_t)512 * HID, HID, NKV * HD); }
    { dim3 g(32, 32); k_transpose_w<<<g, 256, 0, stream>>>(Wo, wot, HID, HID); }

    { dim3 g(MTOT / 128, 3072 / 128);
      k_gemm_qkv<<<g, 256, 0, stream>>>(xb, wqt, qbuf, kv, cosp, sinp); }

    { dim3 g(S_LEN / 64, HD / 64, 16); k_transpose_v<<<g, 256, 0, stream>>>(kv, vtb); }
    { dim3 g(NQT / 2, 16, BATCH);      k_attn<<<g, 512, 0, stream>>>(qbuf, kv, vtb, aob); }

    { dim3 g(MTOT / 128, HID / 128);
      k_gemm<true><<<g, 256, 0, stream>>>(aob, wot, out, MTOT, HID, HID); }
}

// Round 8
// 393.833 us; speedup vs baseline: 1.1586x; 1.0582x over previous
//
#include <hip/hip_runtime.h>
#include <stdint.h>

#define S_LEN 2048
#define BATCH 4
#define HID   2048
#define HD    128
#define NKV   4
#define KVLD  1024          // combined K|V projection row stride (2*NKV*HD)
#define MTOT  (BATCH*S_LEN) // 8192
#define NQT   (S_LEN/128)   // 16 q-tiles (128 rows) per (b,h)
#define QSCALE 0.08838834764831845f

typedef float    f32x4  __attribute__((ext_vector_type(4)));
typedef __bf16   bf16x8 __attribute__((ext_vector_type(8)));
typedef __bf16   bf16x4 __attribute__((ext_vector_type(4)));
typedef unsigned u32x4  __attribute__((ext_vector_type(4)));

// async global->LDS, 16B per lane. LDS dest = wave-uniform base + lane*16.
__device__ __forceinline__ void gld16(const void* g, void* l) {
    __builtin_amdgcn_global_load_lds(
        (const __attribute__((address_space(1))) void*)g,
        (__attribute__((address_space(3))) void*)l, 16, 0, 0);
}

// ---------------- fp32 -> bf16 bulk convert (8 elems/thread) ----------------
__global__ void k_conv_x(const float* __restrict__ in, __bf16* __restrict__ out) {
    int i = blockIdx.x * blockDim.x + threadIdx.x;
    f32x4 a = ((const f32x4*)in)[2 * i];
    f32x4 b = ((const f32x4*)in)[2 * i + 1];
    bf16x8 o;
    o[0] = (__bf16)a[0]; o[1] = (__bf16)a[1]; o[2] = (__bf16)a[2]; o[3] = (__bf16)a[3];
    o[4] = (__bf16)b[0]; o[5] = (__bf16)b[1]; o[6] = (__bf16)b[2]; o[7] = (__bf16)b[3];
    ((bf16x8*)out)[i] = o;
}

// ------------- W [K][N] fp32 -> Wt [N][K] bf16 (64x64 LDS tiles) ------------
__global__ void k_transpose_w(const float* __restrict__ in, __bf16* __restrict__ out,
                              int K, int N) {
    __shared__ float tile[64][65];
    int k0 = blockIdx.x * 64, n0 = blockIdx.y * 64;
    for (int e = threadIdx.x; e < 4096; e += 256) {
        int r = e >> 6, c = e & 63;
        tile[r][c] = in[(size_t)(k0 + r) * N + n0 + c];
    }
    __syncthreads();
    for (int e = threadIdx.x; e < 4096; e += 256) {
        int r = e >> 6, c = e & 63;
        out[(size_t)(n0 + r) * K + k0 + c] = (__bf16)tile[c][r];
    }
}

// -------- V slice of kvbuf [8192][1024] -> vt [16 planes][128 d][2048 s] ----
__global__ void k_transpose_v(const __bf16* __restrict__ kv, __bf16* __restrict__ vt) {
    __shared__ __bf16 tile[64][65];
    int plane = blockIdx.z;          // b*NKV + kvh
    int b = plane >> 2, kvh = plane & 3;
    int s0 = blockIdx.x * 64, d0 = blockIdx.y * 64;
    const __bf16* src = kv + (size_t)(b * S_LEN + s0) * KVLD + NKV * HD + kvh * HD + d0;
    for (int e = threadIdx.x; e < 4096; e += 256) {
        int r = e >> 6, c = e & 63;            // r: s offset, c: d offset
        tile[r][c] = src[(size_t)r * KVLD + c];
    }
    __syncthreads();
    __bf16* dst = vt + (size_t)plane * HD * S_LEN + (size_t)d0 * S_LEN + s0;
    for (int e = threadIdx.x; e < 4096; e += 256) {
        int r = e >> 6, c = e & 63;            // r: d offset, c: s offset
        dst[(size_t)r * S_LEN + c] = tile[c][r];
    }
}

// ---- merged QKV GEMM: C[8192][3072] = xb * [wqt|wkvt]^T, RoPE fused --------
// Compute: R5 structure (128x128 tile, BK=64, 4 waves, XOR-swizzled LDS).
// Epilogue: C-tile -> LDS (padded [128][132], reuses As/Bs space) -> per-thread
// 8-wide row chunks: local rope (no shfl), f32x4 cos/sin loads, bf16x8 stores.
// cols [0,2048) -> q (rope+scale); [2048,2560) -> k (rope); [2560,3072) -> v.
__global__ __launch_bounds__(256) void k_gemm_qkv(const __bf16* __restrict__ A,
                                                  const __bf16* __restrict__ Bt,
                                                  __bf16* __restrict__ qbuf,
                                                  __bf16* __restrict__ kvbuf,
                                                  const float* __restrict__ cosp,
                                                  const float* __restrict__ sinp) {
    __shared__ __align__(16) char smem[33792];      // 128*132*2 epilogue / As+Bs
    __bf16* As = (__bf16*)smem;                     // [128*64]
    __bf16* Bs = (__bf16*)(smem + 16384);           // [128*64]
    const int tid = threadIdx.x, lane = tid & 63, wave = tid >> 6;
    const int wm = wave >> 1, wn = wave & 1;
    const int m0 = blockIdx.x * 128, n0 = blockIdx.y * 128;
    const int lo = lane & 15, hi = lane >> 4;
    f32x4 acc[4][4] = {};

    const int srow = wave * 8 + (lane >> 3); // staging row (+ r*32)
    const int sp   = lane & 7;               // physical 16B chunk

    for (int kt = 0; kt < HID; kt += 64) {
#pragma unroll
        for (int r = 0; r < 4; r++) {        // A tile
            int row = r * 32 + srow;
            int c = sp ^ (row & 7);
            gld16(A + (size_t)(m0 + row) * HID + kt + c * 8, &As[(r * 32 + wave * 8) * 64]);
        }
#pragma unroll
        for (int r = 0; r < 4; r++) {        // B tile
            int row = r * 32 + srow;
            int c = sp ^ (row & 7);
            gld16(Bt + (size_t)(n0 + row) * HID + kt + c * 8, &Bs[(r * 32 + wave * 8) * 64]);
        }
        __syncthreads();
#pragma unroll
        for (int ks = 0; ks < 2; ks++) {
            bf16x8 af[4], bfr[4];
#pragma unroll
            for (int mt = 0; mt < 4; mt++) {
                int row = wm * 64 + mt * 16 + lo;
                int pp = (ks * 4 + hi) ^ (row & 7);
                af[mt] = *(const bf16x8*)&As[row * 64 + pp * 8];
            }
#pragma unroll
            for (int nt = 0; nt < 4; nt++) {
                int row = wn * 64 + nt * 16 + lo;
                int pp = (ks * 4 + hi) ^ (row & 7);
                bfr[nt] = *(const bf16x8*)&Bs[row * 64 + pp * 8];
            }
#pragma unroll
            for (int mt = 0; mt < 4; mt++)
#pragma unroll
                for (int nt = 0; nt < 4; nt++)
                    acc[mt][nt] = __builtin_amdgcn_mfma_f32_16x16x32_bf16(
                        af[mt], bfr[nt], acc[mt][nt], 0, 0, 0);
        }
        __syncthreads();
    }

    // ---- epilogue: stage C (bf16) in LDS, then vectorized rope + stores ----
    __bf16* Cs = (__bf16*)smem;                     // [128][132]
#pragma unroll
    for (int mt = 0; mt < 4; mt++)
#pragma unroll
        for (int nt = 0; nt < 4; nt++) {
            int rl = wm * 64 + mt * 16 + hi * 4;
            int cl = wn * 64 + nt * 16 + lo;
#pragma unroll
            for (int r = 0; r < 4; r++)
                Cs[(rl + r) * 132 + cl] = (__bf16)acc[mt][nt][r];
        }
    __syncthreads();

    const int crow = tid >> 4;           // 0..15 (+16 per rep)
    const int cch  = tid & 15;           // 8-col chunk within the 128-col tile
    const int colg = n0 + cch * 8;
    const bool isQ = colg < 2048;
    const bool doRope = colg < 2560;     // q and k columns
    const int d0 = colg & (HD - 1);
#pragma unroll
    for (int rep = 0; rep < 8; rep++) {
        int row = rep * 16 + crow;
        int rowg = m0 + row;
        bf16x8 v = *(const bf16x8*)&Cs[row * 132 + cch * 8];
        float f[8];
#pragma unroll
        for (int j = 0; j < 8; j++) f[j] = (float)v[j];
        if (doRope) {
            int s = rowg & (S_LEN - 1);
            f32x4 c0 = *(const f32x4*)&cosp[s * HD + d0];
            f32x4 c1 = *(const f32x4*)&cosp[s * HD + d0 + 4];
            f32x4 s0 = *(const f32x4*)&sinp[s * HD + d0];
            f32x4 s1 = *(const f32x4*)&sinp[s * HD + d0 + 4];
            float cc[8] = {c0[0], c0[1], c0[2], c0[3], c1[0], c1[1], c1[2], c1[3]};
            float ss[8] = {s0[0], s0[1], s0[2], s0[3], s1[0], s1[1], s1[2], s1[3]};
#pragma unroll
            for (int p = 0; p < 4; p++) {
                float e0 = f[2 * p], e1 = f[2 * p + 1];
                f[2 * p]     = e0 * cc[2 * p]     - e1 * ss[2 * p];
                f[2 * p + 1] = e1 * cc[2 * p + 1] + e0 * ss[2 * p + 1];
            }
            if (isQ) {
#pragma unroll
                for (int j = 0; j < 8; j++) f[j] *= QSCALE;
            }
        }
        bf16x8 o;
#pragma unroll
        for (int j = 0; j < 8; j++) o[j] = (__bf16)f[j];
        if (isQ) *(bf16x8*)&qbuf[(size_t)rowg * HID + colg] = o;
        else     *(bf16x8*)&kvbuf[(size_t)rowg * KVLD + (colg - 2048)] = o;
    }
}

// --------------- GEMM: C[M][N] = A[M][K] * Bt[N][K]^T  (bf16 MFMA) ----------
// R5 structure, untouched (measured ~890 TF class for O-proj).
template <bool OUTF32>
__global__ __launch_bounds__(256) void k_gemm(const __bf16* __restrict__ A,
                                              const __bf16* __restrict__ Bt,
                                              void* __restrict__ Cp,
                                              int M, int N, int K) {
    (void)M;
    __shared__ __bf16 As[128 * 64];
    __shared__ __bf16 Bs[128 * 64];
    const int tid = threadIdx.x, lane = tid & 63, wave = tid >> 6;
    const int wm = wave >> 1, wn = wave & 1;
    const int m0 = blockIdx.x * 128, n0 = blockIdx.y * 128;
    const int lo = lane & 15, hi = lane >> 4;
    f32x4 acc[4][4] = {};

    const int srow = wave * 8 + (lane >> 3);
    const int sp   = lane & 7;

    for (int kt = 0; kt < K; kt += 64) {
#pragma unroll
        for (int r = 0; r < 4; r++) {
            int row = r * 32 + srow;
            int c = sp ^ (row & 7);
            gld16(A + (size_t)(m0 + row) * K + kt + c * 8, &As[(r * 32 + wave * 8) * 64]);
        }
#pragma unroll
        for (int r = 0; r < 4; r++) {
            int row = r * 32 + srow;
            int c = sp ^ (row & 7);
            gld16(Bt + (size_t)(n0 + row) * K + kt + c * 8, &Bs[(r * 32 + wave * 8) * 64]);
        }
        __syncthreads();
#pragma unroll
        for (int ks = 0; ks < 2; ks++) {
            bf16x8 af[4], bfr[4];
#pragma unroll
            for (int mt = 0; mt < 4; mt++) {
                int row = wm * 64 + mt * 16 + lo;
                int pp = (ks * 4 + hi) ^ (row & 7);
                af[mt] = *(const bf16x8*)&As[row * 64 + pp * 8];
            }
#pragma unroll
            for (int nt = 0; nt < 4; nt++) {
                int row = wn * 64 + nt * 16 + lo;
                int pp = (ks * 4 + hi) ^ (row & 7);
                bfr[nt] = *(const bf16x8*)&Bs[row * 64 + pp * 8];
            }
#pragma unroll
            for (int mt = 0; mt < 4; mt++)
#pragma unroll
                for (int nt = 0; nt < 4; nt++)
                    acc[mt][nt] = __builtin_amdgcn_mfma_f32_16x16x32_bf16(
                        af[mt], bfr[nt], acc[mt][nt], 0, 0, 0);
        }
        __syncthreads();
    }
#pragma unroll
    for (int mt = 0; mt < 4; mt++) {
#pragma unroll
        for (int nt = 0; nt < 4; nt++) {
            int row = m0 + wm * 64 + mt * 16 + hi * 4;
            int col = n0 + wn * 64 + nt * 16 + lo;
#pragma unroll
            for (int r = 0; r < 4; r++) {
                if (OUTF32)
                    ((float*)Cp)[(size_t)(row + r) * N + col] = acc[mt][nt][r];
                else
                    ((__bf16*)Cp)[(size_t)(row + r) * N + col] = (__bf16)acc[mt][nt][r];
            }
        }
    }
}

// ----------------------------- flash attention ------------------------------
// grid (pair=8, head=16, batch=4); block = 512 threads = 8 waves x 16 q-rows.
// Swapped QK^T: lane holds 16 kv-scores for q=lane&15; softmax in-lane + 2 shfl.
// P redistribution: wave-private swizzled LDS round-trip (4 ds_write_b64 +
// lgkmcnt + 2 ds_read_b128) -- measured cheaper than the 12-shfl in-register
// path (R4 141.6us vs R7 160.6us). K and V double-buffered; ONE barrier/tile.
// LDS: K 2x16K + V 2x16K + Ps 16K = 80 KB (1 block/CU either way; free).
__global__ __launch_bounds__(512) void k_attn(const __bf16* __restrict__ qb,
                                              const __bf16* __restrict__ kb,
                                              const __bf16* __restrict__ vtb,
                                              __bf16* __restrict__ ob) {
    __shared__ __bf16 Ks[2][64 * 128];   // [kv][d], XOR-swizzled rows
    __shared__ __bf16 Vs[2][128 * 64];   // [d][kv], XOR-swizzled rows
    __shared__ __bf16 Ps[8][16 * 64];    // wave-private P / epilogue scratch
    const int tid = threadIdx.x, lane = tid & 63, wave = tid >> 6;
    const int pair = blockIdx.x, h = blockIdx.y, b = blockIdx.z;
    const int kvh = h >> 2;
    const int lo = lane & 15, hi = lane >> 4;
    char* PsW = (char*)&Ps[wave][0];

    const __bf16* kbb = kb + kvh * HD + (size_t)b * S_LEN * KVLD;
    const __bf16* vbb = vtb + (size_t)(b * NKV + kvh) * HD * S_LEN;

    const int krow_s = wave * 4 + (lane >> 4);  // + r*32
    const int kp_s   = lane & 15;
    const int vrow_s = wave * 8 + (lane >> 3);  // + r*64
    const int vp_s   = lane & 7;

    auto STAGE_K = [&](int buf, int t) {
#pragma unroll
        for (int r = 0; r < 2; r++) {
            int row = r * 32 + krow_s;
            int c = kp_s ^ (row & 7);
            gld16(kbb + (size_t)(t * 64 + row) * KVLD + c * 8,
                  &Ks[buf][(r * 32 + wave * 4) * 128]);
        }
    };
    auto STAGE_V = [&](int buf, int t) {
#pragma unroll
        for (int r = 0; r < 2; r++) {
            int row = r * 64 + vrow_s;
            int c = vp_s ^ (row & 7);
            gld16(vbb + (size_t)row * S_LEN + t * 64 + c * 8,
                  &Vs[buf][(r * 64 + wave * 8) * 64]);
        }
    };

#pragma unroll 1
    for (int pi = 0; pi < 2; pi++) {
        const int qt = pi ? (NQT - 1 - pair) : pair;   // 128-row q-tile index
        const int nkv = 2 * qt + 2;                    // kv tiles of 64 rows

        // Q fragments (q pre-scaled by 1/sqrt(HD) in GEMM epilogue); q-row = lo
        const int qrow = qt * 128 + wave * 16 + lo;
        const __bf16* qptr = qb + (size_t)(b * S_LEN + qrow) * HID + h * HD;
        bf16x8 qa[4];
#pragma unroll
        for (int kf = 0; kf < 4; kf++) qa[kf] = *(const bf16x8*)(qptr + kf * 32 + hi * 8);

        f32x4 o[8] = {};                 // O^T: o[dt][r] = O[q=lo][d=dt*16+hi*4+r]
        float Mr = -3e30f, Lr = 0.f;

        int cur = 0;
        if (pi == 1) __syncthreads();    // protect K/V bufs from prior q-tile reads
        STAGE_K(0, 0);
        STAGE_V(0, 0);
        __syncthreads();

#pragma unroll 1
        for (int t = 0; t < nkv; t++) {
            if (t < nkv - 1) { STAGE_K(cur ^ 1, t + 1); STAGE_V(cur ^ 1, t + 1); }

            // S^T = K Q^T: sc[nt][r] = S[kv=t*64+nt*16+hi*4+r][q=lo]
            f32x4 sc[4];
            __builtin_amdgcn_s_setprio(1);
#pragma unroll
            for (int nt = 0; nt < 4; nt++) {
                f32x4 s4 = {0.f, 0.f, 0.f, 0.f};
#pragma unroll
                for (int kf = 0; kf < 4; kf++) {
                    int row = nt * 16 + lo;
                    int pp = (kf * 4 + hi) ^ (row & 7);
                    bf16x8 kf8 = *(const bf16x8*)&Ks[cur][row * 128 + pp * 8];
                    s4 = __builtin_amdgcn_mfma_f32_16x16x32_bf16(kf8, qa[kf], s4, 0, 0, 0);
                }
                sc[nt] = s4;
            }
            __builtin_amdgcn_s_setprio(0);

            if (t >= 2 * qt) { // causal mask on q-range-overlapping tiles
                int qg = qt * 128 + wave * 16 + lo;
#pragma unroll
                for (int nt = 0; nt < 4; nt++)
#pragma unroll
                    for (int r = 0; r < 4; r++) {
                        int kg = t * 64 + nt * 16 + hi * 4 + r;
                        if (kg > qg) sc[nt][r] = -1e30f;
                    }
            }
            // online softmax, in-lane + 2 shfl; T13 defer-max (thr=8)
            float mloc = sc[0][0];
#pragma unroll
            for (int nt = 0; nt < 4; nt++)
#pragma unroll
                for (int r = 0; r < 4; r++) mloc = fmaxf(mloc, sc[nt][r]);
            mloc = fmaxf(mloc, __shfl_xor(mloc, 16, 64));
            mloc = fmaxf(mloc, __shfl_xor(mloc, 32, 64));
            float mn = (mloc <= Mr + 8.f) ? Mr : mloc;
            float sum = 0.f;
#pragma unroll
            for (int nt = 0; nt < 4; nt++)
#pragma unroll
                for (int r = 0; r < 4; r++) {
                    float e = __expf(sc[nt][r] - mn);
                    sc[nt][r] = e;
                    sum += e;
                }
            sum += __shfl_xor(sum, 16, 64);
            sum += __shfl_xor(sum, 32, 64);
            if (mn != Mr) {
                float scl = __expf(Mr - mn);
                Lr = Lr * scl + sum;
                Mr = mn;
#pragma unroll
                for (int dt = 0; dt < 8; dt++) o[dt] *= scl;
            } else {
                Lr += sum;
            }
            // P redistribution via wave-private swizzled LDS (no barrier):
            // lane holds P[kv=nt*16+hi*4+r][q=lo] -> Ps[q=lo][kv], b64 packed.
#pragma unroll
            for (int nt = 0; nt < 4; nt++) {
                bf16x4 pk;
#pragma unroll
                for (int r = 0; r < 4; r++) pk[r] = (__bf16)sc[nt][r];
                *(bf16x4*)(PsW + lo * 128 + ((nt * 32 + hi * 8) ^ ((lo & 7) << 4))) = pk;
            }
            asm volatile("s_waitcnt lgkmcnt(0)" ::: "memory");
            // B-frag: pf[c] = P[kv=c*32+hi*8+j][q=lo], j=0..7
            bf16x8 pf[2];
#pragma unroll
            for (int c = 0; c < 2; c++)
                pf[c] = *(const bf16x8*)(PsW + lo * 128 + ((c * 64 + hi * 16) ^ ((lo & 7) << 4)));
            // O^T += V^T P
            __builtin_amdgcn_s_setprio(1);
#pragma unroll
            for (int dt = 0; dt < 8; dt++) {
                int rowd = dt * 16 + lo;
#pragma unroll
                for (int c = 0; c < 2; c++) {
                    int ch = c * 4 + hi;
                    bf16x8 vv = *(const bf16x8*)&Vs[cur][rowd * 64 + (ch ^ (rowd & 7)) * 8];
                    o[dt] = __builtin_amdgcn_mfma_f32_16x16x32_bf16(vv, pf[c], o[dt], 0, 0, 0);
                }
            }
            __builtin_amdgcn_s_setprio(0);
            __syncthreads();  // drains prefetch; protects both bufs before reuse
            cur ^= 1;
        }
        // epilogue: O^T -> Ps (wave-private) -> coalesced bf16x8 stores
        float rl = 1.0f / Lr;
        const int qe = lane >> 2, c4 = lane & 3;
#pragma unroll
        for (int h2 = 0; h2 < 2; h2++) {
#pragma unroll
            for (int dt4 = 0; dt4 < 4; dt4++) {
                bf16x4 w;
#pragma unroll
                for (int r = 0; r < 4; r++) w[r] = (__bf16)(o[h2 * 4 + dt4][r] * rl);
                *(bf16x4*)(PsW + lo * 128 + ((dt4 * 32 + hi * 8) ^ ((lo & 7) << 4))) = w;
            }
            asm volatile("s_waitcnt lgkmcnt(0)" ::: "memory");
            __builtin_amdgcn_sched_barrier(0);
#pragma unroll
            for (int s2 = 0; s2 < 2; s2++) {
                int ch = c4 + s2 * 4;
                bf16x8 v = *(const bf16x8*)(PsW + qe * 128 + ((ch * 16) ^ ((qe & 7) << 4)));
                int qg = qt * 128 + wave * 16 + qe;
                int col = h * HD + h2 * 64 + ch * 8;
                *(bf16x8*)&ob[(size_t)(b * S_LEN + qg) * HID + col] = v;
            }
        }
    }
}

// ----------------------------------- host -----------------------------------
extern "C" void kernel_launch(void* const* d_in, const int* in_sizes, int n_in,
                              void* d_out, int out_size, void* d_ws, size_t ws_size,
                              hipStream_t stream) {
    (void)in_sizes; (void)n_in; (void)out_size; (void)ws_size;
    const float* x    = (const float*)d_in[0];
    const float* cosp = (const float*)d_in[1];
    const float* sinp = (const float*)d_in[2];
    const float* Wq   = (const float*)d_in[3];
    const float* Wk   = (const float*)d_in[4];
    const float* Wv   = (const float*)d_in[5];
    const float* Wo   = (const float*)d_in[6];
    float* out = (float*)d_out;

    char* ws = (char*)d_ws;
    __bf16* xb   = (__bf16*)(ws);                 // [8192][2048]        32 MB
    __bf16* wqt  = (__bf16*)(ws + 33554432);      // [2048][2048]         8 MB
    __bf16* wkvt = (__bf16*)(ws + 41943040);      // [1024][2048] (k|v)   4 MB  (contiguous with wqt -> [3072][2048])
    __bf16* wot  = (__bf16*)(ws + 46137344);      // [2048][2048]         8 MB
    __bf16* qbuf = (__bf16*)(ws + 54525952);      // [8192][2048]        32 MB
    __bf16* kv   = (__bf16*)(ws + 88080384);      // [8192][1024]        16 MB
    __bf16* vtb  = (__bf16*)(ws + 104857600);     // [16][128][2048]      8 MB
    __bf16* aob  = xb;                            // reuse xb after QKV GEMM

    k_conv_x<<<MTOT * HID / 8 / 256, 256, 0, stream>>>(x, xb);
    { dim3 g(32, 32); k_transpose_w<<<g, 256, 0, stream>>>(Wq, wqt, HID, HID); }
    { dim3 g(32, 8);  k_transpose_w<<<g, 256, 0, stream>>>(Wk, wkvt, HID, NKV * HD); }
    { dim3 g(32, 8);  k_transpose_w<<<g, 256, 0, stream>>>(Wv, wkvt + (size_t)512 * HID, HID, NKV * HD); }
    { dim3 g(32, 32); k_transpose_w<<<g, 256, 0, stream>>>(Wo, wot, HID, HID); }

    { dim3 g(MTOT / 128, 3072 / 128);
      k_gemm_qkv<<<g, 256, 0, stream>>>(xb, wqt, qbuf, kv, cosp, sinp); }

    { dim3 g(S_LEN / 64, HD / 64, 16); k_transpose_v<<<g, 256, 0, stream>>>(kv, vtb); }
    { dim3 g(NQT / 2, 16, BATCH);      k_attn<<<g, 512, 0, stream>>>(qbuf, kv, vtb, aob); }

    { dim3 g(MTOT / 128, HID / 128);
      k_gemm<true><<<g, 256, 0, stream>>>(aob, wot, out, MTOT, HID, HID); }
}

// Round 9
// 357.808 us; speedup vs baseline: 1.2753x; 1.1007x over previous
//
#include <hip/hip_runtime.h>
#include <stdint.h>

#define S_LEN 2048
#define BATCH 4
#define HID   2048
#define HD    128
#define NKV   4
#define KVLD  1024          // combined K|V projection row stride (2*NKV*HD)
#define MTOT  (BATCH*S_LEN) // 8192
#define NQT2  (S_LEN/256)   // 8 q-tiles (256 rows) per (b,h)
#define QSCALE 0.08838834764831845f

typedef float    f32x4  __attribute__((ext_vector_type(4)));
typedef __bf16   bf16x8 __attribute__((ext_vector_type(8)));
typedef __bf16   bf16x4 __attribute__((ext_vector_type(4)));

// async global->LDS, 16B per lane. LDS dest = wave-uniform base + lane*16.
__device__ __forceinline__ void gld16(const void* g, void* l) {
    __builtin_amdgcn_global_load_lds(
        (const __attribute__((address_space(1))) void*)g,
        (__attribute__((address_space(3))) void*)l, 16, 0, 0);
}

// ---------------- fp32 -> bf16 bulk convert (8 elems/thread) ----------------
__global__ void k_conv_x(const float* __restrict__ in, __bf16* __restrict__ out) {
    int i = blockIdx.x * blockDim.x + threadIdx.x;
    f32x4 a = ((const f32x4*)in)[2 * i];
    f32x4 b = ((const f32x4*)in)[2 * i + 1];
    bf16x8 o;
    o[0] = (__bf16)a[0]; o[1] = (__bf16)a[1]; o[2] = (__bf16)a[2]; o[3] = (__bf16)a[3];
    o[4] = (__bf16)b[0]; o[5] = (__bf16)b[1]; o[6] = (__bf16)b[2]; o[7] = (__bf16)b[3];
    ((bf16x8*)out)[i] = o;
}

// ------------- W [K][N] fp32 -> Wt [N][K] bf16 (64x64 LDS tiles) ------------
__global__ void k_transpose_w(const float* __restrict__ in, __bf16* __restrict__ out,
                              int K, int N) {
    __shared__ float tile[64][65];
    int k0 = blockIdx.x * 64, n0 = blockIdx.y * 64;
    for (int e = threadIdx.x; e < 4096; e += 256) {
        int r = e >> 6, c = e & 63;
        tile[r][c] = in[(size_t)(k0 + r) * N + n0 + c];
    }
    __syncthreads();
    for (int e = threadIdx.x; e < 4096; e += 256) {
        int r = e >> 6, c = e & 63;
        out[(size_t)(n0 + r) * K + k0 + c] = (__bf16)tile[c][r];
    }
}

// -------- V slice of kvbuf [8192][1024] -> vt [16 planes][128 d][2048 s] ----
__global__ void k_transpose_v(const __bf16* __restrict__ kv, __bf16* __restrict__ vt) {
    __shared__ __bf16 tile[64][65];
    int plane = blockIdx.z;          // b*NKV + kvh
    int b = plane >> 2, kvh = plane & 3;
    int s0 = blockIdx.x * 64, d0 = blockIdx.y * 64;
    const __bf16* src = kv + (size_t)(b * S_LEN + s0) * KVLD + NKV * HD + kvh * HD + d0;
    for (int e = threadIdx.x; e < 4096; e += 256) {
        int r = e >> 6, c = e & 63;            // r: s offset, c: d offset
        tile[r][c] = src[(size_t)r * KVLD + c];
    }
    __syncthreads();
    __bf16* dst = vt + (size_t)plane * HD * S_LEN + (size_t)d0 * S_LEN + s0;
    for (int e = threadIdx.x; e < 4096; e += 256) {
        int r = e >> 6, c = e & 63;            // r: d offset, c: s offset
        dst[(size_t)r * S_LEN + c] = tile[c][r];
    }
}

// ---- merged QKV GEMM: C[8192][3072] = xb * [wqt|wkvt]^T, RoPE fused --------
// Compute: R5 structure (128x128 tile, BK=64, 4 waves, XOR-swizzled LDS).
// Epilogue: C-tile -> LDS (padded [128][132]) -> vectorized rope + stores.
__global__ __launch_bounds__(256) void k_gemm_qkv(const __bf16* __restrict__ A,
                                                  const __bf16* __restrict__ Bt,
                                                  __bf16* __restrict__ qbuf,
                                                  __bf16* __restrict__ kvbuf,
                                                  const float* __restrict__ cosp,
                                                  const float* __restrict__ sinp) {
    __shared__ __align__(16) char smem[33792];      // 128*132*2 epilogue / As+Bs
    __bf16* As = (__bf16*)smem;                     // [128*64]
    __bf16* Bs = (__bf16*)(smem + 16384);           // [128*64]
    const int tid = threadIdx.x, lane = tid & 63, wave = tid >> 6;
    const int wm = wave >> 1, wn = wave & 1;
    const int m0 = blockIdx.x * 128, n0 = blockIdx.y * 128;
    const int lo = lane & 15, hi = lane >> 4;
    f32x4 acc[4][4] = {};

    const int srow = wave * 8 + (lane >> 3); // staging row (+ r*32)
    const int sp   = lane & 7;               // physical 16B chunk

    for (int kt = 0; kt < HID; kt += 64) {
#pragma unroll
        for (int r = 0; r < 4; r++) {        // A tile
            int row = r * 32 + srow;
            int c = sp ^ (row & 7);
            gld16(A + (size_t)(m0 + row) * HID + kt + c * 8, &As[(r * 32 + wave * 8) * 64]);
        }
#pragma unroll
        for (int r = 0; r < 4; r++) {        // B tile
            int row = r * 32 + srow;
            int c = sp ^ (row & 7);
            gld16(Bt + (size_t)(n0 + row) * HID + kt + c * 8, &Bs[(r * 32 + wave * 8) * 64]);
        }
        __syncthreads();
#pragma unroll
        for (int ks = 0; ks < 2; ks++) {
            bf16x8 af[4], bfr[4];
#pragma unroll
            for (int mt = 0; mt < 4; mt++) {
                int row = wm * 64 + mt * 16 + lo;
                int pp = (ks * 4 + hi) ^ (row & 7);
                af[mt] = *(const bf16x8*)&As[row * 64 + pp * 8];
            }
#pragma unroll
            for (int nt = 0; nt < 4; nt++) {
                int row = wn * 64 + nt * 16 + lo;
                int pp = (ks * 4 + hi) ^ (row & 7);
                bfr[nt] = *(const bf16x8*)&Bs[row * 64 + pp * 8];
            }
#pragma unroll
            for (int mt = 0; mt < 4; mt++)
#pragma unroll
                for (int nt = 0; nt < 4; nt++)
                    acc[mt][nt] = __builtin_amdgcn_mfma_f32_16x16x32_bf16(
                        af[mt], bfr[nt], acc[mt][nt], 0, 0, 0);
        }
        __syncthreads();
    }

    // ---- epilogue: stage C (bf16) in LDS, then vectorized rope + stores ----
    __bf16* Cs = (__bf16*)smem;                     // [128][132]
#pragma unroll
    for (int mt = 0; mt < 4; mt++)
#pragma unroll
        for (int nt = 0; nt < 4; nt++) {
            int rl = wm * 64 + mt * 16 + hi * 4;
            int cl = wn * 64 + nt * 16 + lo;
#pragma unroll
            for (int r = 0; r < 4; r++)
                Cs[(rl + r) * 132 + cl] = (__bf16)acc[mt][nt][r];
        }
    __syncthreads();

    const int crow = tid >> 4;           // 0..15 (+16 per rep)
    const int cch  = tid & 15;           // 8-col chunk within the 128-col tile
    const int colg = n0 + cch * 8;
    const bool isQ = colg < 2048;
    const bool doRope = colg < 2560;     // q and k columns
    const int d0 = colg & (HD - 1);
#pragma unroll
    for (int rep = 0; rep < 8; rep++) {
        int row = rep * 16 + crow;
        int rowg = m0 + row;
        bf16x8 v = *(const bf16x8*)&Cs[row * 132 + cch * 8];
        float f[8];
#pragma unroll
        for (int j = 0; j < 8; j++) f[j] = (float)v[j];
        if (doRope) {
            int s = rowg & (S_LEN - 1);
            f32x4 c0 = *(const f32x4*)&cosp[s * HD + d0];
            f32x4 c1 = *(const f32x4*)&cosp[s * HD + d0 + 4];
            f32x4 s0 = *(const f32x4*)&sinp[s * HD + d0];
            f32x4 s1 = *(const f32x4*)&sinp[s * HD + d0 + 4];
            float cc[8] = {c0[0], c0[1], c0[2], c0[3], c1[0], c1[1], c1[2], c1[3]};
            float ss[8] = {s0[0], s0[1], s0[2], s0[3], s1[0], s1[1], s1[2], s1[3]};
#pragma unroll
            for (int p = 0; p < 4; p++) {
                float e0 = f[2 * p], e1 = f[2 * p + 1];
                f[2 * p]     = e0 * cc[2 * p]     - e1 * ss[2 * p];
                f[2 * p + 1] = e1 * cc[2 * p + 1] + e0 * ss[2 * p + 1];
            }
            if (isQ) {
#pragma unroll
                for (int j = 0; j < 8; j++) f[j] *= QSCALE;
            }
        }
        bf16x8 o;
#pragma unroll
        for (int j = 0; j < 8; j++) o[j] = (__bf16)f[j];
        if (isQ) *(bf16x8*)&qbuf[(size_t)rowg * HID + colg] = o;
        else     *(bf16x8*)&kvbuf[(size_t)rowg * KVLD + (colg - 2048)] = o;
    }
}

// --------------- GEMM: C[M][N] = A[M][K] * Bt[N][K]^T  (bf16 MFMA) ----------
// R5 structure, untouched (measured ~890 TF class for O-proj).
template <bool OUTF32>
__global__ __launch_bounds__(256) void k_gemm(const __bf16* __restrict__ A,
                                              const __bf16* __restrict__ Bt,
                                              void* __restrict__ Cp,
                                              int M, int N, int K) {
    (void)M;
    __shared__ __bf16 As[128 * 64];
    __shared__ __bf16 Bs[128 * 64];
    const int tid = threadIdx.x, lane = tid & 63, wave = tid >> 6;
    const int wm = wave >> 1, wn = wave & 1;
    const int m0 = blockIdx.x * 128, n0 = blockIdx.y * 128;
    const int lo = lane & 15, hi = lane >> 4;
    f32x4 acc[4][4] = {};

    const int srow = wave * 8 + (lane >> 3);
    const int sp   = lane & 7;

    for (int kt = 0; kt < K; kt += 64) {
#pragma unroll
        for (int r = 0; r < 4; r++) {
            int row = r * 32 + srow;
            int c = sp ^ (row & 7);
            gld16(A + (size_t)(m0 + row) * K + kt + c * 8, &As[(r * 32 + wave * 8) * 64]);
        }
#pragma unroll
        for (int r = 0; r < 4; r++) {
            int row = r * 32 + srow;
            int c = sp ^ (row & 7);
            gld16(Bt + (size_t)(n0 + row) * K + kt + c * 8, &Bs[(r * 32 + wave * 8) * 64]);
        }
        __syncthreads();
#pragma unroll
        for (int ks = 0; ks < 2; ks++) {
            bf16x8 af[4], bfr[4];
#pragma unroll
            for (int mt = 0; mt < 4; mt++) {
                int row = wm * 64 + mt * 16 + lo;
                int pp = (ks * 4 + hi) ^ (row & 7);
                af[mt] = *(const bf16x8*)&As[row * 64 + pp * 8];
            }
#pragma unroll
            for (int nt = 0; nt < 4; nt++) {
                int row = wn * 64 + nt * 16 + lo;
                int pp = (ks * 4 + hi) ^ (row & 7);
                bfr[nt] = *(const bf16x8*)&Bs[row * 64 + pp * 8];
            }
#pragma unroll
            for (int mt = 0; mt < 4; mt++)
#pragma unroll
                for (int nt = 0; nt < 4; nt++)
                    acc[mt][nt] = __builtin_amdgcn_mfma_f32_16x16x32_bf16(
                        af[mt], bfr[nt], acc[mt][nt], 0, 0, 0);
        }
        __syncthreads();
    }
#pragma unroll
    for (int mt = 0; mt < 4; mt++) {
#pragma unroll
        for (int nt = 0; nt < 4; nt++) {
            int row = m0 + wm * 64 + mt * 16 + hi * 4;
            int col = n0 + wn * 64 + nt * 16 + lo;
#pragma unroll
            for (int r = 0; r < 4; r++) {
                if (OUTF32)
                    ((float*)Cp)[(size_t)(row + r) * N + col] = acc[mt][nt][r];
                else
                    ((__bf16*)Cp)[(size_t)(row + r) * N + col] = (__bf16)acc[mt][nt][r];
            }
        }
    }
}

// ----------------------------- flash attention ------------------------------
// LDS-throughput-bound fix: each wave computes 32 q-rows (2 subtiles of 16),
// SHARING every K/V ds_read between both subtiles (read kf8/vv once -> 2 MFMA).
// QBLK=256, grid (4,16,4) = 256 blocks = exactly 1/CU, uniform 36 tiles/block.
// Swapped QK^T softmax (in-lane + 2 shfl); P via wave-private swizzled LDS.
// K,V double-buffered; ONE barrier per kv-tile.
// LDS: K 2x16K + V 2x16K + Ps 8x4K = 96 KB.
__global__ __launch_bounds__(512) void k_attn(const __bf16* __restrict__ qb,
                                              const __bf16* __restrict__ kb,
                                              const __bf16* __restrict__ vtb,
                                              __bf16* __restrict__ ob) {
    __shared__ __bf16 Ks[2][64 * 128];   // [kv][d], XOR-swizzled rows
    __shared__ __bf16 Vs[2][128 * 64];   // [d][kv], XOR-swizzled rows
    __shared__ __bf16 Ps[8][2048];       // wave-private: 2 subtiles x 16x64
    const int tid = threadIdx.x, lane = tid & 63, wave = tid >> 6;
    const int pair = blockIdx.x, h = blockIdx.y, b = blockIdx.z;
    const int kvh = h >> 2;
    const int lo = lane & 15, hi = lane >> 4;
    char* PsW = (char*)&Ps[wave][0];

    const __bf16* kbb = kb + kvh * HD + (size_t)b * S_LEN * KVLD;
    const __bf16* vbb = vtb + (size_t)(b * NKV + kvh) * HD * S_LEN;

    const int krow_s = wave * 4 + (lane >> 4);  // + r*32
    const int kp_s   = lane & 15;
    const int vrow_s = wave * 8 + (lane >> 3);  // + r*64
    const int vp_s   = lane & 7;

    auto STAGE_K = [&](int buf, int t) {
#pragma unroll
        for (int r = 0; r < 2; r++) {
            int row = r * 32 + krow_s;
            int c = kp_s ^ (row & 7);
            gld16(kbb + (size_t)(t * 64 + row) * KVLD + c * 8,
                  &Ks[buf][(r * 32 + wave * 4) * 128]);
        }
    };
    auto STAGE_V = [&](int buf, int t) {
#pragma unroll
        for (int r = 0; r < 2; r++) {
            int row = r * 64 + vrow_s;
            int c = vp_s ^ (row & 7);
            gld16(vbb + (size_t)row * S_LEN + t * 64 + c * 8,
                  &Vs[buf][(r * 64 + wave * 8) * 64]);
        }
    };

    // online softmax for one subtile (in-lane + 2 shfl; T13 defer-max thr=8)
    auto SM = [&](f32x4 (&sc)[4], float& Mr, float& Lr, f32x4 (&o)[8]) {
        float mloc = sc[0][0];
#pragma unroll
        for (int nt = 0; nt < 4; nt++)
#pragma unroll
            for (int r = 0; r < 4; r++) mloc = fmaxf(mloc, sc[nt][r]);
        mloc = fmaxf(mloc, __shfl_xor(mloc, 16, 64));
        mloc = fmaxf(mloc, __shfl_xor(mloc, 32, 64));
        float mn = (mloc <= Mr + 8.f) ? Mr : mloc;
        float sum = 0.f;
#pragma unroll
        for (int nt = 0; nt < 4; nt++)
#pragma unroll
            for (int r = 0; r < 4; r++) {
                float e = __expf(sc[nt][r] - mn);
                sc[nt][r] = e;
                sum += e;
            }
        sum += __shfl_xor(sum, 16, 64);
        sum += __shfl_xor(sum, 32, 64);
        if (mn != Mr) {
            float scl = __expf(Mr - mn);
            Lr = Lr * scl + sum;
            Mr = mn;
#pragma unroll
            for (int dt = 0; dt < 8; dt++) o[dt] *= scl;
        } else {
            Lr += sum;
        }
    };

#pragma unroll 1
    for (int pi = 0; pi < 2; pi++) {
        const int qt = pi ? (NQT2 - 1 - pair) : pair;  // 256-row q-tile index
        const int nkv = 4 * qt + 4;                    // kv tiles of 64 rows
        const int qbase = qt * 256 + wave * 32;        // this wave's 32 q-rows

        // Q fragments for both subtiles (q pre-scaled in GEMM epilogue)
        const __bf16* qptr0 = qb + (size_t)(b * S_LEN + qbase + lo) * HID + h * HD;
        const __bf16* qptr1 = qptr0 + (size_t)16 * HID;
        bf16x8 qa0[4], qa1[4];
#pragma unroll
        for (int kf = 0; kf < 4; kf++) {
            qa0[kf] = *(const bf16x8*)(qptr0 + kf * 32 + hi * 8);
            qa1[kf] = *(const bf16x8*)(qptr1 + kf * 32 + hi * 8);
        }

        f32x4 o0[8] = {}, o1[8] = {};    // O^T per subtile
        float Mr0 = -3e30f, Lr0 = 0.f, Mr1 = -3e30f, Lr1 = 0.f;

        int cur = 0;
        if (pi == 1) __syncthreads();    // protect K/V bufs from prior q-tile reads
        STAGE_K(0, 0);
        STAGE_V(0, 0);
        __syncthreads();

#pragma unroll 1
        for (int t = 0; t < nkv; t++) {
            if (t < nkv - 1) { STAGE_K(cur ^ 1, t + 1); STAGE_V(cur ^ 1, t + 1); }

            // S^T = K Q^T, both subtiles share every kf8 read
            f32x4 sc0[4], sc1[4];
            __builtin_amdgcn_s_setprio(1);
#pragma unroll
            for (int nt = 0; nt < 4; nt++) {
                f32x4 a = {0.f, 0.f, 0.f, 0.f}, bb = {0.f, 0.f, 0.f, 0.f};
#pragma unroll
                for (int kf = 0; kf < 4; kf++) {
                    int row = nt * 16 + lo;
                    int pp = (kf * 4 + hi) ^ (row & 7);
                    bf16x8 kf8 = *(const bf16x8*)&Ks[cur][row * 128 + pp * 8];
                    a  = __builtin_amdgcn_mfma_f32_16x16x32_bf16(kf8, qa0[kf], a, 0, 0, 0);
                    bb = __builtin_amdgcn_mfma_f32_16x16x32_bf16(kf8, qa1[kf], bb, 0, 0, 0);
                }
                sc0[nt] = a; sc1[nt] = bb;
            }
            __builtin_amdgcn_s_setprio(0);

            // causal mask (wave-uniform guard per subtile)
            if (t * 64 + 63 > qbase) {
                int qg = qbase + lo;
#pragma unroll
                for (int nt = 0; nt < 4; nt++)
#pragma unroll
                    for (int r = 0; r < 4; r++) {
                        int kg = t * 64 + nt * 16 + hi * 4 + r;
                        if (kg > qg) sc0[nt][r] = -1e30f;
                    }
            }
            if (t * 64 + 63 > qbase + 16) {
                int qg = qbase + 16 + lo;
#pragma unroll
                for (int nt = 0; nt < 4; nt++)
#pragma unroll
                    for (int r = 0; r < 4; r++) {
                        int kg = t * 64 + nt * 16 + hi * 4 + r;
                        if (kg > qg) sc1[nt][r] = -1e30f;
                    }
            }

            SM(sc0, Mr0, Lr0, o0);
            SM(sc1, Mr1, Lr1, o1);

            // P -> wave-private swizzled LDS (both subtiles), one lgkm drain
#pragma unroll
            for (int nt = 0; nt < 4; nt++) {
                bf16x4 p0, p1;
#pragma unroll
                for (int r = 0; r < 4; r++) { p0[r] = (__bf16)sc0[nt][r]; p1[r] = (__bf16)sc1[nt][r]; }
                int off = lo * 128 + ((nt * 32 + hi * 8) ^ ((lo & 7) << 4));
                *(bf16x4*)(PsW + off)        = p0;
                *(bf16x4*)(PsW + 2048 + off) = p1;
            }
            asm volatile("s_waitcnt lgkmcnt(0)" ::: "memory");
            bf16x8 pf0[2], pf1[2];
#pragma unroll
            for (int c = 0; c < 2; c++) {
                int off = lo * 128 + ((c * 64 + hi * 16) ^ ((lo & 7) << 4));
                pf0[c] = *(const bf16x8*)(PsW + off);
                pf1[c] = *(const bf16x8*)(PsW + 2048 + off);
            }
            // O^T += V^T P, both subtiles share every vv read
            __builtin_amdgcn_s_setprio(1);
#pragma unroll
            for (int dt = 0; dt < 8; dt++) {
                int rowd = dt * 16 + lo;
#pragma unroll
                for (int c = 0; c < 2; c++) {
                    int ch = c * 4 + hi;
                    bf16x8 vv = *(const bf16x8*)&Vs[cur][rowd * 64 + (ch ^ (rowd & 7)) * 8];
                    o0[dt] = __builtin_amdgcn_mfma_f32_16x16x32_bf16(vv, pf0[c], o0[dt], 0, 0, 0);
                    o1[dt] = __builtin_amdgcn_mfma_f32_16x16x32_bf16(vv, pf1[c], o1[dt], 0, 0, 0);
                }
            }
            __builtin_amdgcn_s_setprio(0);
            __syncthreads();  // drains prefetch; protects both bufs before reuse
            cur ^= 1;
        }

        // epilogue per subtile: O^T -> Ps -> coalesced bf16x8 stores
        const int qe = lane >> 2, c4 = lane & 3;
#pragma unroll
        for (int sub = 0; sub < 2; sub++) {
            float rl = 1.0f / (sub ? Lr1 : Lr0);
            char* Pp = PsW + sub * 2048;
#pragma unroll
            for (int h2 = 0; h2 < 2; h2++) {
#pragma unroll
                for (int dt4 = 0; dt4 < 4; dt4++) {
                    f32x4 ov = sub ? o1[h2 * 4 + dt4] : o0[h2 * 4 + dt4];
                    bf16x4 w;
#pragma unroll
                    for (int r = 0; r < 4; r++) w[r] = (__bf16)(ov[r] * rl);
                    *(bf16x4*)(Pp + lo * 128 + ((dt4 * 32 + hi * 8) ^ ((lo & 7) << 4))) = w;
                }
                asm volatile("s_waitcnt lgkmcnt(0)" ::: "memory");
                __builtin_amdgcn_sched_barrier(0);
#pragma unroll
                for (int s2 = 0; s2 < 2; s2++) {
                    int ch = c4 + s2 * 4;
                    bf16x8 v = *(const bf16x8*)(Pp + qe * 128 + ((ch * 16) ^ ((qe & 7) << 4)));
                    int qg = qbase + sub * 16 + qe;
                    int col = h * HD + h2 * 64 + ch * 8;
                    *(bf16x8*)&ob[(size_t)(b * S_LEN + qg) * HID + col] = v;
                }
            }
        }
    }
}

// ----------------------------------- host -----------------------------------
extern "C" void kernel_launch(void* const* d_in, const int* in_sizes, int n_in,
                              void* d_out, int out_size, void* d_ws, size_t ws_size,
                              hipStream_t stream) {
    (void)in_sizes; (void)n_in; (void)out_size; (void)ws_size;
    const float* x    = (const float*)d_in[0];
    const float* cosp = (const float*)d_in[1];
    const float* sinp = (const float*)d_in[2];
    const float* Wq   = (const float*)d_in[3];
    const float* Wk   = (const float*)d_in[4];
    const float* Wv   = (const float*)d_in[5];
    const float* Wo   = (const float*)d_in[6];
    float* out = (float*)d_out;

    char* ws = (char*)d_ws;
    __bf16* xb   = (__bf16*)(ws);                 // [8192][2048]        32 MB
    __bf16* wqt  = (__bf16*)(ws + 33554432);      // [2048][2048]         8 MB
    __bf16* wkvt = (__bf16*)(ws + 41943040);      // [1024][2048] (k|v)   4 MB  (contiguous with wqt -> [3072][2048])
    __bf16* wot  = (__bf16*)(ws + 46137344);      // [2048][2048]         8 MB
    __bf16* qbuf = (__bf16*)(ws + 54525952);      // [8192][2048]        32 MB
    __bf16* kv   = (__bf16*)(ws + 88080384);      // [8192][1024]        16 MB
    __bf16* vtb  = (__bf16*)(ws + 104857600);     // [16][128][2048]      8 MB
    __bf16* aob  = xb;                            // reuse xb after QKV GEMM

    k_conv_x<<<MTOT * HID / 8 / 256, 256, 0, stream>>>(x, xb);
    { dim3 g(32, 32); k_transpose_w<<<g, 256, 0, stream>>>(Wq, wqt, HID, HID); }
    { dim3 g(32, 8);  k_transpose_w<<<g, 256, 0, stream>>>(Wk, wkvt, HID, NKV * HD); }
    { dim3 g(32, 8);  k_transpose_w<<<g, 256, 0, stream>>>(Wv, wkvt + (size_t)512 * HID, HID, NKV * HD); }
    { dim3 g(32, 32); k_transpose_w<<<g, 256, 0, stream>>>(Wo, wot, HID, HID); }

    { dim3 g(MTOT / 128, 3072 / 128);
      k_gemm_qkv<<<g, 256, 0, stream>>>(xb, wqt, qbuf, kv, cosp, sinp); }

    { dim3 g(S_LEN / 64, HD / 64, 16); k_transpose_v<<<g, 256, 0, stream>>>(kv, vtb); }
    { dim3 g(NQT2 / 2, 16, BATCH);     k_attn<<<g, 512, 0, stream>>>(qbuf, kv, vtb, aob); }

    { dim3 g(MTOT / 128, HID / 128);
      k_gemm<true><<<g, 256, 0, stream>>>(aob, wot, out, MTOT, HID, HID); }
}

// Round 10
// 345.670 us; speedup vs baseline: 1.3201x; 1.0351x over previous
//
#include <hip/hip_runtime.h>
#include <stdint.h>

#define S_LEN 2048
#define BATCH 4
#define HID   2048
#define HD    128
#define NKV   4
#define MTOT  (BATCH*S_LEN) // 8192
#define NQT2  (S_LEN/256)   // 8 q-tiles (256 rows) per (b,h)
#define QSCALE 0.08838834764831845f

typedef float    f32x4  __attribute__((ext_vector_type(4)));
typedef __bf16   bf16x8 __attribute__((ext_vector_type(8)));
typedef __bf16   bf16x4 __attribute__((ext_vector_type(4)));
typedef unsigned u32x2  __attribute__((ext_vector_type(2)));

// async global->LDS, 16B per lane. LDS dest = wave-uniform base + lane*16.
__device__ __forceinline__ void gld16(const void* g, void* l) {
    __builtin_amdgcn_global_load_lds(
        (const __attribute__((address_space(1))) void*)g,
        (__attribute__((address_space(3))) void*)l, 16, 0, 0);
}

// ---------------- fp32 -> bf16 bulk convert (8 elems/thread) ----------------
__global__ void k_conv_x(const float* __restrict__ in, __bf16* __restrict__ out) {
    int i = blockIdx.x * blockDim.x + threadIdx.x;
    f32x4 a = ((const f32x4*)in)[2 * i];
    f32x4 b = ((const f32x4*)in)[2 * i + 1];
    bf16x8 o;
    o[0] = (__bf16)a[0]; o[1] = (__bf16)a[1]; o[2] = (__bf16)a[2]; o[3] = (__bf16)a[3];
    o[4] = (__bf16)b[0]; o[5] = (__bf16)b[1]; o[6] = (__bf16)b[2]; o[7] = (__bf16)b[3];
    ((bf16x8*)out)[i] = o;
}

// ------------- W [K][N] fp32 -> Wt [N][K] bf16 (64x64 LDS tiles) ------------
__global__ void k_transpose_w(const float* __restrict__ in, __bf16* __restrict__ out,
                              int K, int N) {
    __shared__ float tile[64][65];
    int k0 = blockIdx.x * 64, n0 = blockIdx.y * 64;
    for (int e = threadIdx.x; e < 4096; e += 256) {
        int r = e >> 6, c = e & 63;
        tile[r][c] = in[(size_t)(k0 + r) * N + n0 + c];
    }
    __syncthreads();
    for (int e = threadIdx.x; e < 4096; e += 256) {
        int r = e >> 6, c = e & 63;
        out[(size_t)(n0 + r) * K + k0 + c] = (__bf16)tile[c][r];
    }
}

// ---- merged QKV GEMM: C[8192][3072] = xb * [wqt|wkvt]^T -------------------
// Compute: m97 structure (128x128 tile, BK=64, 4 waves, XOR-swizzled LDS).
// Epilogue (per n0, block-uniform):
//   n0<2048   -> q: rope(f32) + QSCALE + fp8 pack -> qbuf8 [8192][2048] e4m3
//   <2560     -> k: rope(f32) + fp8 pack          -> kbuf8 [8192][512]  e4m3
//   else      -> v: TRANSPOSED LDS stage -> vtb [16 planes][128 d][2048 s] bf16
__global__ __launch_bounds__(256) void k_gemm_qkv(const __bf16* __restrict__ A,
                                                  const __bf16* __restrict__ Bt,
                                                  unsigned char* __restrict__ qb8,
                                                  unsigned char* __restrict__ kb8,
                                                  __bf16* __restrict__ vtb,
                                                  const float* __restrict__ cosp,
                                                  const float* __restrict__ sinp) {
    __shared__ __align__(16) char smem[33792];      // As+Bs / 128*132 bf16 epilogue
    __bf16* As = (__bf16*)smem;                     // [128*64]
    __bf16* Bs = (__bf16*)(smem + 16384);           // [128*64]
    const int tid = threadIdx.x, lane = tid & 63, wave = tid >> 6;
    const int wm = wave >> 1, wn = wave & 1;
    const int m0 = blockIdx.x * 128, n0 = blockIdx.y * 128;
    const int lo = lane & 15, hi = lane >> 4;
    f32x4 acc[4][4] = {};

    const int srow = wave * 8 + (lane >> 3); // staging row (+ r*32)
    const int sp   = lane & 7;               // physical 16B chunk

    for (int kt = 0; kt < HID; kt += 64) {
#pragma unroll
        for (int r = 0; r < 4; r++) {        // A tile
            int row = r * 32 + srow;
            int c = sp ^ (row & 7);
            gld16(A + (size_t)(m0 + row) * HID + kt + c * 8, &As[(r * 32 + wave * 8) * 64]);
        }
#pragma unroll
        for (int r = 0; r < 4; r++) {        // B tile
            int row = r * 32 + srow;
            int c = sp ^ (row & 7);
            gld16(Bt + (size_t)(n0 + row) * HID + kt + c * 8, &Bs[(r * 32 + wave * 8) * 64]);
        }
        __syncthreads();
#pragma unroll
        for (int ks = 0; ks < 2; ks++) {
            bf16x8 af[4], bfr[4];
#pragma unroll
            for (int mt = 0; mt < 4; mt++) {
                int row = wm * 64 + mt * 16 + lo;
                int pp = (ks * 4 + hi) ^ (row & 7);
                af[mt] = *(const bf16x8*)&As[row * 64 + pp * 8];
            }
#pragma unroll
            for (int nt = 0; nt < 4; nt++) {
                int row = wn * 64 + nt * 16 + lo;
                int pp = (ks * 4 + hi) ^ (row & 7);
                bfr[nt] = *(const bf16x8*)&Bs[row * 64 + pp * 8];
            }
#pragma unroll
            for (int mt = 0; mt < 4; mt++)
#pragma unroll
                for (int nt = 0; nt < 4; nt++)
                    acc[mt][nt] = __builtin_amdgcn_mfma_f32_16x16x32_bf16(
                        af[mt], bfr[nt], acc[mt][nt], 0, 0, 0);
        }
        __syncthreads();
    }

    if (n0 < 2560) {
        // ---- Q/K epilogue: row-major C stage -> rope -> fp8 pack -> store --
        __bf16* Cs = (__bf16*)smem;                 // [128][132]
#pragma unroll
        for (int mt = 0; mt < 4; mt++)
#pragma unroll
            for (int nt = 0; nt < 4; nt++) {
                int rl = wm * 64 + mt * 16 + hi * 4;
                int cl = wn * 64 + nt * 16 + lo;
#pragma unroll
                for (int r = 0; r < 4; r++)
                    Cs[(rl + r) * 132 + cl] = (__bf16)acc[mt][nt][r];
            }
        __syncthreads();

        const int crow = tid >> 4;           // 0..15 (+16 per rep)
        const int cch  = tid & 15;           // 8-col chunk
        const int colg = n0 + cch * 8;
        const bool isQ = n0 < 2048;
        const int d0 = colg & (HD - 1);
#pragma unroll
        for (int rep = 0; rep < 8; rep++) {
            int row = rep * 16 + crow;
            int rowg = m0 + row;
            bf16x8 v = *(const bf16x8*)&Cs[row * 132 + cch * 8];
            float f[8];
#pragma unroll
            for (int j = 0; j < 8; j++) f[j] = (float)v[j];
            {   // rope (q and k both)
                int s = rowg & (S_LEN - 1);
                f32x4 c0 = *(const f32x4*)&cosp[s * HD + d0];
                f32x4 c1 = *(const f32x4*)&cosp[s * HD + d0 + 4];
                f32x4 s0 = *(const f32x4*)&sinp[s * HD + d0];
                f32x4 s1 = *(const f32x4*)&sinp[s * HD + d0 + 4];
                float cc[8] = {c0[0], c0[1], c0[2], c0[3], c1[0], c1[1], c1[2], c1[3]};
                float ss[8] = {s0[0], s0[1], s0[2], s0[3], s1[0], s1[1], s1[2], s1[3]};
#pragma unroll
                for (int p = 0; p < 4; p++) {
                    float e0 = f[2 * p], e1 = f[2 * p + 1];
                    f[2 * p]     = e0 * cc[2 * p]     - e1 * ss[2 * p];
                    f[2 * p + 1] = e1 * cc[2 * p + 1] + e0 * ss[2 * p + 1];
                }
            }
            if (isQ) {
#pragma unroll
                for (int j = 0; j < 8; j++) f[j] *= QSCALE;
            }
            // pack 8 f32 -> 8 e4m3 bytes (2 u32)
            int u0 = __builtin_amdgcn_cvt_pk_fp8_f32(f[0], f[1], 0, false);
            u0     = __builtin_amdgcn_cvt_pk_fp8_f32(f[2], f[3], u0, true);
            int u1 = __builtin_amdgcn_cvt_pk_fp8_f32(f[4], f[5], 0, false);
            u1     = __builtin_amdgcn_cvt_pk_fp8_f32(f[6], f[7], u1, true);
            u32x2 pk; pk[0] = (unsigned)u0; pk[1] = (unsigned)u1;
            if (isQ) *(u32x2*)&qb8[(size_t)rowg * HID + colg] = pk;
            else     *(u32x2*)&kb8[(size_t)rowg * 512 + (colg - 2048)] = pk;
        }
    } else {
        // ---- V epilogue: TRANSPOSED stage CsT[col][row] -> vtb[d][s] -------
        __bf16* CsT = (__bf16*)smem;                // [128 cols][132 rows pad]
#pragma unroll
        for (int mt = 0; mt < 4; mt++)
#pragma unroll
            for (int nt = 0; nt < 4; nt++) {
                int cl = wn * 64 + nt * 16 + lo;
                int mrow = wm * 64 + mt * 16 + hi * 4;
                bf16x4 w;
#pragma unroll
                for (int r = 0; r < 4; r++) w[r] = (__bf16)acc[mt][nt][r];
                *(bf16x4*)&CsT[cl * 132 + mrow] = w;   // 8B, aligned (264|8, mrow*2|8)
            }
        __syncthreads();

        const int kvh = (n0 - 2560) >> 7;    // block covers exactly one kv head
        const int bb = m0 >> 11;             // batch
        const int s0 = m0 & (S_LEN - 1);
        __bf16* dst = vtb + (size_t)(bb * NKV + kvh) * HD * S_LEN;
        const int dloc = tid >> 4;           // 0..15 (+16 per rep)
        const int sch  = tid & 15;           // 8-elem s chunk
#pragma unroll
        for (int rep = 0; rep < 8; rep++) {
            int d = rep * 16 + dloc;
            bf16x8 v = *(const bf16x8*)&CsT[d * 132 + sch * 8];
            *(bf16x8*)&dst[(size_t)d * S_LEN + s0 + sch * 8] = v;
        }
    }
}

// --------------- GEMM: C[M][N] = A[M][K] * Bt[N][K]^T  (bf16 MFMA) ----------
// m97 structure, untouched (measured ~890 TF class for O-proj).
template <bool OUTF32>
__global__ __launch_bounds__(256) void k_gemm(const __bf16* __restrict__ A,
                                              const __bf16* __restrict__ Bt,
                                              void* __restrict__ Cp,
                                              int M, int N, int K) {
    (void)M;
    __shared__ __bf16 As[128 * 64];
    __shared__ __bf16 Bs[128 * 64];
    const int tid = threadIdx.x, lane = tid & 63, wave = tid >> 6;
    const int wm = wave >> 1, wn = wave & 1;
    const int m0 = blockIdx.x * 128, n0 = blockIdx.y * 128;
    const int lo = lane & 15, hi = lane >> 4;
    f32x4 acc[4][4] = {};

    const int srow = wave * 8 + (lane >> 3);
    const int sp   = lane & 7;

    for (int kt = 0; kt < K; kt += 64) {
#pragma unroll
        for (int r = 0; r < 4; r++) {
            int row = r * 32 + srow;
            int c = sp ^ (row & 7);
            gld16(A + (size_t)(m0 + row) * K + kt + c * 8, &As[(r * 32 + wave * 8) * 64]);
        }
#pragma unroll
        for (int r = 0; r < 4; r++) {
            int row = r * 32 + srow;
            int c = sp ^ (row & 7);
            gld16(Bt + (size_t)(n0 + row) * K + kt + c * 8, &Bs[(r * 32 + wave * 8) * 64]);
        }
        __syncthreads();
#pragma unroll
        for (int ks = 0; ks < 2; ks++) {
            bf16x8 af[4], bfr[4];
#pragma unroll
            for (int mt = 0; mt < 4; mt++) {
                int row = wm * 64 + mt * 16 + lo;
                int pp = (ks * 4 + hi) ^ (row & 7);
                af[mt] = *(const bf16x8*)&As[row * 64 + pp * 8];
            }
#pragma unroll
            for (int nt = 0; nt < 4; nt++) {
                int row = wn * 64 + nt * 16 + lo;
                int pp = (ks * 4 + hi) ^ (row & 7);
                bfr[nt] = *(const bf16x8*)&Bs[row * 64 + pp * 8];
            }
#pragma unroll
            for (int mt = 0; mt < 4; mt++)
#pragma unroll
                for (int nt = 0; nt < 4; nt++)
                    acc[mt][nt] = __builtin_amdgcn_mfma_f32_16x16x32_bf16(
                        af[mt], bfr[nt], acc[mt][nt], 0, 0, 0);
        }
        __syncthreads();
    }
#pragma unroll
    for (int mt = 0; mt < 4; mt++) {
#pragma unroll
        for (int nt = 0; nt < 4; nt++) {
            int row = m0 + wm * 64 + mt * 16 + hi * 4;
            int col = n0 + wn * 64 + nt * 16 + lo;
#pragma unroll
            for (int r = 0; r < 4; r++) {
                if (OUTF32)
                    ((float*)Cp)[(size_t)(row + r) * N + col] = acc[mt][nt][r];
                else
                    ((__bf16*)Cp)[(size_t)(row + r) * N + col] = (__bf16)acc[mt][nt][r];
            }
        }
    }
}

// ----------------------------- flash attention ------------------------------
// QK^T in FP8 e4m3 (Q,K quantized after f32 rope): K LDS tile 8 KB, b64 frag
// reads, 1 gld16/stage. PV stays bf16. Per wave: 32 q-rows (2 subtiles),
// every K/V LDS read shared across both subtiles. QBLK=256, grid 256 = 1/CU.
// LDS: Ks8 2x8K + Vs 2x16K + Ps 8x4K = 80 KB.
__global__ __launch_bounds__(512) void k_attn(const unsigned char* __restrict__ qb8,
                                              const unsigned char* __restrict__ kb8,
                                              const __bf16* __restrict__ vtb,
                                              __bf16* __restrict__ ob) {
    __shared__ char   Ks8[2][64 * 128];  // [kv][128B of fp8 d], XOR-swizzled
    __shared__ __bf16 Vs[2][128 * 64];   // [d][kv] bf16, XOR-swizzled
    __shared__ __bf16 Ps[8][2048];       // wave-private: 2 subtiles x 16x64
    const int tid = threadIdx.x, lane = tid & 63, wave = tid >> 6;
    const int pair = blockIdx.x, h = blockIdx.y, b = blockIdx.z;
    const int kvh = h >> 2;
    const int lo = lane & 15, hi = lane >> 4;
    char* PsW = (char*)&Ps[wave][0];

    const unsigned char* kbb = kb8 + (size_t)b * S_LEN * 512 + kvh * HD;
    const __bf16* vbb = vtb + (size_t)(b * NKV + kvh) * HD * S_LEN;

    const int krow_s = tid >> 3;                // 0..63
    const int kp_s   = tid & 7;
    const int vrow_s = wave * 8 + (lane >> 3);  // + r*64
    const int vp_s   = lane & 7;

    auto STAGE_K = [&](int buf, int t) {        // 8 KB: ONE gld16
        int c = kp_s ^ (krow_s & 7);
        gld16(kbb + (size_t)(t * 64 + krow_s) * 512 + c * 16,
              &Ks8[buf][wave * 1024]);
    };
    auto STAGE_V = [&](int buf, int t) {
#pragma unroll
        for (int r = 0; r < 2; r++) {
            int row = r * 64 + vrow_s;
            int c = vp_s ^ (row & 7);
            gld16(vbb + (size_t)row * S_LEN + t * 64 + c * 8,
                  &Vs[buf][(r * 64 + wave * 8) * 64]);
        }
    };

    // online softmax for one subtile (in-lane + 2 shfl; T13 defer-max thr=8)
    auto SM = [&](f32x4 (&sc)[4], float& Mr, float& Lr, f32x4 (&o)[8]) {
        float mloc = sc[0][0];
#pragma unroll
        for (int nt = 0; nt < 4; nt++)
#pragma unroll
            for (int r = 0; r < 4; r++) mloc = fmaxf(mloc, sc[nt][r]);
        mloc = fmaxf(mloc, __shfl_xor(mloc, 16, 64));
        mloc = fmaxf(mloc, __shfl_xor(mloc, 32, 64));
        float mn = (mloc <= Mr + 8.f) ? Mr : mloc;
        float sum = 0.f;
#pragma unroll
        for (int nt = 0; nt < 4; nt++)
#pragma unroll
            for (int r = 0; r < 4; r++) {
                float e = __expf(sc[nt][r] - mn);
                sc[nt][r] = e;
                sum += e;
            }
        sum += __shfl_xor(sum, 16, 64);
        sum += __shfl_xor(sum, 32, 64);
        if (mn != Mr) {
            float scl = __expf(Mr - mn);
            Lr = Lr * scl + sum;
            Mr = mn;
#pragma unroll
            for (int dt = 0; dt < 8; dt++) o[dt] *= scl;
        } else {
            Lr += sum;
        }
    };

#pragma unroll 1
    for (int pi = 0; pi < 2; pi++) {
        const int qt = pi ? (NQT2 - 1 - pair) : pair;  // 256-row q-tile index
        const int nkv = 4 * qt + 4;                    // kv tiles of 64 rows
        const int qbase = qt * 256 + wave * 32;        // this wave's 32 q-rows

        // Q fragments (fp8, 8B each) for both subtiles
        const unsigned char* qp0 = qb8 + (size_t)(b * S_LEN + qbase + lo) * HID + h * HD;
        const unsigned char* qp1 = qp0 + (size_t)16 * HID;
        long qa0[4], qa1[4];
#pragma unroll
        for (int kf = 0; kf < 4; kf++) {
            qa0[kf] = *(const long*)(qp0 + kf * 32 + hi * 8);
            qa1[kf] = *(const long*)(qp1 + kf * 32 + hi * 8);
        }

        f32x4 o0[8] = {}, o1[8] = {};    // O^T per subtile
        float Mr0 = -3e30f, Lr0 = 0.f, Mr1 = -3e30f, Lr1 = 0.f;

        int cur = 0;
        if (pi == 1) __syncthreads();    // protect K/V bufs from prior q-tile reads
        STAGE_K(0, 0);
        STAGE_V(0, 0);
        __syncthreads();

#pragma unroll 1
        for (int t = 0; t < nkv; t++) {
            if (t < nkv - 1) { STAGE_K(cur ^ 1, t + 1); STAGE_V(cur ^ 1, t + 1); }

            // S^T = K Q^T (fp8), both subtiles share every K frag read
            f32x4 sc0[4], sc1[4];
            __builtin_amdgcn_s_setprio(1);
#pragma unroll
            for (int nt = 0; nt < 4; nt++) {
                f32x4 a = {0.f, 0.f, 0.f, 0.f}, bb = {0.f, 0.f, 0.f, 0.f};
#pragma unroll
                for (int kf = 0; kf < 4; kf++) {
                    int row = nt * 16 + lo;
                    int lch = 2 * kf + (hi >> 1);          // logical 16B chunk
                    long kf8 = *(const long*)&Ks8[cur][row * 128 +
                                ((lch ^ (row & 7)) * 16) + (hi & 1) * 8];
                    a  = __builtin_amdgcn_mfma_f32_16x16x32_fp8_fp8(kf8, qa0[kf], a, 0, 0, 0);
                    bb = __builtin_amdgcn_mfma_f32_16x16x32_fp8_fp8(kf8, qa1[kf], bb, 0, 0, 0);
                }
                sc0[nt] = a; sc1[nt] = bb;
            }
            __builtin_amdgcn_s_setprio(0);

            // causal mask (wave-uniform guard per subtile)
            if (t * 64 + 63 > qbase) {
                int qg = qbase + lo;
#pragma unroll
                for (int nt = 0; nt < 4; nt++)
#pragma unroll
                    for (int r = 0; r < 4; r++) {
                        int kg = t * 64 + nt * 16 + hi * 4 + r;
                        if (kg > qg) sc0[nt][r] = -1e30f;
                    }
            }
            if (t * 64 + 63 > qbase + 16) {
                int qg = qbase + 16 + lo;
#pragma unroll
                for (int nt = 0; nt < 4; nt++)
#pragma unroll
                    for (int r = 0; r < 4; r++) {
                        int kg = t * 64 + nt * 16 + hi * 4 + r;
                        if (kg > qg) sc1[nt][r] = -1e30f;
                    }
            }

            SM(sc0, Mr0, Lr0, o0);
            SM(sc1, Mr1, Lr1, o1);

            // P (bf16) -> wave-private swizzled LDS, one lgkm drain
#pragma unroll
            for (int nt = 0; nt < 4; nt++) {
                bf16x4 p0, p1;
#pragma unroll
                for (int r = 0; r < 4; r++) { p0[r] = (__bf16)sc0[nt][r]; p1[r] = (__bf16)sc1[nt][r]; }
                int off = lo * 128 + ((nt * 32 + hi * 8) ^ ((lo & 7) << 4));
                *(bf16x4*)(PsW + off)        = p0;
                *(bf16x4*)(PsW + 2048 + off) = p1;
            }
            asm volatile("s_waitcnt lgkmcnt(0)" ::: "memory");
            bf16x8 pf0[2], pf1[2];
#pragma unroll
            for (int c = 0; c < 2; c++) {
                int off = lo * 128 + ((c * 64 + hi * 16) ^ ((lo & 7) << 4));
                pf0[c] = *(const bf16x8*)(PsW + off);
                pf1[c] = *(const bf16x8*)(PsW + 2048 + off);
            }
            // O^T += V^T P (bf16), both subtiles share every V read
            __builtin_amdgcn_s_setprio(1);
#pragma unroll
            for (int dt = 0; dt < 8; dt++) {
                int rowd = dt * 16 + lo;
#pragma unroll
                for (int c = 0; c < 2; c++) {
                    int ch = c * 4 + hi;
                    bf16x8 vv = *(const bf16x8*)&Vs[cur][rowd * 64 + (ch ^ (rowd & 7)) * 8];
                    o0[dt] = __builtin_amdgcn_mfma_f32_16x16x32_bf16(vv, pf0[c], o0[dt], 0, 0, 0);
                    o1[dt] = __builtin_amdgcn_mfma_f32_16x16x32_bf16(vv, pf1[c], o1[dt], 0, 0, 0);
                }
            }
            __builtin_amdgcn_s_setprio(0);
            __syncthreads();  // drains prefetch; protects both bufs before reuse
            cur ^= 1;
        }

        // epilogue per subtile: O^T -> Ps -> coalesced bf16x8 stores
        const int qe = lane >> 2, c4 = lane & 3;
#pragma unroll
        for (int sub = 0; sub < 2; sub++) {
            float rl = 1.0f / (sub ? Lr1 : Lr0);
            char* Pp = PsW + sub * 2048;
#pragma unroll
            for (int h2 = 0; h2 < 2; h2++) {
#pragma unroll
                for (int dt4 = 0; dt4 < 4; dt4++) {
                    f32x4 ov = sub ? o1[h2 * 4 + dt4] : o0[h2 * 4 + dt4];
                    bf16x4 w;
#pragma unroll
                    for (int r = 0; r < 4; r++) w[r] = (__bf16)(ov[r] * rl);
                    *(bf16x4*)(Pp + lo * 128 + ((dt4 * 32 + hi * 8) ^ ((lo & 7) << 4))) = w;
                }
                asm volatile("s_waitcnt lgkmcnt(0)" ::: "memory");
                __builtin_amdgcn_sched_barrier(0);
#pragma unroll
                for (int s2 = 0; s2 < 2; s2++) {
                    int ch = c4 + s2 * 4;
                    bf16x8 v = *(const bf16x8*)(Pp + qe * 128 + ((ch * 16) ^ ((qe & 7) << 4)));
                    int qg = qbase + sub * 16 + qe;
                    int col = h * HD + h2 * 64 + ch * 8;
                    *(bf16x8*)&ob[(size_t)(b * S_LEN + qg) * HID + col] = v;
                }
            }
        }
    }
}

// ----------------------------------- host -----------------------------------
extern "C" void kernel_launch(void* const* d_in, const int* in_sizes, int n_in,
                              void* d_out, int out_size, void* d_ws, size_t ws_size,
                              hipStream_t stream) {
    (void)in_sizes; (void)n_in; (void)out_size; (void)ws_size;
    const float* x    = (const float*)d_in[0];
    const float* cosp = (const float*)d_in[1];
    const float* sinp = (const float*)d_in[2];
    const float* Wq   = (const float*)d_in[3];
    const float* Wk   = (const float*)d_in[4];
    const float* Wv   = (const float*)d_in[5];
    const float* Wo   = (const float*)d_in[6];
    float* out = (float*)d_out;

    char* ws = (char*)d_ws;
    __bf16*        xb   = (__bf16*)(ws);               // [8192][2048] bf16  32 MB
    __bf16*        wqt  = (__bf16*)(ws + 33554432);    // [2048][2048]        8 MB
    __bf16*        wkvt = (__bf16*)(ws + 41943040);    // [1024][2048] (k|v)  4 MB (contig with wqt)
    __bf16*        wot  = (__bf16*)(ws + 46137344);    // [2048][2048]        8 MB
    unsigned char* qb8  = (unsigned char*)(ws + 54525952);  // [8192][2048] fp8 16 MB
    unsigned char* kb8  = (unsigned char*)(ws + 71303168);  // [8192][512]  fp8  4 MB
    __bf16*        vtb  = (__bf16*)(ws + 75497472);    // [16][128][2048] bf16 8 MB
    __bf16*        aob  = xb;                          // reuse xb after QKV GEMM

    k_conv_x<<<MTOT * HID / 8 / 256, 256, 0, stream>>>(x, xb);
    { dim3 g(32, 32); k_transpose_w<<<g, 256, 0, stream>>>(Wq, wqt, HID, HID); }
    { dim3 g(32, 8);  k_transpose_w<<<g, 256, 0, stream>>>(Wk, wkvt, HID, NKV * HD); }
    { dim3 g(32, 8);  k_transpose_w<<<g, 256, 0, stream>>>(Wv, wkvt + (size_t)512 * HID, HID, NKV * HD); }
    { dim3 g(32, 32); k_transpose_w<<<g, 256, 0, stream>>>(Wo, wot, HID, HID); }

    { dim3 g(MTOT / 128, 3072 / 128);
      k_gemm_qkv<<<g, 256, 0, stream>>>(xb, wqt, qb8, kb8, vtb, cosp, sinp); }

    { dim3 g(NQT2 / 2, 16, BATCH); k_attn<<<g, 512, 0, stream>>>(qb8, kb8, vtb, aob); }

    { dim3 g(MTOT / 128, HID / 128);
      k_gemm<true><<<g, 256, 0, stream>>>(aob, wot, out, MTOT, HID, HID); }
}

// Round 11
// 338.194 us; speedup vs baseline: 1.3492x; 1.0221x over previous
//
#include <hip/hip_runtime.h>
#include <stdint.h>

#define S_LEN 2048
#define BATCH 4
#define HID   2048
#define HD    128
#define NKV   4
#define MTOT  (BATCH*S_LEN) // 8192
#define NQT2  (S_LEN/256)   // 8 q-tiles (256 rows) per (b,h)
#define QSCALE 0.08838834764831845f

typedef float    f32x4  __attribute__((ext_vector_type(4)));
typedef __bf16   bf16x8 __attribute__((ext_vector_type(8)));
typedef __bf16   bf16x4 __attribute__((ext_vector_type(4)));
typedef unsigned u32x2  __attribute__((ext_vector_type(2)));

// async global->LDS, 16B per lane. LDS dest = wave-uniform base + lane*16.
__device__ __forceinline__ void gld16(const void* g, void* l) {
    __builtin_amdgcn_global_load_lds(
        (const __attribute__((address_space(1))) void*)g,
        (__attribute__((address_space(3))) void*)l, 16, 0, 0);
}

// ---------------- fp32 -> bf16 bulk convert (8 elems/thread) ----------------
__global__ void k_conv_x(const float* __restrict__ in, __bf16* __restrict__ out) {
    int i = blockIdx.x * blockDim.x + threadIdx.x;
    f32x4 a = ((const f32x4*)in)[2 * i];
    f32x4 b = ((const f32x4*)in)[2 * i + 1];
    bf16x8 o;
    o[0] = (__bf16)a[0]; o[1] = (__bf16)a[1]; o[2] = (__bf16)a[2]; o[3] = (__bf16)a[3];
    o[4] = (__bf16)b[0]; o[5] = (__bf16)b[1]; o[6] = (__bf16)b[2]; o[7] = (__bf16)b[3];
    ((bf16x8*)out)[i] = o;
}

// ---- ALL weight transposes in one launch: W [K][N] fp32 -> Wt [N][K] bf16 --
// z=0: Wq->wqt (N=2048), z=1: Wk->wkvt (512), z=2: Wv->wkvt+512*K (512),
// z=3: Wo->wot (2048). K=2048 for all.
__global__ void k_transpose_all(const float* __restrict__ Wq,
                                const float* __restrict__ Wk,
                                const float* __restrict__ Wv,
                                const float* __restrict__ Wo,
                                __bf16* __restrict__ wqt,
                                __bf16* __restrict__ wkvt,
                                __bf16* __restrict__ wot) {
    const int z = blockIdx.z;
    const float* in; __bf16* out; int N;
    if      (z == 0) { in = Wq; out = wqt;  N = 2048; }
    else if (z == 1) { in = Wk; out = wkvt; N = 512;  }
    else if (z == 2) { in = Wv; out = wkvt + (size_t)512 * HID; N = 512; }
    else             { in = Wo; out = wot;  N = 2048; }
    int k0 = blockIdx.x * 64, n0 = blockIdx.y * 64;
    if (n0 >= N) return;
    __shared__ float tile[64][65];
    for (int e = threadIdx.x; e < 4096; e += 256) {
        int r = e >> 6, c = e & 63;
        tile[r][c] = in[(size_t)(k0 + r) * N + n0 + c];
    }
    __syncthreads();
    for (int e = threadIdx.x; e < 4096; e += 256) {
        int r = e >> 6, c = e & 63;
        out[(size_t)(n0 + r) * HID + k0 + c] = (__bf16)tile[c][r];
    }
}

// ---- merged QKV GEMM: C[8192][3072] = xb * [wqt|wkvt]^T -------------------
// Compute: m97 structure (128x128 tile, BK=64, 4 waves, XOR-swizzled LDS).
// 1D grid 1536, T1 XCD swizzle: XCD k owns m-blocks [8k,8k+8) for all n ->
// 4MB A-panel stays L2-resident, staging loads L2-hit, barrier drain shortens.
// Epilogue (per n0, block-uniform):
//   n0<2048 -> q: rope(f32)+QSCALE+fp8 -> qb8; <2560 -> k: rope+fp8 -> kb8;
//   else    -> v: transposed LDS stage -> vtb [16 planes][128 d][2048 s] bf16.
__global__ __launch_bounds__(256) void k_gemm_qkv(const __bf16* __restrict__ A,
                                                  const __bf16* __restrict__ Bt,
                                                  unsigned char* __restrict__ qb8,
                                                  unsigned char* __restrict__ kb8,
                                                  __bf16* __restrict__ vtb,
                                                  const float* __restrict__ cosp,
                                                  const float* __restrict__ sinp) {
    __shared__ __align__(16) char smem[33792];      // As+Bs / 128*132 bf16 epilogue
    __bf16* As = (__bf16*)smem;                     // [128*64]
    __bf16* Bs = (__bf16*)(smem + 16384);           // [128*64]
    const int tid = threadIdx.x, lane = tid & 63, wave = tid >> 6;
    const int wm = wave >> 1, wn = wave & 1;
    // T1 swizzle: id -> (xcd, m-in-stripe, n)
    const int id = blockIdx.x;
    const int xcd = id & 7, g = id >> 3;            // g in [0,192)
    const int m0 = (xcd * 8 + (g & 7)) * 128;
    const int n0 = (g >> 3) * 128;
    const int lo = lane & 15, hi = lane >> 4;
    f32x4 acc[4][4] = {};

    const int srow = wave * 8 + (lane >> 3); // staging row (+ r*32)
    const int sp   = lane & 7;               // physical 16B chunk

    for (int kt = 0; kt < HID; kt += 64) {
#pragma unroll
        for (int r = 0; r < 4; r++) {        // A tile
            int row = r * 32 + srow;
            int c = sp ^ (row & 7);
            gld16(A + (size_t)(m0 + row) * HID + kt + c * 8, &As[(r * 32 + wave * 8) * 64]);
        }
#pragma unroll
        for (int r = 0; r < 4; r++) {        // B tile
            int row = r * 32 + srow;
            int c = sp ^ (row & 7);
            gld16(Bt + (size_t)(n0 + row) * HID + kt + c * 8, &Bs[(r * 32 + wave * 8) * 64]);
        }
        __syncthreads();
#pragma unroll
        for (int ks = 0; ks < 2; ks++) {
            bf16x8 af[4], bfr[4];
#pragma unroll
            for (int mt = 0; mt < 4; mt++) {
                int row = wm * 64 + mt * 16 + lo;
                int pp = (ks * 4 + hi) ^ (row & 7);
                af[mt] = *(const bf16x8*)&As[row * 64 + pp * 8];
            }
#pragma unroll
            for (int nt = 0; nt < 4; nt++) {
                int row = wn * 64 + nt * 16 + lo;
                int pp = (ks * 4 + hi) ^ (row & 7);
                bfr[nt] = *(const bf16x8*)&Bs[row * 64 + pp * 8];
            }
#pragma unroll
            for (int mt = 0; mt < 4; mt++)
#pragma unroll
                for (int nt = 0; nt < 4; nt++)
                    acc[mt][nt] = __builtin_amdgcn_mfma_f32_16x16x32_bf16(
                        af[mt], bfr[nt], acc[mt][nt], 0, 0, 0);
        }
        __syncthreads();
    }

    if (n0 < 2560) {
        // ---- Q/K epilogue: row-major C stage -> rope -> fp8 pack -> store --
        __bf16* Cs = (__bf16*)smem;                 // [128][132]
#pragma unroll
        for (int mt = 0; mt < 4; mt++)
#pragma unroll
            for (int nt = 0; nt < 4; nt++) {
                int rl = wm * 64 + mt * 16 + hi * 4;
                int cl = wn * 64 + nt * 16 + lo;
#pragma unroll
                for (int r = 0; r < 4; r++)
                    Cs[(rl + r) * 132 + cl] = (__bf16)acc[mt][nt][r];
            }
        __syncthreads();

        const int crow = tid >> 4;           // 0..15 (+16 per rep)
        const int cch  = tid & 15;           // 8-col chunk
        const int colg = n0 + cch * 8;
        const bool isQ = n0 < 2048;
        const int d0 = colg & (HD - 1);
#pragma unroll
        for (int rep = 0; rep < 8; rep++) {
            int row = rep * 16 + crow;
            int rowg = m0 + row;
            bf16x8 v = *(const bf16x8*)&Cs[row * 132 + cch * 8];
            float f[8];
#pragma unroll
            for (int j = 0; j < 8; j++) f[j] = (float)v[j];
            {   // rope (q and k both)
                int s = rowg & (S_LEN - 1);
                f32x4 c0 = *(const f32x4*)&cosp[s * HD + d0];
                f32x4 c1 = *(const f32x4*)&cosp[s * HD + d0 + 4];
                f32x4 s0 = *(const f32x4*)&sinp[s * HD + d0];
                f32x4 s1 = *(const f32x4*)&sinp[s * HD + d0 + 4];
                float cc[8] = {c0[0], c0[1], c0[2], c0[3], c1[0], c1[1], c1[2], c1[3]};
                float ss[8] = {s0[0], s0[1], s0[2], s0[3], s1[0], s1[1], s1[2], s1[3]};
#pragma unroll
                for (int p = 0; p < 4; p++) {
                    float e0 = f[2 * p], e1 = f[2 * p + 1];
                    f[2 * p]     = e0 * cc[2 * p]     - e1 * ss[2 * p];
                    f[2 * p + 1] = e1 * cc[2 * p + 1] + e0 * ss[2 * p + 1];
                }
            }
            if (isQ) {
#pragma unroll
                for (int j = 0; j < 8; j++) f[j] *= QSCALE;
            }
            // pack 8 f32 -> 8 e4m3 bytes (2 u32)
            int u0 = __builtin_amdgcn_cvt_pk_fp8_f32(f[0], f[1], 0, false);
            u0     = __builtin_amdgcn_cvt_pk_fp8_f32(f[2], f[3], u0, true);
            int u1 = __builtin_amdgcn_cvt_pk_fp8_f32(f[4], f[5], 0, false);
            u1     = __builtin_amdgcn_cvt_pk_fp8_f32(f[6], f[7], u1, true);
            u32x2 pk; pk[0] = (unsigned)u0; pk[1] = (unsigned)u1;
            if (isQ) *(u32x2*)&qb8[(size_t)rowg * HID + colg] = pk;
            else     *(u32x2*)&kb8[(size_t)rowg * 512 + (colg - 2048)] = pk;
        }
    } else {
        // ---- V epilogue: TRANSPOSED stage CsT[col][row] -> vtb[d][s] -------
        __bf16* CsT = (__bf16*)smem;                // [128 cols][132 rows pad]
#pragma unroll
        for (int mt = 0; mt < 4; mt++)
#pragma unroll
            for (int nt = 0; nt < 4; nt++) {
                int cl = wn * 64 + nt * 16 + lo;
                int mrow = wm * 64 + mt * 16 + hi * 4;
                bf16x4 w;
#pragma unroll
                for (int r = 0; r < 4; r++) w[r] = (__bf16)acc[mt][nt][r];
                *(bf16x4*)&CsT[cl * 132 + mrow] = w;
            }
        __syncthreads();

        const int kvh = (n0 - 2560) >> 7;    // block covers exactly one kv head
        const int bb = m0 >> 11;             // batch
        const int s0 = m0 & (S_LEN - 1);
        __bf16* dst = vtb + (size_t)(bb * NKV + kvh) * HD * S_LEN;
        const int dloc = tid >> 4;           // 0..15 (+16 per rep)
        const int sch  = tid & 15;           // 8-elem s chunk
#pragma unroll
        for (int rep = 0; rep < 8; rep++) {
            int d = rep * 16 + dloc;
            bf16x8 v = *(const bf16x8*)&CsT[d * 132 + sch * 8];
            *(bf16x8*)&dst[(size_t)d * S_LEN + s0 + sch * 8] = v;
        }
    }
}

// --------------- O-proj GEMM: C[M][2048] f32 = A * Wot^T  (bf16 MFMA) -------
// m97 structure + T1 XCD swizzle (1D grid 1024: XCD k owns m-blocks [8k,8k+8)).
__global__ __launch_bounds__(256) void k_gemm_o(const __bf16* __restrict__ A,
                                                const __bf16* __restrict__ Bt,
                                                float* __restrict__ Cp) {
    __shared__ __bf16 As[128 * 64];
    __shared__ __bf16 Bs[128 * 64];
    const int tid = threadIdx.x, lane = tid & 63, wave = tid >> 6;
    const int wm = wave >> 1, wn = wave & 1;
    const int id = blockIdx.x;
    const int xcd = id & 7, g = id >> 3;            // g in [0,128)
    const int m0 = (xcd * 8 + (g & 7)) * 128;
    const int n0 = (g >> 3) * 128;
    const int lo = lane & 15, hi = lane >> 4;
    f32x4 acc[4][4] = {};

    const int srow = wave * 8 + (lane >> 3);
    const int sp   = lane & 7;

    for (int kt = 0; kt < HID; kt += 64) {
#pragma unroll
        for (int r = 0; r < 4; r++) {
            int row = r * 32 + srow;
            int c = sp ^ (row & 7);
            gld16(A + (size_t)(m0 + row) * HID + kt + c * 8, &As[(r * 32 + wave * 8) * 64]);
        }
#pragma unroll
        for (int r = 0; r < 4; r++) {
            int row = r * 32 + srow;
            int c = sp ^ (row & 7);
            gld16(Bt + (size_t)(n0 + row) * HID + kt + c * 8, &Bs[(r * 32 + wave * 8) * 64]);
        }
        __syncthreads();
#pragma unroll
        for (int ks = 0; ks < 2; ks++) {
            bf16x8 af[4], bfr[4];
#pragma unroll
            for (int mt = 0; mt < 4; mt++) {
                int row = wm * 64 + mt * 16 + lo;
                int pp = (ks * 4 + hi) ^ (row & 7);
                af[mt] = *(const bf16x8*)&As[row * 64 + pp * 8];
            }
#pragma unroll
            for (int nt = 0; nt < 4; nt++) {
                int row = wn * 64 + nt * 16 + lo;
                int pp = (ks * 4 + hi) ^ (row & 7);
                bfr[nt] = *(const bf16x8*)&Bs[row * 64 + pp * 8];
            }
#pragma unroll
            for (int mt = 0; mt < 4; mt++)
#pragma unroll
                for (int nt = 0; nt < 4; nt++)
                    acc[mt][nt] = __builtin_amdgcn_mfma_f32_16x16x32_bf16(
                        af[mt], bfr[nt], acc[mt][nt], 0, 0, 0);
        }
        __syncthreads();
    }
#pragma unroll
    for (int mt = 0; mt < 4; mt++) {
#pragma unroll
        for (int nt = 0; nt < 4; nt++) {
            int row = m0 + wm * 64 + mt * 16 + hi * 4;
            int col = n0 + wn * 64 + nt * 16 + lo;
#pragma unroll
            for (int r = 0; r < 4; r++)
                Cp[(size_t)(row + r) * HID + col] = acc[mt][nt][r];
        }
    }
}

// ----------------------------- flash attention ------------------------------
// QK^T in FP8 e4m3 (Q,K quantized after f32 rope): K LDS tile 8 KB, b64 frag
// reads, 1 gld16/stage. PV stays bf16. Per wave: 32 q-rows (2 subtiles),
// every K/V LDS read shared across both subtiles. QBLK=256, grid 256 = 1/CU.
// LDS: Ks8 2x8K + Vs 2x16K + Ps 8x4K = 80 KB.
__global__ __launch_bounds__(512) void k_attn(const unsigned char* __restrict__ qb8,
                                              const unsigned char* __restrict__ kb8,
                                              const __bf16* __restrict__ vtb,
                                              __bf16* __restrict__ ob) {
    __shared__ char   Ks8[2][64 * 128];  // [kv][128B of fp8 d], XOR-swizzled
    __shared__ __bf16 Vs[2][128 * 64];   // [d][kv] bf16, XOR-swizzled
    __shared__ __bf16 Ps[8][2048];       // wave-private: 2 subtiles x 16x64
    const int tid = threadIdx.x, lane = tid & 63, wave = tid >> 6;
    const int pair = blockIdx.x, h = blockIdx.y, b = blockIdx.z;
    const int kvh = h >> 2;
    const int lo = lane & 15, hi = lane >> 4;
    char* PsW = (char*)&Ps[wave][0];

    const unsigned char* kbb = kb8 + (size_t)b * S_LEN * 512 + kvh * HD;
    const __bf16* vbb = vtb + (size_t)(b * NKV + kvh) * HD * S_LEN;

    const int krow_s = tid >> 3;                // 0..63
    const int kp_s   = tid & 7;
    const int vrow_s = wave * 8 + (lane >> 3);  // + r*64
    const int vp_s   = lane & 7;

    auto STAGE_K = [&](int buf, int t) {        // 8 KB: ONE gld16
        int c = kp_s ^ (krow_s & 7);
        gld16(kbb + (size_t)(t * 64 + krow_s) * 512 + c * 16,
              &Ks8[buf][wave * 1024]);
    };
    auto STAGE_V = [&](int buf, int t) {
#pragma unroll
        for (int r = 0; r < 2; r++) {
            int row = r * 64 + vrow_s;
            int c = vp_s ^ (row & 7);
            gld16(vbb + (size_t)row * S_LEN + t * 64 + c * 8,
                  &Vs[buf][(r * 64 + wave * 8) * 64]);
        }
    };

    // online softmax for one subtile (in-lane + 2 shfl; T13 defer-max thr=8)
    auto SM = [&](f32x4 (&sc)[4], float& Mr, float& Lr, f32x4 (&o)[8]) {
        float mloc = sc[0][0];
#pragma unroll
        for (int nt = 0; nt < 4; nt++)
#pragma unroll
            for (int r = 0; r < 4; r++) mloc = fmaxf(mloc, sc[nt][r]);
        mloc = fmaxf(mloc, __shfl_xor(mloc, 16, 64));
        mloc = fmaxf(mloc, __shfl_xor(mloc, 32, 64));
        float mn = (mloc <= Mr + 8.f) ? Mr : mloc;
        float sum = 0.f;
#pragma unroll
        for (int nt = 0; nt < 4; nt++)
#pragma unroll
            for (int r = 0; r < 4; r++) {
                float e = __expf(sc[nt][r] - mn);
                sc[nt][r] = e;
                sum += e;
            }
        sum += __shfl_xor(sum, 16, 64);
        sum += __shfl_xor(sum, 32, 64);
        if (mn != Mr) {
            float scl = __expf(Mr - mn);
            Lr = Lr * scl + sum;
            Mr = mn;
#pragma unroll
            for (int dt = 0; dt < 8; dt++) o[dt] *= scl;
        } else {
            Lr += sum;
        }
    };

#pragma unroll 1
    for (int pi = 0; pi < 2; pi++) {
        const int qt = pi ? (NQT2 - 1 - pair) : pair;  // 256-row q-tile index
        const int nkv = 4 * qt + 4;                    // kv tiles of 64 rows
        const int qbase = qt * 256 + wave * 32;        // this wave's 32 q-rows

        // Q fragments (fp8, 8B each) for both subtiles
        const unsigned char* qp0 = qb8 + (size_t)(b * S_LEN + qbase + lo) * HID + h * HD;
        const unsigned char* qp1 = qp0 + (size_t)16 * HID;
        long qa0[4], qa1[4];
#pragma unroll
        for (int kf = 0; kf < 4; kf++) {
            qa0[kf] = *(const long*)(qp0 + kf * 32 + hi * 8);
            qa1[kf] = *(const long*)(qp1 + kf * 32 + hi * 8);
        }

        f32x4 o0[8] = {}, o1[8] = {};    // O^T per subtile
        float Mr0 = -3e30f, Lr0 = 0.f, Mr1 = -3e30f, Lr1 = 0.f;

        int cur = 0;
        if (pi == 1) __syncthreads();    // protect K/V bufs from prior q-tile reads
        STAGE_K(0, 0);
        STAGE_V(0, 0);
        __syncthreads();

#pragma unroll 1
        for (int t = 0; t < nkv; t++) {
            if (t < nkv - 1) { STAGE_K(cur ^ 1, t + 1); STAGE_V(cur ^ 1, t + 1); }

            // S^T = K Q^T (fp8), both subtiles share every K frag read
            f32x4 sc0[4], sc1[4];
            __builtin_amdgcn_s_setprio(1);
#pragma unroll
            for (int nt = 0; nt < 4; nt++) {
                f32x4 a = {0.f, 0.f, 0.f, 0.f}, bb = {0.f, 0.f, 0.f, 0.f};
#pragma unroll
                for (int kf = 0; kf < 4; kf++) {
                    int row = nt * 16 + lo;
                    int lch = 2 * kf + (hi >> 1);          // logical 16B chunk
                    long kf8 = *(const long*)&Ks8[cur][row * 128 +
                                ((lch ^ (row & 7)) * 16) + (hi & 1) * 8];
                    a  = __builtin_amdgcn_mfma_f32_16x16x32_fp8_fp8(kf8, qa0[kf], a, 0, 0, 0);
                    bb = __builtin_amdgcn_mfma_f32_16x16x32_fp8_fp8(kf8, qa1[kf], bb, 0, 0, 0);
                }
                sc0[nt] = a; sc1[nt] = bb;
            }
            __builtin_amdgcn_s_setprio(0);

            // causal mask (wave-uniform guard per subtile)
            if (t * 64 + 63 > qbase) {
                int qg = qbase + lo;
#pragma unroll
                for (int nt = 0; nt < 4; nt++)
#pragma unroll
                    for (int r = 0; r < 4; r++) {
                        int kg = t * 64 + nt * 16 + hi * 4 + r;
                        if (kg > qg) sc0[nt][r] = -1e30f;
                    }
            }
            if (t * 64 + 63 > qbase + 16) {
                int qg = qbase + 16 + lo;
#pragma unroll
                for (int nt = 0; nt < 4; nt++)
#pragma unroll
                    for (int r = 0; r < 4; r++) {
                        int kg = t * 64 + nt * 16 + hi * 4 + r;
                        if (kg > qg) sc1[nt][r] = -1e30f;
                    }
            }

            SM(sc0, Mr0, Lr0, o0);
            SM(sc1, Mr1, Lr1, o1);

            // P (bf16) -> wave-private swizzled LDS, one lgkm drain
#pragma unroll
            for (int nt = 0; nt < 4; nt++) {
                bf16x4 p0, p1;
#pragma unroll
                for (int r = 0; r < 4; r++) { p0[r] = (__bf16)sc0[nt][r]; p1[r] = (__bf16)sc1[nt][r]; }
                int off = lo * 128 + ((nt * 32 + hi * 8) ^ ((lo & 7) << 4));
                *(bf16x4*)(PsW + off)        = p0;
                *(bf16x4*)(PsW + 2048 + off) = p1;
            }
            asm volatile("s_waitcnt lgkmcnt(0)" ::: "memory");
            bf16x8 pf0[2], pf1[2];
#pragma unroll
            for (int c = 0; c < 2; c++) {
                int off = lo * 128 + ((c * 64 + hi * 16) ^ ((lo & 7) << 4));
                pf0[c] = *(const bf16x8*)(PsW + off);
                pf1[c] = *(const bf16x8*)(PsW + 2048 + off);
            }
            // O^T += V^T P (bf16), both subtiles share every V read
            __builtin_amdgcn_s_setprio(1);
#pragma unroll
            for (int dt = 0; dt < 8; dt++) {
                int rowd = dt * 16 + lo;
#pragma unroll
                for (int c = 0; c < 2; c++) {
                    int ch = c * 4 + hi;
                    bf16x8 vv = *(const bf16x8*)&Vs[cur][rowd * 64 + (ch ^ (rowd & 7)) * 8];
                    o0[dt] = __builtin_amdgcn_mfma_f32_16x16x32_bf16(vv, pf0[c], o0[dt], 0, 0, 0);
                    o1[dt] = __builtin_amdgcn_mfma_f32_16x16x32_bf16(vv, pf1[c], o1[dt], 0, 0, 0);
                }
            }
            __builtin_amdgcn_s_setprio(0);
            __syncthreads();  // drains prefetch; protects both bufs before reuse
            cur ^= 1;
        }

        // epilogue per subtile: O^T -> Ps -> coalesced bf16x8 stores
        const int qe = lane >> 2, c4 = lane & 3;
#pragma unroll
        for (int sub = 0; sub < 2; sub++) {
            float rl = 1.0f / (sub ? Lr1 : Lr0);
            char* Pp = PsW + sub * 2048;
#pragma unroll
            for (int h2 = 0; h2 < 2; h2++) {
#pragma unroll
                for (int dt4 = 0; dt4 < 4; dt4++) {
                    f32x4 ov = sub ? o1[h2 * 4 + dt4] : o0[h2 * 4 + dt4];
                    bf16x4 w;
#pragma unroll
                    for (int r = 0; r < 4; r++) w[r] = (__bf16)(ov[r] * rl);
                    *(bf16x4*)(Pp + lo * 128 + ((dt4 * 32 + hi * 8) ^ ((lo & 7) << 4))) = w;
                }
                asm volatile("s_waitcnt lgkmcnt(0)" ::: "memory");
                __builtin_amdgcn_sched_barrier(0);
#pragma unroll
                for (int s2 = 0; s2 < 2; s2++) {
                    int ch = c4 + s2 * 4;
                    bf16x8 v = *(const bf16x8*)(Pp + qe * 128 + ((ch * 16) ^ ((qe & 7) << 4)));
                    int qg = qbase + sub * 16 + qe;
                    int col = h * HD + h2 * 64 + ch * 8;
                    *(bf16x8*)&ob[(size_t)(b * S_LEN + qg) * HID + col] = v;
                }
            }
        }
    }
}

// ----------------------------------- host -----------------------------------
extern "C" void kernel_launch(void* const* d_in, const int* in_sizes, int n_in,
                              void* d_out, int out_size, void* d_ws, size_t ws_size,
                              hipStream_t stream) {
    (void)in_sizes; (void)n_in; (void)out_size; (void)ws_size;
    const float* x    = (const float*)d_in[0];
    const float* cosp = (const float*)d_in[1];
    const float* sinp = (const float*)d_in[2];
    const float* Wq   = (const float*)d_in[3];
    const float* Wk   = (const float*)d_in[4];
    const float* Wv   = (const float*)d_in[5];
    const float* Wo   = (const float*)d_in[6];
    float* out = (float*)d_out;

    char* ws = (char*)d_ws;
    __bf16*        xb   = (__bf16*)(ws);               // [8192][2048] bf16  32 MB
    __bf16*        wqt  = (__bf16*)(ws + 33554432);    // [2048][2048]        8 MB
    __bf16*        wkvt = (__bf16*)(ws + 41943040);    // [1024][2048] (k|v)  4 MB (contig with wqt)
    __bf16*        wot  = (__bf16*)(ws + 46137344);    // [2048][2048]        8 MB
    unsigned char* qb8  = (unsigned char*)(ws + 54525952);  // [8192][2048] fp8 16 MB
    unsigned char* kb8  = (unsigned char*)(ws + 71303168);  // [8192][512]  fp8  4 MB
    __bf16*        vtb  = (__bf16*)(ws + 75497472);    // [16][128][2048] bf16 8 MB
    __bf16*        aob  = xb;                          // reuse xb after QKV GEMM

    k_conv_x<<<MTOT * HID / 8 / 256, 256, 0, stream>>>(x, xb);
    { dim3 g(32, 32, 4);
      k_transpose_all<<<g, 256, 0, stream>>>(Wq, Wk, Wv, Wo, wqt, wkvt, wot); }

    k_gemm_qkv<<<1536, 256, 0, stream>>>(xb, wqt, qb8, kb8, vtb, cosp, sinp);

    { dim3 g(NQT2 / 2, 16, BATCH); k_attn<<<g, 512, 0, stream>>>(qb8, kb8, vtb, aob); }

    k_gemm_o<<<1024, 256, 0, stream>>>(aob, wot, out);
}

// Round 13
// 327.341 us; speedup vs baseline: 1.3940x; 1.0332x over previous
//
#include <hip/hip_runtime.h>
#include <stdint.h>

#define S_LEN 2048
#define BATCH 4
#define HID   2048
#define HD    128
#define NKV   4
#define MTOT  (BATCH*S_LEN) // 8192
#define NQT2  (S_LEN/256)   // 8 q-tiles (256 rows) per (b,h)
#define QSCALE 0.08838834764831845f

typedef float    f32x4  __attribute__((ext_vector_type(4)));
typedef __bf16   bf16x8 __attribute__((ext_vector_type(8)));
typedef __bf16   bf16x4 __attribute__((ext_vector_type(4)));
typedef unsigned u32x2  __attribute__((ext_vector_type(2)));

// async global->LDS, 16B per lane. LDS dest = wave-uniform base + lane*16.
__device__ __forceinline__ void gld16(const void* g, void* l) {
    __builtin_amdgcn_global_load_lds(
        (const __attribute__((address_space(1))) void*)g,
        (__attribute__((address_space(3))) void*)l, 16, 0, 0);
}

// ---------------- fp32 -> bf16 bulk convert (8 elems/thread) ----------------
__global__ void k_conv_x(const float* __restrict__ in, __bf16* __restrict__ out) {
    int i = blockIdx.x * blockDim.x + threadIdx.x;
    f32x4 a = ((const f32x4*)in)[2 * i];
    f32x4 b = ((const f32x4*)in)[2 * i + 1];
    bf16x8 o;
    o[0] = (__bf16)a[0]; o[1] = (__bf16)a[1]; o[2] = (__bf16)a[2]; o[3] = (__bf16)a[3];
    o[4] = (__bf16)b[0]; o[5] = (__bf16)b[1]; o[6] = (__bf16)b[2]; o[7] = (__bf16)b[3];
    ((bf16x8*)out)[i] = o;
}

// ---- ALL weight transposes in one launch: W [K][N] fp32 -> Wt [N][K] bf16 --
__global__ void k_transpose_all(const float* __restrict__ Wq,
                                const float* __restrict__ Wk,
                                const float* __restrict__ Wv,
                                const float* __restrict__ Wo,
                                __bf16* __restrict__ wqt,
                                __bf16* __restrict__ wkvt,
                                __bf16* __restrict__ wot) {
    const int z = blockIdx.z;
    const float* in; __bf16* out; int N;
    if      (z == 0) { in = Wq; out = wqt;  N = 2048; }
    else if (z == 1) { in = Wk; out = wkvt; N = 512;  }
    else if (z == 2) { in = Wv; out = wkvt + (size_t)512 * HID; N = 512; }
    else             { in = Wo; out = wot;  N = 2048; }
    int k0 = blockIdx.x * 64, n0 = blockIdx.y * 64;
    if (n0 >= N) return;
    __shared__ float tile[64][65];
    for (int e = threadIdx.x; e < 4096; e += 256) {
        int r = e >> 6, c = e & 63;
        tile[r][c] = in[(size_t)(k0 + r) * N + n0 + c];
    }
    __syncthreads();
    for (int e = threadIdx.x; e < 4096; e += 256) {
        int r = e >> 6, c = e & 63;
        out[(size_t)(n0 + r) * HID + k0 + c] = (__bf16)tile[c][r];
    }
}

// ---- merged QKV GEMM: C[8192][3072] = xb * [wqt|wkvt]^T (m97 structure) ----
__global__ __launch_bounds__(256) void k_gemm_qkv(const __bf16* __restrict__ A,
                                                  const __bf16* __restrict__ Bt,
                                                  unsigned char* __restrict__ qb8,
                                                  unsigned char* __restrict__ kb8,
                                                  __bf16* __restrict__ vtb,
                                                  const float* __restrict__ cosp,
                                                  const float* __restrict__ sinp) {
    __shared__ __align__(16) char smem[33792];      // As+Bs / 128*132 bf16 epilogue
    __bf16* As = (__bf16*)smem;                     // [128*64]
    __bf16* Bs = (__bf16*)(smem + 16384);           // [128*64]
    const int tid = threadIdx.x, lane = tid & 63, wave = tid >> 6;
    const int wm = wave >> 1, wn = wave & 1;
    const int id = blockIdx.x;
    const int xcd = id & 7, g = id >> 3;            // g in [0,192)
    const int m0 = (xcd * 8 + (g & 7)) * 128;
    const int n0 = (g >> 3) * 128;
    const int lo = lane & 15, hi = lane >> 4;
    f32x4 acc[4][4] = {};

    const int srow = wave * 8 + (lane >> 3); // staging row (+ r*32)
    const int sp   = lane & 7;               // physical 16B chunk

    for (int kt = 0; kt < HID; kt += 64) {
#pragma unroll
        for (int r = 0; r < 4; r++) {        // A tile
            int row = r * 32 + srow;
            int c = sp ^ (row & 7);
            gld16(A + (size_t)(m0 + row) * HID + kt + c * 8, &As[(r * 32 + wave * 8) * 64]);
        }
#pragma unroll
        for (int r = 0; r < 4; r++) {        // B tile
            int row = r * 32 + srow;
            int c = sp ^ (row & 7);
            gld16(Bt + (size_t)(n0 + row) * HID + kt + c * 8, &Bs[(r * 32 + wave * 8) * 64]);
        }
        __syncthreads();
#pragma unroll
        for (int ks = 0; ks < 2; ks++) {
            bf16x8 af[4], bfr[4];
#pragma unroll
            for (int mt = 0; mt < 4; mt++) {
                int row = wm * 64 + mt * 16 + lo;
                int pp = (ks * 4 + hi) ^ (row & 7);
                af[mt] = *(const bf16x8*)&As[row * 64 + pp * 8];
            }
#pragma unroll
            for (int nt = 0; nt < 4; nt++) {
                int row = wn * 64 + nt * 16 + lo;
                int pp = (ks * 4 + hi) ^ (row & 7);
                bfr[nt] = *(const bf16x8*)&Bs[row * 64 + pp * 8];
            }
#pragma unroll
            for (int mt = 0; mt < 4; mt++)
#pragma unroll
                for (int nt = 0; nt < 4; nt++)
                    acc[mt][nt] = __builtin_amdgcn_mfma_f32_16x16x32_bf16(
                        af[mt], bfr[nt], acc[mt][nt], 0, 0, 0);
        }
        __syncthreads();
    }

    if (n0 < 2560) {
        // ---- Q/K epilogue: row-major C stage -> rope -> fp8 pack -> store --
        __bf16* Cs = (__bf16*)smem;                 // [128][132]
#pragma unroll
        for (int mt = 0; mt < 4; mt++)
#pragma unroll
            for (int nt = 0; nt < 4; nt++) {
                int rl = wm * 64 + mt * 16 + hi * 4;
                int cl = wn * 64 + nt * 16 + lo;
#pragma unroll
                for (int r = 0; r < 4; r++)
                    Cs[(rl + r) * 132 + cl] = (__bf16)acc[mt][nt][r];
            }
        __syncthreads();

        const int crow = tid >> 4;           // 0..15 (+16 per rep)
        const int cch  = tid & 15;           // 8-col chunk
        const int colg = n0 + cch * 8;
        const bool isQ = n0 < 2048;
        const int d0 = colg & (HD - 1);
#pragma unroll
        for (int rep = 0; rep < 8; rep++) {
            int row = rep * 16 + crow;
            int rowg = m0 + row;
            bf16x8 v = *(const bf16x8*)&Cs[row * 132 + cch * 8];
            float f[8];
#pragma unroll
            for (int j = 0; j < 8; j++) f[j] = (float)v[j];
            {   // rope (q and k both)
                int s = rowg & (S_LEN - 1);
                f32x4 c0 = *(const f32x4*)&cosp[s * HD + d0];
                f32x4 c1 = *(const f32x4*)&cosp[s * HD + d0 + 4];
                f32x4 s0 = *(const f32x4*)&sinp[s * HD + d0];
                f32x4 s1 = *(const f32x4*)&sinp[s * HD + d0 + 4];
                float cc[8] = {c0[0], c0[1], c0[2], c0[3], c1[0], c1[1], c1[2], c1[3]};
                float ss[8] = {s0[0], s0[1], s0[2], s0[3], s1[0], s1[1], s1[2], s1[3]};
#pragma unroll
                for (int p = 0; p < 4; p++) {
                    float e0 = f[2 * p], e1 = f[2 * p + 1];
                    f[2 * p]     = e0 * cc[2 * p]     - e1 * ss[2 * p];
                    f[2 * p + 1] = e1 * cc[2 * p + 1] + e0 * ss[2 * p + 1];
                }
            }
            if (isQ) {
#pragma unroll
                for (int j = 0; j < 8; j++) f[j] *= QSCALE;
            }
            int u0 = __builtin_amdgcn_cvt_pk_fp8_f32(f[0], f[1], 0, false);
            u0     = __builtin_amdgcn_cvt_pk_fp8_f32(f[2], f[3], u0, true);
            int u1 = __builtin_amdgcn_cvt_pk_fp8_f32(f[4], f[5], 0, false);
            u1     = __builtin_amdgcn_cvt_pk_fp8_f32(f[6], f[7], u1, true);
            u32x2 pk; pk[0] = (unsigned)u0; pk[1] = (unsigned)u1;
            if (isQ) *(u32x2*)&qb8[(size_t)rowg * HID + colg] = pk;
            else     *(u32x2*)&kb8[(size_t)rowg * 512 + (colg - 2048)] = pk;
        }
    } else {
        // ---- V epilogue: TRANSPOSED stage CsT[col][row] -> vtb[d][s] -------
        __bf16* CsT = (__bf16*)smem;                // [128 cols][132 rows pad]
#pragma unroll
        for (int mt = 0; mt < 4; mt++)
#pragma unroll
            for (int nt = 0; nt < 4; nt++) {
                int cl = wn * 64 + nt * 16 + lo;
                int mrow = wm * 64 + mt * 16 + hi * 4;
                bf16x4 w;
#pragma unroll
                for (int r = 0; r < 4; r++) w[r] = (__bf16)acc[mt][nt][r];
                *(bf16x4*)&CsT[cl * 132 + mrow] = w;
            }
        __syncthreads();

        const int kvh = (n0 - 2560) >> 7;    // block covers exactly one kv head
        const int bb = m0 >> 11;             // batch
        const int s0 = m0 & (S_LEN - 1);
        __bf16* dst = vtb + (size_t)(bb * NKV + kvh) * HD * S_LEN;
        const int dloc = tid >> 4;           // 0..15 (+16 per rep)
        const int sch  = tid & 15;           // 8-elem s chunk
#pragma unroll
        for (int rep = 0; rep < 8; rep++) {
            int d = rep * 16 + dloc;
            bf16x8 v = *(const bf16x8*)&CsT[d * 132 + sch * 8];
            *(bf16x8*)&dst[(size_t)d * S_LEN + s0 + sch * 8] = v;
        }
    }
}

// -------- O-proj GEMM, 8-phase deep pipeline (T2+T3+T4+T5) ------------------
// RACE FIX vs R12: __builtin_amdgcn_s_barrier() is IntrNoMem in LLVM -> the
// compiler may hoist LDS loads across it (a phase-P+1 ds_read hoisted above
// phase-P's end barrier reads rows whose owner wave hasn't passed its vmcnt
// yet -> stale data, intermittent). Every barrier here is emitted as
// asm volatile("s_barrier" ::: "memory") — hardware barrier + compiler
// memory fence. Schedule is otherwise identical to R12 (mapping validated:
// first-run absmax matched R11).
#define BARM asm volatile("s_barrier" ::: "memory")
#define BAR1 do { BARM;                                                       \
                  asm volatile("s_waitcnt lgkmcnt(0)" ::: "memory");          \
                  __builtin_amdgcn_sched_barrier(0); } while (0)
#define BAR2 BARM
#define MM(qm, qn)                                                            \
    do {                                                                      \
        __builtin_amdgcn_s_setprio(1);                                        \
        _Pragma("unroll") for (int ks = 0; ks < 2; ks++)                      \
        _Pragma("unroll") for (int mf = 0; mf < 4; mf++)                      \
        _Pragma("unroll") for (int nf = 0; nf < 2; nf++)                      \
            acc[qm][qn][mf][nf] = __builtin_amdgcn_mfma_f32_16x16x32_bf16(    \
                af[mf][ks], bf[nf][ks], acc[qm][qn][mf][nf], 0, 0, 0);        \
        __builtin_amdgcn_s_setprio(0);                                        \
    } while (0)

__global__ __launch_bounds__(512) void k_gemm_o8(const __bf16* __restrict__ A,
                                                 const __bf16* __restrict__ Bt,
                                                 float* __restrict__ Cp) {
    __shared__ __bf16 Ab[2][2][128 * 64];   // [slot][half] 64 KB
    __shared__ __bf16 Bb[2][2][128 * 64];   // 64 KB
    const int tid = threadIdx.x, lane = tid & 63, wave = tid >> 6;
    const int wm = wave >> 2, wn = wave & 3;
    const int m0 = (blockIdx.x >> 3) * 256;  // n = id&7 -> XCD owns n-stripe
    const int n0 = (blockIdx.x & 7) * 256;
    const int lo = lane & 15, hi = lane >> 4;
    f32x4 acc[2][2][4][2] = {};

    const int srow = wave * 8 + (lane >> 3);  // + pass*64
    const int sp   = lane & 7;

    auto STA = [&](int s, int h, int t) {    // one A half-tile: 2 gld16/thread
#pragma unroll
        for (int p = 0; p < 2; p++) {
            int rr = p * 64 + srow;
            int c = sp ^ (rr & 7);
            gld16(A + (size_t)(m0 + h * 128 + rr) * HID + t * 64 + c * 8,
                  &Ab[s][h][(p * 64 + wave * 8) * 64]);
        }
    };
    auto STB = [&](int s, int h, int t) {
#pragma unroll
        for (int p = 0; p < 2; p++) {
            int rr = p * 64 + srow;
            int c = sp ^ (rr & 7);
            gld16(Bt + (size_t)(n0 + h * 128 + rr) * HID + t * 64 + c * 8,
                  &Bb[s][h][(p * 64 + wave * 8) * 64]);
        }
    };

    bf16x8 af[4][2], bf[2][2];
    auto LDA = [&](int s, int qm) {          // 8 ds_read_b128
#pragma unroll
        for (int mf = 0; mf < 4; mf++) {
            int rr = wm * 64 + mf * 16 + lo;
#pragma unroll
            for (int ks = 0; ks < 2; ks++) {
                int pp = (ks * 4 + hi) ^ (rr & 7);
                af[mf][ks] = *(const bf16x8*)&Ab[s][qm][rr * 64 + pp * 8];
            }
        }
    };
    auto LDB = [&](int s, int qn) {          // 4 ds_read_b128
#pragma unroll
        for (int nf = 0; nf < 2; nf++) {
            int rr = wn * 32 + nf * 16 + lo;
#pragma unroll
            for (int ks = 0; ks < 2; ks++) {
                int pp = (ks * 4 + hi) ^ (rr & 7);
                bf[nf][ks] = *(const bf16x8*)&Bb[s][qn][rr * 64 + pp * 8];
            }
        }
    };

    // prologue: t0=0 fully (slot0), t1=1 h1 only (slot1); h0 of t1 at P1.
    STA(0, 0, 0); STB(0, 0, 0); STA(0, 1, 0); STB(0, 1, 0);
    STA(1, 1, 1); STB(1, 1, 1);
    asm volatile("s_waitcnt vmcnt(4)" ::: "memory");  // t0 landed; t1-h1 flies
    BARM;

#pragma unroll 1
    for (int i = 0; i < 16; i++) {
        const int t0 = 2 * i, t1 = 2 * i + 1;
        const bool more = (i < 15);
        // P1: Q(0,0) of t0   [reads slot0 h0; stages t1 h0 -> slot1]
        LDA(0, 0); LDB(0, 0);
        STA(1, 0, t1); STB(1, 0, t1);
        BAR1; MM(0, 0); BAR2;
        // P2: Q(0,1)         [A-h0 frags retained]
        LDB(0, 1);
        BAR1; MM(0, 1); BAR2;
        // P3: Q(1,0)         [stages next-t0 A-h0 (slot0 A-h0 free after P1 read)]
        LDA(0, 1); LDB(0, 0);
        if (more) STA(0, 0, t0 + 2);
        BAR1; MM(1, 0); BAR2;
        // P4: Q(1,1)         [stages next-t0 B-h0; counted vmcnt -> t1 ready]
        LDB(0, 1);
        if (more) STB(0, 0, t0 + 2);
        BAR1; MM(1, 1);
        if (more) { asm volatile("s_waitcnt vmcnt(4)" ::: "memory"); }
        else      { asm volatile("s_waitcnt vmcnt(0)" ::: "memory"); }
        BAR2;
        // P5: Q(1,1) of t1   [reads slot1 h1; stages next-t0 h1 (free after P3/P4)]
        LDA(1, 1); LDB(1, 1);
        if (more) { STA(0, 1, t0 + 2); STB(0, 1, t0 + 2); }
        BAR1; MM(1, 1); BAR2;
        // P6: Q(1,0)
        LDB(1, 0);
        BAR1; MM(1, 0); BAR2;
        // P7: Q(0,1)         [stages next-t1 A-h1 (slot1 A-h1 free after P6)]
        LDA(1, 0); LDB(1, 1);
        if (more) STA(1, 1, t1 + 2);
        BAR1; MM(0, 1); BAR2;
        // P8: Q(0,0)         [stages next-t1 B-h1; counted vmcnt -> next-t0 ready]
        LDB(1, 0);
        if (more) STB(1, 1, t1 + 2);
        BAR1; MM(0, 0);
        if (more) { asm volatile("s_waitcnt vmcnt(4)" ::: "memory"); }
        BAR2;
    }

    // epilogue: fp32 C writes (register-only; no LDS dependence)
#pragma unroll
    for (int qm = 0; qm < 2; qm++)
#pragma unroll
        for (int qn = 0; qn < 2; qn++)
#pragma unroll
            for (int mf = 0; mf < 4; mf++)
#pragma unroll
                for (int nf = 0; nf < 2; nf++) {
                    int row = m0 + qm * 128 + wm * 64 + mf * 16 + hi * 4;
                    int col = n0 + qn * 128 + wn * 32 + nf * 16 + lo;
#pragma unroll
                    for (int r = 0; r < 4; r++)
                        Cp[(size_t)(row + r) * HID + col] = acc[qm][qn][mf][nf][r];
                }
}

// ----------------------------- flash attention ------------------------------
// QK^T in FP8 e4m3; PV bf16. Per wave: 32 q-rows (2 subtiles), every K/V LDS
// read shared. QBLK=256, grid 256 = 1/CU. LDS: Ks8 2x8K + Vs 2x16K + Ps 32K.
__global__ __launch_bounds__(512) void k_attn(const unsigned char* __restrict__ qb8,
                                              const unsigned char* __restrict__ kb8,
                                              const __bf16* __restrict__ vtb,
                                              __bf16* __restrict__ ob) {
    __shared__ char   Ks8[2][64 * 128];  // [kv][128B of fp8 d], XOR-swizzled
    __shared__ __bf16 Vs[2][128 * 64];   // [d][kv] bf16, XOR-swizzled
    __shared__ __bf16 Ps[8][2048];       // wave-private: 2 subtiles x 16x64
    const int tid = threadIdx.x, lane = tid & 63, wave = tid >> 6;
    const int pair = blockIdx.x, h = blockIdx.y, b = blockIdx.z;
    const int kvh = h >> 2;
    const int lo = lane & 15, hi = lane >> 4;
    char* PsW = (char*)&Ps[wave][0];

    const unsigned char* kbb = kb8 + (size_t)b * S_LEN * 512 + kvh * HD;
    const __bf16* vbb = vtb + (size_t)(b * NKV + kvh) * HD * S_LEN;

    const int krow_s = tid >> 3;                // 0..63
    const int kp_s   = tid & 7;
    const int vrow_s = wave * 8 + (lane >> 3);  // + r*64
    const int vp_s   = lane & 7;

    auto STAGE_K = [&](int buf, int t) {        // 8 KB: ONE gld16
        int c = kp_s ^ (krow_s & 7);
        gld16(kbb + (size_t)(t * 64 + krow_s) * 512 + c * 16,
              &Ks8[buf][wave * 1024]);
    };
    auto STAGE_V = [&](int buf, int t) {
#pragma unroll
        for (int r = 0; r < 2; r++) {
            int row = r * 64 + vrow_s;
            int c = vp_s ^ (row & 7);
            gld16(vbb + (size_t)row * S_LEN + t * 64 + c * 8,
                  &Vs[buf][(r * 64 + wave * 8) * 64]);
        }
    };

    auto SM = [&](f32x4 (&sc)[4], float& Mr, float& Lr, f32x4 (&o)[8]) {
        float mloc = sc[0][0];
#pragma unroll
        for (int nt = 0; nt < 4; nt++)
#pragma unroll
            for (int r = 0; r < 4; r++) mloc = fmaxf(mloc, sc[nt][r]);
        mloc = fmaxf(mloc, __shfl_xor(mloc, 16, 64));
        mloc = fmaxf(mloc, __shfl_xor(mloc, 32, 64));
        float mn = (mloc <= Mr + 8.f) ? Mr : mloc;
        float sum = 0.f;
#pragma unroll
        for (int nt = 0; nt < 4; nt++)
#pragma unroll
            for (int r = 0; r < 4; r++) {
                float e = __expf(sc[nt][r] - mn);
                sc[nt][r] = e;
                sum += e;
            }
        sum += __shfl_xor(sum, 16, 64);
        sum += __shfl_xor(sum, 32, 64);
        if (mn != Mr) {
            float scl = __expf(Mr - mn);
            Lr = Lr * scl + sum;
            Mr = mn;
#pragma unroll
            for (int dt = 0; dt < 8; dt++) o[dt] *= scl;
        } else {
            Lr += sum;
        }
    };

#pragma unroll 1
    for (int pi = 0; pi < 2; pi++) {
        const int qt = pi ? (NQT2 - 1 - pair) : pair;  // 256-row q-tile index
        const int nkv = 4 * qt + 4;                    // kv tiles of 64 rows
        const int qbase = qt * 256 + wave * 32;        // this wave's 32 q-rows

        const unsigned char* qp0 = qb8 + (size_t)(b * S_LEN + qbase + lo) * HID + h * HD;
        const unsigned char* qp1 = qp0 + (size_t)16 * HID;
        long qa0[4], qa1[4];
#pragma unroll
        for (int kf = 0; kf < 4; kf++) {
            qa0[kf] = *(const long*)(qp0 + kf * 32 + hi * 8);
            qa1[kf] = *(const long*)(qp1 + kf * 32 + hi * 8);
        }

        f32x4 o0[8] = {}, o1[8] = {};
        float Mr0 = -3e30f, Lr0 = 0.f, Mr1 = -3e30f, Lr1 = 0.f;

        int cur = 0;
        if (pi == 1) __syncthreads();
        STAGE_K(0, 0);
        STAGE_V(0, 0);
        __syncthreads();

#pragma unroll 1
        for (int t = 0; t < nkv; t++) {
            if (t < nkv - 1) { STAGE_K(cur ^ 1, t + 1); STAGE_V(cur ^ 1, t + 1); }

            f32x4 sc0[4], sc1[4];
            __builtin_amdgcn_s_setprio(1);
#pragma unroll
            for (int nt = 0; nt < 4; nt++) {
                f32x4 a = {0.f, 0.f, 0.f, 0.f}, bb = {0.f, 0.f, 0.f, 0.f};
#pragma unroll
                for (int kf = 0; kf < 4; kf++) {
                    int row = nt * 16 + lo;
                    int lch = 2 * kf + (hi >> 1);
                    long kf8 = *(const long*)&Ks8[cur][row * 128 +
                                ((lch ^ (row & 7)) * 16) + (hi & 1) * 8];
                    a  = __builtin_amdgcn_mfma_f32_16x16x32_fp8_fp8(kf8, qa0[kf], a, 0, 0, 0);
                    bb = __builtin_amdgcn_mfma_f32_16x16x32_fp8_fp8(kf8, qa1[kf], bb, 0, 0, 0);
                }
                sc0[nt] = a; sc1[nt] = bb;
            }
            __builtin_amdgcn_s_setprio(0);

            if (t * 64 + 63 > qbase) {
                int qg = qbase + lo;
#pragma unroll
                for (int nt = 0; nt < 4; nt++)
#pragma unroll
                    for (int r = 0; r < 4; r++) {
                        int kg = t * 64 + nt * 16 + hi * 4 + r;
                        if (kg > qg) sc0[nt][r] = -1e30f;
                    }
            }
            if (t * 64 + 63 > qbase + 16) {
                int qg = qbase + 16 + lo;
#pragma unroll
                for (int nt = 0; nt < 4; nt++)
#pragma unroll
                    for (int r = 0; r < 4; r++) {
                        int kg = t * 64 + nt * 16 + hi * 4 + r;
                        if (kg > qg) sc1[nt][r] = -1e30f;
                    }
            }

            SM(sc0, Mr0, Lr0, o0);
            SM(sc1, Mr1, Lr1, o1);

#pragma unroll
            for (int nt = 0; nt < 4; nt++) {
                bf16x4 p0, p1;
#pragma unroll
                for (int r = 0; r < 4; r++) { p0[r] = (__bf16)sc0[nt][r]; p1[r] = (__bf16)sc1[nt][r]; }
                int off = lo * 128 + ((nt * 32 + hi * 8) ^ ((lo & 7) << 4));
                *(bf16x4*)(PsW + off)        = p0;
                *(bf16x4*)(PsW + 2048 + off) = p1;
            }
            asm volatile("s_waitcnt lgkmcnt(0)" ::: "memory");
            bf16x8 pf0[2], pf1[2];
#pragma unroll
            for (int c = 0; c < 2; c++) {
                int off = lo * 128 + ((c * 64 + hi * 16) ^ ((lo & 7) << 4));
                pf0[c] = *(const bf16x8*)(PsW + off);
                pf1[c] = *(const bf16x8*)(PsW + 2048 + off);
            }
            __builtin_amdgcn_s_setprio(1);
#pragma unroll
            for (int dt = 0; dt < 8; dt++) {
                int rowd = dt * 16 + lo;
#pragma unroll
                for (int c = 0; c < 2; c++) {
                    int ch = c * 4 + hi;
                    bf16x8 vv = *(const bf16x8*)&Vs[cur][rowd * 64 + (ch ^ (rowd & 7)) * 8];
                    o0[dt] = __builtin_amdgcn_mfma_f32_16x16x32_bf16(vv, pf0[c], o0[dt], 0, 0, 0);
                    o1[dt] = __builtin_amdgcn_mfma_f32_16x16x32_bf16(vv, pf1[c], o1[dt], 0, 0, 0);
                }
            }
            __builtin_amdgcn_s_setprio(0);
            __syncthreads();
            cur ^= 1;
        }

        const int qe = lane >> 2, c4 = lane & 3;
#pragma unroll
        for (int sub = 0; sub < 2; sub++) {
            float rl = 1.0f / (sub ? Lr1 : Lr0);
            char* Pp = PsW + sub * 2048;
#pragma unroll
            for (int h2 = 0; h2 < 2; h2++) {
#pragma unroll
                for (int dt4 = 0; dt4 < 4; dt4++) {
                    f32x4 ov = sub ? o1[h2 * 4 + dt4] : o0[h2 * 4 + dt4];
                    bf16x4 w;
#pragma unroll
                    for (int r = 0; r < 4; r++) w[r] = (__bf16)(ov[r] * rl);
                    *(bf16x4*)(Pp + lo * 128 + ((dt4 * 32 + hi * 8) ^ ((lo & 7) << 4))) = w;
                }
                asm volatile("s_waitcnt lgkmcnt(0)" ::: "memory");
                __builtin_amdgcn_sched_barrier(0);
#pragma unroll
                for (int s2 = 0; s2 < 2; s2++) {
                    int ch = c4 + s2 * 4;
                    bf16x8 v = *(const bf16x8*)(Pp + qe * 128 + ((ch * 16) ^ ((qe & 7) << 4)));
                    int qg = qbase + sub * 16 + qe;
                    int col = h * HD + h2 * 64 + ch * 8;
                    *(bf16x8*)&ob[(size_t)(b * S_LEN + qg) * HID + col] = v;
                }
            }
        }
    }
}

// ----------------------------------- host -----------------------------------
extern "C" void kernel_launch(void* const* d_in, const int* in_sizes, int n_in,
                              void* d_out, int out_size, void* d_ws, size_t ws_size,
                              hipStream_t stream) {
    (void)in_sizes; (void)n_in; (void)out_size; (void)ws_size;
    const float* x    = (const float*)d_in[0];
    const float* cosp = (const float*)d_in[1];
    const float* sinp = (const float*)d_in[2];
    const float* Wq   = (const float*)d_in[3];
    const float* Wk   = (const float*)d_in[4];
    const float* Wv   = (const float*)d_in[5];
    const float* Wo   = (const float*)d_in[6];
    float* out = (float*)d_out;

    char* ws = (char*)d_ws;
    __bf16*        xb   = (__bf16*)(ws);               // [8192][2048] bf16  32 MB
    __bf16*        wqt  = (__bf16*)(ws + 33554432);    // [2048][2048]        8 MB
    __bf16*        wkvt = (__bf16*)(ws + 41943040);    // [1024][2048] (k|v)  4 MB (contig with wqt)
    __bf16*        wot  = (__bf16*)(ws + 46137344);    // [2048][2048]        8 MB
    unsigned char* qb8  = (unsigned char*)(ws + 54525952);  // [8192][2048] fp8 16 MB
    unsigned char* kb8  = (unsigned char*)(ws + 71303168);  // [8192][512]  fp8  4 MB
    __bf16*        vtb  = (__bf16*)(ws + 75497472);    // [16][128][2048] bf16 8 MB
    __bf16*        aob  = xb;                          // reuse xb after QKV GEMM

    k_conv_x<<<MTOT * HID / 8 / 256, 256, 0, stream>>>(x, xb);
    { dim3 g(32, 32, 4);
      k_transpose_all<<<g, 256, 0, stream>>>(Wq, Wk, Wv, Wo, wqt, wkvt, wot); }

    k_gemm_qkv<<<1536, 256, 0, stream>>>(xb, wqt, qb8, kb8, vtb, cosp, sinp);

    { dim3 g(NQT2 / 2, 16, BATCH); k_attn<<<g, 512, 0, stream>>>(qb8, kb8, vtb, aob); }

    k_gemm_o8<<<256, 512, 0, stream>>>(aob, wot, out);
}

// Round 14
// 319.220 us; speedup vs baseline: 1.4294x; 1.0254x over previous
//
#include <hip/hip_runtime.h>
#include <stdint.h>

#define S_LEN 2048
#define BATCH 4
#define HID   2048
#define HD    128
#define NKV   4
#define MTOT  (BATCH*S_LEN) // 8192
#define NQT2  (S_LEN/256)   // 8 q-tiles (256 rows) per (b,h)
#define QSCALE 0.08838834764831845f

typedef float    f32x4  __attribute__((ext_vector_type(4)));
typedef __bf16   bf16x8 __attribute__((ext_vector_type(8)));
typedef __bf16   bf16x4 __attribute__((ext_vector_type(4)));
typedef unsigned u32x2  __attribute__((ext_vector_type(2)));

// async global->LDS, 16B per lane. LDS dest = wave-uniform base + lane*16.
__device__ __forceinline__ void gld16(const void* g, void* l) {
    __builtin_amdgcn_global_load_lds(
        (const __attribute__((address_space(1))) void*)g,
        (__attribute__((address_space(3))) void*)l, 16, 0, 0);
}

// ---------------- fp32 -> bf16 bulk convert (8 elems/thread) ----------------
__global__ void k_conv_x(const float* __restrict__ in, __bf16* __restrict__ out) {
    int i = blockIdx.x * blockDim.x + threadIdx.x;
    f32x4 a = ((const f32x4*)in)[2 * i];
    f32x4 b = ((const f32x4*)in)[2 * i + 1];
    bf16x8 o;
    o[0] = (__bf16)a[0]; o[1] = (__bf16)a[1]; o[2] = (__bf16)a[2]; o[3] = (__bf16)a[3];
    o[4] = (__bf16)b[0]; o[5] = (__bf16)b[1]; o[6] = (__bf16)b[2]; o[7] = (__bf16)b[3];
    ((bf16x8*)out)[i] = o;
}

// ---- ALL weight transposes in one launch: W [K][N] fp32 -> Wt [N][K] bf16 --
__global__ void k_transpose_all(const float* __restrict__ Wq,
                                const float* __restrict__ Wk,
                                const float* __restrict__ Wv,
                                const float* __restrict__ Wo,
                                __bf16* __restrict__ wqt,
                                __bf16* __restrict__ wkvt,
                                __bf16* __restrict__ wot) {
    const int z = blockIdx.z;
    const float* in; __bf16* out; int N;
    if      (z == 0) { in = Wq; out = wqt;  N = 2048; }
    else if (z == 1) { in = Wk; out = wkvt; N = 512;  }
    else if (z == 2) { in = Wv; out = wkvt + (size_t)512 * HID; N = 512; }
    else             { in = Wo; out = wot;  N = 2048; }
    int k0 = blockIdx.x * 64, n0 = blockIdx.y * 64;
    if (n0 >= N) return;
    __shared__ float tile[64][65];
    for (int e = threadIdx.x; e < 4096; e += 256) {
        int r = e >> 6, c = e & 63;
        tile[r][c] = in[(size_t)(k0 + r) * N + n0 + c];
    }
    __syncthreads();
    for (int e = threadIdx.x; e < 4096; e += 256) {
        int r = e >> 6, c = e & 63;
        out[(size_t)(n0 + r) * HID + k0 + c] = (__bf16)tile[c][r];
    }
}

// ============== 8-phase deep-pipeline K-loop (validated R13) ================
// Barriers MUST be memory-fenced asm ("s_barrier" ::: "memory"): the bare
// builtin is IntrNoMem and the compiler hoists ds_reads across it (R12 race).
#define BARM asm volatile("s_barrier" ::: "memory")
#define BAR1 do { BARM;                                                       \
                  asm volatile("s_waitcnt lgkmcnt(0)" ::: "memory");          \
                  __builtin_amdgcn_sched_barrier(0); } while (0)
#define BAR2 BARM
#define MM(qm, qn)                                                            \
    do {                                                                      \
        __builtin_amdgcn_s_setprio(1);                                        \
        _Pragma("unroll") for (int ks = 0; ks < 2; ks++)                      \
        _Pragma("unroll") for (int mf = 0; mf < 4; mf++)                      \
        _Pragma("unroll") for (int nf = 0; nf < 2; nf++)                      \
            acc[qm][qn][mf][nf] = __builtin_amdgcn_mfma_f32_16x16x32_bf16(    \
                af[mf][ks], bf[nf][ks], acc[qm][qn][mf][nf], 0, 0, 0);        \
        __builtin_amdgcn_s_setprio(0);                                        \
    } while (0)

// The shared 8-phase K-loop body (BM=BN=256, BK=64, 8 waves 2Mx4N, K=2048,
// LDS 128 KiB). Declares Ab/Bb/acc/af/bf and runs the full 16-iteration loop.
#define GEMM8_BODY(Aptr, Bptr)                                                \
    __shared__ __bf16 Ab[2][2][128 * 64];                                     \
    __shared__ __bf16 Bb[2][2][128 * 64];                                     \
    const int tid = threadIdx.x, lane = tid & 63, wave = tid >> 6;            \
    const int wm = wave >> 2, wn = wave & 3;                                  \
    const int lo = lane & 15, hi = lane >> 4;                                 \
    f32x4 acc[2][2][4][2] = {};                                               \
    const int srow = wave * 8 + (lane >> 3);                                  \
    const int sp   = lane & 7;                                                \
    auto STA = [&](int s, int h, int t) {                                     \
        _Pragma("unroll") for (int p = 0; p < 2; p++) {                       \
            int rr = p * 64 + srow;                                           \
            int c = sp ^ (rr & 7);                                            \
            gld16(Aptr + (size_t)(m0 + h * 128 + rr) * HID + t * 64 + c * 8,  \
                  &Ab[s][h][(p * 64 + wave * 8) * 64]);                       \
        }                                                                     \
    };                                                                        \
    auto STB = [&](int s, int h, int t) {                                     \
        _Pragma("unroll") for (int p = 0; p < 2; p++) {                       \
            int rr = p * 64 + srow;                                           \
            int c = sp ^ (rr & 7);                                            \
            gld16(Bptr + (size_t)(n0 + h * 128 + rr) * HID + t * 64 + c * 8,  \
                  &Bb[s][h][(p * 64 + wave * 8) * 64]);                       \
        }                                                                     \
    };                                                                        \
    bf16x8 af[4][2], bf[2][2];                                                \
    auto LDA = [&](int s, int qm) {                                           \
        _Pragma("unroll") for (int mf = 0; mf < 4; mf++) {                    \
            int rr = wm * 64 + mf * 16 + lo;                                  \
            _Pragma("unroll") for (int ks = 0; ks < 2; ks++) {                \
                int pp = (ks * 4 + hi) ^ (rr & 7);                            \
                af[mf][ks] = *(const bf16x8*)&Ab[s][qm][rr * 64 + pp * 8];    \
            }                                                                 \
        }                                                                     \
    };                                                                        \
    auto LDB = [&](int s, int qn) {                                           \
        _Pragma("unroll") for (int nf = 0; nf < 2; nf++) {                    \
            int rr = wn * 32 + nf * 16 + lo;                                  \
            _Pragma("unroll") for (int ks = 0; ks < 2; ks++) {                \
                int pp = (ks * 4 + hi) ^ (rr & 7);                            \
                bf[nf][ks] = *(const bf16x8*)&Bb[s][qn][rr * 64 + pp * 8];    \
            }                                                                 \
        }                                                                     \
    };                                                                        \
    STA(0, 0, 0); STB(0, 0, 0); STA(0, 1, 0); STB(0, 1, 0);                   \
    STA(1, 1, 1); STB(1, 1, 1);                                               \
    asm volatile("s_waitcnt vmcnt(4)" ::: "memory");                          \
    BARM;                                                                     \
    _Pragma("unroll 1")                                                       \
    for (int i = 0; i < 16; i++) {                                            \
        const int t0 = 2 * i, t1 = 2 * i + 1;                                 \
        const bool more = (i < 15);                                           \
        LDA(0, 0); LDB(0, 0);                                                 \
        STA(1, 0, t1); STB(1, 0, t1);                                         \
        BAR1; MM(0, 0); BAR2;                                                 \
        LDB(0, 1);                                                            \
        BAR1; MM(0, 1); BAR2;                                                 \
        LDA(0, 1); LDB(0, 0);                                                 \
        if (more) STA(0, 0, t0 + 2);                                          \
        BAR1; MM(1, 0); BAR2;                                                 \
        LDB(0, 1);                                                            \
        if (more) STB(0, 0, t0 + 2);                                          \
        BAR1; MM(1, 1);                                                       \
        if (more) { asm volatile("s_waitcnt vmcnt(4)" ::: "memory"); }        \
        else      { asm volatile("s_waitcnt vmcnt(0)" ::: "memory"); }        \
        BAR2;                                                                 \
        LDA(1, 1); LDB(1, 1);                                                 \
        if (more) { STA(0, 1, t0 + 2); STB(0, 1, t0 + 2); }                   \
        BAR1; MM(1, 1); BAR2;                                                 \
        LDB(1, 0);                                                            \
        BAR1; MM(1, 0); BAR2;                                                 \
        LDA(1, 0); LDB(1, 1);                                                 \
        if (more) STA(1, 1, t1 + 2);                                          \
        BAR1; MM(0, 1); BAR2;                                                 \
        LDB(1, 0);                                                            \
        if (more) STB(1, 1, t1 + 2);                                          \
        BAR1; MM(0, 0);                                                       \
        if (more) { asm volatile("s_waitcnt vmcnt(4)" ::: "memory"); }        \
        BAR2;                                                                 \
    }

// -------- Q-proj GEMM, 8-phase: qb8[8192][2048] fp8 = rope(xb*wqt^T)*QSCALE -
// grid 256 = (m 32) x (n 8) = exactly 1 block/CU.
__global__ __launch_bounds__(512) void k_gemm_q8(const __bf16* __restrict__ A,
                                                 const __bf16* __restrict__ Bt,
                                                 unsigned char* __restrict__ qb8,
                                                 const float* __restrict__ cosp,
                                                 const float* __restrict__ sinp) {
    const int m0 = (blockIdx.x >> 3) * 256;
    const int n0 = (blockIdx.x & 7) * 256;
    GEMM8_BODY(A, Bt)

    // epilogue: per-quadrant LDS stage -> rope + QSCALE + fp8 -> store.
    // After the loop's final BAR2 all LDS reads are done; Ab space is free.
    __bf16* Cs = (__bf16*)&Ab[0][0][0];            // [128][132]
    const int crow = tid >> 4;                     // 0..31 (+32 per rep)
    const int cch  = tid & 15;                     // 8-col chunk
    const int d0 = cch * 8;                        // colg & 127 (qn*128 = 0 mod 128)
#pragma unroll
    for (int qm = 0; qm < 2; qm++)
#pragma unroll
        for (int qn = 0; qn < 2; qn++) {
#pragma unroll
            for (int mf = 0; mf < 4; mf++)
#pragma unroll
                for (int nf = 0; nf < 2; nf++) {
                    int rl = wm * 64 + mf * 16 + hi * 4;
                    int cl = wn * 32 + nf * 16 + lo;
#pragma unroll
                    for (int r = 0; r < 4; r++)
                        Cs[(rl + r) * 132 + cl] = (__bf16)acc[qm][qn][mf][nf][r];
                }
            __syncthreads();
#pragma unroll
            for (int rep = 0; rep < 4; rep++) {
                int row = rep * 32 + crow;
                int rowg = m0 + qm * 128 + row;
                int colg = n0 + qn * 128 + cch * 8;
                bf16x8 v = *(const bf16x8*)&Cs[row * 132 + cch * 8];
                float f[8];
#pragma unroll
                for (int j = 0; j < 8; j++) f[j] = (float)v[j];
                int s = rowg & (S_LEN - 1);
                f32x4 c0 = *(const f32x4*)&cosp[s * HD + d0];
                f32x4 c1 = *(const f32x4*)&cosp[s * HD + d0 + 4];
                f32x4 s0 = *(const f32x4*)&sinp[s * HD + d0];
                f32x4 s1 = *(const f32x4*)&sinp[s * HD + d0 + 4];
                float cc[8] = {c0[0], c0[1], c0[2], c0[3], c1[0], c1[1], c1[2], c1[3]};
                float ss[8] = {s0[0], s0[1], s0[2], s0[3], s1[0], s1[1], s1[2], s1[3]};
#pragma unroll
                for (int p = 0; p < 4; p++) {
                    float e0 = f[2 * p], e1 = f[2 * p + 1];
                    f[2 * p]     = (e0 * cc[2 * p]     - e1 * ss[2 * p])     * QSCALE;
                    f[2 * p + 1] = (e1 * cc[2 * p + 1] + e0 * ss[2 * p + 1]) * QSCALE;
                }
                int u0 = __builtin_amdgcn_cvt_pk_fp8_f32(f[0], f[1], 0, false);
                u0     = __builtin_amdgcn_cvt_pk_fp8_f32(f[2], f[3], u0, true);
                int u1 = __builtin_amdgcn_cvt_pk_fp8_f32(f[4], f[5], 0, false);
                u1     = __builtin_amdgcn_cvt_pk_fp8_f32(f[6], f[7], u1, true);
                u32x2 pk; pk[0] = (unsigned)u0; pk[1] = (unsigned)u1;
                *(u32x2*)&qb8[(size_t)rowg * HID + colg] = pk;
            }
            __syncthreads();
        }
}

// -------- O-proj GEMM, 8-phase (validated R13): out[8192][2048] f32 ---------
__global__ __launch_bounds__(512) void k_gemm_o8(const __bf16* __restrict__ A,
                                                 const __bf16* __restrict__ Bt,
                                                 float* __restrict__ Cp) {
    const int m0 = (blockIdx.x >> 3) * 256;
    const int n0 = (blockIdx.x & 7) * 256;
    GEMM8_BODY(A, Bt)

    // epilogue: fp32 C writes (register-only; no LDS dependence)
#pragma unroll
    for (int qm = 0; qm < 2; qm++)
#pragma unroll
        for (int qn = 0; qn < 2; qn++)
#pragma unroll
            for (int mf = 0; mf < 4; mf++)
#pragma unroll
                for (int nf = 0; nf < 2; nf++) {
                    int row = m0 + qm * 128 + wm * 64 + mf * 16 + hi * 4;
                    int col = n0 + qn * 128 + wn * 32 + nf * 16 + lo;
#pragma unroll
                    for (int r = 0; r < 4; r++)
                        Cp[(size_t)(row + r) * HID + col] = acc[qm][qn][mf][nf][r];
                }
}

// ---- KV-proj GEMM (m97 structure): C[8192][1024] = xb * wkvt^T -------------
// grid (64, 8): n0 = 2048 + by*128. cols [2048,2560) -> k rope+fp8 -> kb8;
// [2560,3072) -> v transposed -> vtb.
__global__ __launch_bounds__(256) void k_gemm_kv(const __bf16* __restrict__ A,
                                                 const __bf16* __restrict__ Bt,
                                                 unsigned char* __restrict__ kb8,
                                                 __bf16* __restrict__ vtb,
                                                 const float* __restrict__ cosp,
                                                 const float* __restrict__ sinp) {
    __shared__ __align__(16) char smem[33792];      // As+Bs / 128*132 bf16 epilogue
    __bf16* As = (__bf16*)smem;                     // [128*64]
    __bf16* Bs = (__bf16*)(smem + 16384);           // [128*64]
    const int tid = threadIdx.x, lane = tid & 63, wave = tid >> 6;
    const int wm = wave >> 1, wn = wave & 1;
    const int m0 = blockIdx.x * 128;
    const int n0 = 2048 + blockIdx.y * 128;
    const int lo = lane & 15, hi = lane >> 4;
    f32x4 acc[4][4] = {};

    const int srow = wave * 8 + (lane >> 3); // staging row (+ r*32)
    const int sp   = lane & 7;               // physical 16B chunk

    for (int kt = 0; kt < HID; kt += 64) {
#pragma unroll
        for (int r = 0; r < 4; r++) {        // A tile
            int row = r * 32 + srow;
            int c = sp ^ (row & 7);
            gld16(A + (size_t)(m0 + row) * HID + kt + c * 8, &As[(r * 32 + wave * 8) * 64]);
        }
#pragma unroll
        for (int r = 0; r < 4; r++) {        // B tile
            int row = r * 32 + srow;
            int c = sp ^ (row & 7);
            gld16(Bt + (size_t)(n0 + row) * HID + kt + c * 8, &Bs[(r * 32 + wave * 8) * 64]);
        }
        __syncthreads();
#pragma unroll
        for (int ks = 0; ks < 2; ks++) {
            bf16x8 af[4], bfr[4];
#pragma unroll
            for (int mt = 0; mt < 4; mt++) {
                int row = wm * 64 + mt * 16 + lo;
                int pp = (ks * 4 + hi) ^ (row & 7);
                af[mt] = *(const bf16x8*)&As[row * 64 + pp * 8];
            }
#pragma unroll
            for (int nt = 0; nt < 4; nt++) {
                int row = wn * 64 + nt * 16 + lo;
                int pp = (ks * 4 + hi) ^ (row & 7);
                bfr[nt] = *(const bf16x8*)&Bs[row * 64 + pp * 8];
            }
#pragma unroll
            for (int mt = 0; mt < 4; mt++)
#pragma unroll
                for (int nt = 0; nt < 4; nt++)
                    acc[mt][nt] = __builtin_amdgcn_mfma_f32_16x16x32_bf16(
                        af[mt], bfr[nt], acc[mt][nt], 0, 0, 0);
        }
        __syncthreads();
    }

    if (n0 < 2560) {
        // ---- K epilogue: row-major C stage -> rope -> fp8 pack -> store ----
        __bf16* Cs = (__bf16*)smem;                 // [128][132]
#pragma unroll
        for (int mt = 0; mt < 4; mt++)
#pragma unroll
            for (int nt = 0; nt < 4; nt++) {
                int rl = wm * 64 + mt * 16 + hi * 4;
                int cl = wn * 64 + nt * 16 + lo;
#pragma unroll
                for (int r = 0; r < 4; r++)
                    Cs[(rl + r) * 132 + cl] = (__bf16)acc[mt][nt][r];
            }
        __syncthreads();

        const int crow = tid >> 4;           // 0..15 (+16 per rep)
        const int cch  = tid & 15;           // 8-col chunk
        const int colg = n0 + cch * 8;
        const int d0 = colg & (HD - 1);
#pragma unroll
        for (int rep = 0; rep < 8; rep++) {
            int row = rep * 16 + crow;
            int rowg = m0 + row;
            bf16x8 v = *(const bf16x8*)&Cs[row * 132 + cch * 8];
            float f[8];
#pragma unroll
            for (int j = 0; j < 8; j++) f[j] = (float)v[j];
            int s = rowg & (S_LEN - 1);
            f32x4 c0 = *(const f32x4*)&cosp[s * HD + d0];
            f32x4 c1 = *(const f32x4*)&cosp[s * HD + d0 + 4];
            f32x4 s0 = *(const f32x4*)&sinp[s * HD + d0];
            f32x4 s1 = *(const f32x4*)&sinp[s * HD + d0 + 4];
            float cc[8] = {c0[0], c0[1], c0[2], c0[3], c1[0], c1[1], c1[2], c1[3]};
            float ss[8] = {s0[0], s0[1], s0[2], s0[3], s1[0], s1[1], s1[2], s1[3]};
#pragma unroll
            for (int p = 0; p < 4; p++) {
                float e0 = f[2 * p], e1 = f[2 * p + 1];
                f[2 * p]     = e0 * cc[2 * p]     - e1 * ss[2 * p];
                f[2 * p + 1] = e1 * cc[2 * p + 1] + e0 * ss[2 * p + 1];
            }
            int u0 = __builtin_amdgcn_cvt_pk_fp8_f32(f[0], f[1], 0, false);
            u0     = __builtin_amdgcn_cvt_pk_fp8_f32(f[2], f[3], u0, true);
            int u1 = __builtin_amdgcn_cvt_pk_fp8_f32(f[4], f[5], 0, false);
            u1     = __builtin_amdgcn_cvt_pk_fp8_f32(f[6], f[7], u1, true);
            u32x2 pk; pk[0] = (unsigned)u0; pk[1] = (unsigned)u1;
            *(u32x2*)&kb8[(size_t)rowg * 512 + (colg - 2048)] = pk;
        }
    } else {
        // ---- V epilogue: TRANSPOSED stage CsT[col][row] -> vtb[d][s] -------
        __bf16* CsT = (__bf16*)smem;                // [128 cols][132 rows pad]
#pragma unroll
        for (int mt = 0; mt < 4; mt++)
#pragma unroll
            for (int nt = 0; nt < 4; nt++) {
                int cl = wn * 64 + nt * 16 + lo;
                int mrow = wm * 64 + mt * 16 + hi * 4;
                bf16x4 w;
#pragma unroll
                for (int r = 0; r < 4; r++) w[r] = (__bf16)acc[mt][nt][r];
                *(bf16x4*)&CsT[cl * 132 + mrow] = w;
            }
        __syncthreads();

        const int kvh = (n0 - 2560) >> 7;    // block covers exactly one kv head
        const int bb = m0 >> 11;             // batch
        const int s0 = m0 & (S_LEN - 1);
        __bf16* dst = vtb + (size_t)(bb * NKV + kvh) * HD * S_LEN;
        const int dloc = tid >> 4;           // 0..15 (+16 per rep)
        const int sch  = tid & 15;           // 8-elem s chunk
#pragma unroll
        for (int rep = 0; rep < 8; rep++) {
            int d = rep * 16 + dloc;
            bf16x8 v = *(const bf16x8*)&CsT[d * 132 + sch * 8];
            *(bf16x8*)&dst[(size_t)d * S_LEN + s0 + sch * 8] = v;
        }
    }
}

// ----------------------------- flash attention ------------------------------
// QK^T in FP8 e4m3; PV bf16. Per wave: 32 q-rows (2 subtiles), every K/V LDS
// read shared. QBLK=256, grid 256 = 1/CU. LDS: Ks8 2x8K + Vs 2x16K + Ps 32K.
__global__ __launch_bounds__(512) void k_attn(const unsigned char* __restrict__ qb8,
                                              const unsigned char* __restrict__ kb8,
                                              const __bf16* __restrict__ vtb,
                                              __bf16* __restrict__ ob) {
    __shared__ char   Ks8[2][64 * 128];  // [kv][128B of fp8 d], XOR-swizzled
    __shared__ __bf16 Vs[2][128 * 64];   // [d][kv] bf16, XOR-swizzled
    __shared__ __bf16 Ps[8][2048];       // wave-private: 2 subtiles x 16x64
    const int tid = threadIdx.x, lane = tid & 63, wave = tid >> 6;
    const int pair = blockIdx.x, h = blockIdx.y, b = blockIdx.z;
    const int kvh = h >> 2;
    const int lo = lane & 15, hi = lane >> 4;
    char* PsW = (char*)&Ps[wave][0];

    const unsigned char* kbb = kb8 + (size_t)b * S_LEN * 512 + kvh * HD;
    const __bf16* vbb = vtb + (size_t)(b * NKV + kvh) * HD * S_LEN;

    const int krow_s = tid >> 3;                // 0..63
    const int kp_s   = tid & 7;
    const int vrow_s = wave * 8 + (lane >> 3);  // + r*64
    const int vp_s   = lane & 7;

    auto STAGE_K = [&](int buf, int t) {        // 8 KB: ONE gld16
        int c = kp_s ^ (krow_s & 7);
        gld16(kbb + (size_t)(t * 64 + krow_s) * 512 + c * 16,
              &Ks8[buf][wave * 1024]);
    };
    auto STAGE_V = [&](int buf, int t) {
#pragma unroll
        for (int r = 0; r < 2; r++) {
            int row = r * 64 + vrow_s;
            int c = vp_s ^ (row & 7);
            gld16(vbb + (size_t)row * S_LEN + t * 64 + c * 8,
                  &Vs[buf][(r * 64 + wave * 8) * 64]);
        }
    };

    auto SM = [&](f32x4 (&sc)[4], float& Mr, float& Lr, f32x4 (&o)[8]) {
        float mloc = sc[0][0];
#pragma unroll
        for (int nt = 0; nt < 4; nt++)
#pragma unroll
            for (int r = 0; r < 4; r++) mloc = fmaxf(mloc, sc[nt][r]);
        mloc = fmaxf(mloc, __shfl_xor(mloc, 16, 64));
        mloc = fmaxf(mloc, __shfl_xor(mloc, 32, 64));
        float mn = (mloc <= Mr + 8.f) ? Mr : mloc;
        float sum = 0.f;
#pragma unroll
        for (int nt = 0; nt < 4; nt++)
#pragma unroll
            for (int r = 0; r < 4; r++) {
                float e = __expf(sc[nt][r] - mn);
                sc[nt][r] = e;
                sum += e;
            }
        sum += __shfl_xor(sum, 16, 64);
        sum += __shfl_xor(sum, 32, 64);
        if (mn != Mr) {
            float scl = __expf(Mr - mn);
            Lr = Lr * scl + sum;
            Mr = mn;
#pragma unroll
            for (int dt = 0; dt < 8; dt++) o[dt] *= scl;
        } else {
            Lr += sum;
        }
    };

#pragma unroll 1
    for (int pi = 0; pi < 2; pi++) {
        const int qt = pi ? (NQT2 - 1 - pair) : pair;  // 256-row q-tile index
        const int nkv = 4 * qt + 4;                    // kv tiles of 64 rows
        const int qbase = qt * 256 + wave * 32;        // this wave's 32 q-rows

        const unsigned char* qp0 = qb8 + (size_t)(b * S_LEN + qbase + lo) * HID + h * HD;
        const unsigned char* qp1 = qp0 + (size_t)16 * HID;
        long qa0[4], qa1[4];
#pragma unroll
        for (int kf = 0; kf < 4; kf++) {
            qa0[kf] = *(const long*)(qp0 + kf * 32 + hi * 8);
            qa1[kf] = *(const long*)(qp1 + kf * 32 + hi * 8);
        }

        f32x4 o0[8] = {}, o1[8] = {};
        float Mr0 = -3e30f, Lr0 = 0.f, Mr1 = -3e30f, Lr1 = 0.f;

        int cur = 0;
        if (pi == 1) __syncthreads();
        STAGE_K(0, 0);
        STAGE_V(0, 0);
        __syncthreads();

#pragma unroll 1
        for (int t = 0; t < nkv; t++) {
            if (t < nkv - 1) { STAGE_K(cur ^ 1, t + 1); STAGE_V(cur ^ 1, t + 1); }

            f32x4 sc0[4], sc1[4];
            __builtin_amdgcn_s_setprio(1);
#pragma unroll
            for (int nt = 0; nt < 4; nt++) {
                f32x4 a = {0.f, 0.f, 0.f, 0.f}, bb = {0.f, 0.f, 0.f, 0.f};
#pragma unroll
                for (int kf = 0; kf < 4; kf++) {
                    int row = nt * 16 + lo;
                    int lch = 2 * kf + (hi >> 1);
                    long kf8 = *(const long*)&Ks8[cur][row * 128 +
                                ((lch ^ (row & 7)) * 16) + (hi & 1) * 8];
                    a  = __builtin_amdgcn_mfma_f32_16x16x32_fp8_fp8(kf8, qa0[kf], a, 0, 0, 0);
                    bb = __builtin_amdgcn_mfma_f32_16x16x32_fp8_fp8(kf8, qa1[kf], bb, 0, 0, 0);
                }
                sc0[nt] = a; sc1[nt] = bb;
            }
            __builtin_amdgcn_s_setprio(0);

            if (t * 64 + 63 > qbase) {
                int qg = qbase + lo;
#pragma unroll
                for (int nt = 0; nt < 4; nt++)
#pragma unroll
                    for (int r = 0; r < 4; r++) {
                        int kg = t * 64 + nt * 16 + hi * 4 + r;
                        if (kg > qg) sc0[nt][r] = -1e30f;
                    }
            }
            if (t * 64 + 63 > qbase + 16) {
                int qg = qbase + 16 + lo;
#pragma unroll
                for (int nt = 0; nt < 4; nt++)
#pragma unroll
                    for (int r = 0; r < 4; r++) {
                        int kg = t * 64 + nt * 16 + hi * 4 + r;
                        if (kg > qg) sc1[nt][r] = -1e30f;
                    }
            }

            SM(sc0, Mr0, Lr0, o0);
            SM(sc1, Mr1, Lr1, o1);

#pragma unroll
            for (int nt = 0; nt < 4; nt++) {
                bf16x4 p0, p1;
#pragma unroll
                for (int r = 0; r < 4; r++) { p0[r] = (__bf16)sc0[nt][r]; p1[r] = (__bf16)sc1[nt][r]; }
                int off = lo * 128 + ((nt * 32 + hi * 8) ^ ((lo & 7) << 4));
                *(bf16x4*)(PsW + off)        = p0;
                *(bf16x4*)(PsW + 2048 + off) = p1;
            }
            asm volatile("s_waitcnt lgkmcnt(0)" ::: "memory");
            bf16x8 pf0[2], pf1[2];
#pragma unroll
            for (int c = 0; c < 2; c++) {
                int off = lo * 128 + ((c * 64 + hi * 16) ^ ((lo & 7) << 4));
                pf0[c] = *(const bf16x8*)(PsW + off);
                pf1[c] = *(const bf16x8*)(PsW + 2048 + off);
            }
            __builtin_amdgcn_s_setprio(1);
#pragma unroll
            for (int dt = 0; dt < 8; dt++) {
                int rowd = dt * 16 + lo;
#pragma unroll
                for (int c = 0; c < 2; c++) {
                    int ch = c * 4 + hi;
                    bf16x8 vv = *(const bf16x8*)&Vs[cur][rowd * 64 + (ch ^ (rowd & 7)) * 8];
                    o0[dt] = __builtin_amdgcn_mfma_f32_16x16x32_bf16(vv, pf0[c], o0[dt], 0, 0, 0);
                    o1[dt] = __builtin_amdgcn_mfma_f32_16x16x32_bf16(vv, pf1[c], o1[dt], 0, 0, 0);
                }
            }
            __builtin_amdgcn_s_setprio(0);
            __syncthreads();
            cur ^= 1;
        }

        const int qe = lane >> 2, c4 = lane & 3;
#pragma unroll
        for (int sub = 0; sub < 2; sub++) {
            float rl = 1.0f / (sub ? Lr1 : Lr0);
            char* Pp = PsW + sub * 2048;
#pragma unroll
            for (int h2 = 0; h2 < 2; h2++) {
#pragma unroll
                for (int dt4 = 0; dt4 < 4; dt4++) {
                    f32x4 ov = sub ? o1[h2 * 4 + dt4] : o0[h2 * 4 + dt4];
                    bf16x4 w;
#pragma unroll
                    for (int r = 0; r < 4; r++) w[r] = (__bf16)(ov[r] * rl);
                    *(bf16x4*)(Pp + lo * 128 + ((dt4 * 32 + hi * 8) ^ ((lo & 7) << 4))) = w;
                }
                asm volatile("s_waitcnt lgkmcnt(0)" ::: "memory");
                __builtin_amdgcn_sched_barrier(0);
#pragma unroll
                for (int s2 = 0; s2 < 2; s2++) {
                    int ch = c4 + s2 * 4;
                    bf16x8 v = *(const bf16x8*)(Pp + qe * 128 + ((ch * 16) ^ ((qe & 7) << 4)));
                    int qg = qbase + sub * 16 + qe;
                    int col = h * HD + h2 * 64 + ch * 8;
                    *(bf16x8*)&ob[(size_t)(b * S_LEN + qg) * HID + col] = v;
                }
            }
        }
    }
}

// ----------------------------------- host -----------------------------------
extern "C" void kernel_launch(void* const* d_in, const int* in_sizes, int n_in,
                              void* d_out, int out_size, void* d_ws, size_t ws_size,
                              hipStream_t stream) {
    (void)in_sizes; (void)n_in; (void)out_size; (void)ws_size;
    const float* x    = (const float*)d_in[0];
    const float* cosp = (const float*)d_in[1];
    const float* sinp = (const float*)d_in[2];
    const float* Wq   = (const float*)d_in[3];
    const float* Wk   = (const float*)d_in[4];
    const float* Wv   = (const float*)d_in[5];
    const float* Wo   = (const float*)d_in[6];
    float* out = (float*)d_out;

    char* ws = (char*)d_ws;
    __bf16*        xb   = (__bf16*)(ws);               // [8192][2048] bf16  32 MB
    __bf16*        wqt  = (__bf16*)(ws + 33554432);    // [2048][2048]        8 MB
    __bf16*        wkvt = (__bf16*)(ws + 41943040);    // [1024][2048] (k|v)  4 MB (contig with wqt)
    __bf16*        wot  = (__bf16*)(ws + 46137344);    // [2048][2048]        8 MB
    unsigned char* qb8  = (unsigned char*)(ws + 54525952);  // [8192][2048] fp8 16 MB
    unsigned char* kb8  = (unsigned char*)(ws + 71303168);  // [8192][512]  fp8  4 MB
    __bf16*        vtb  = (__bf16*)(ws + 75497472);    // [16][128][2048] bf16 8 MB
    __bf16*        aob  = xb;                          // reuse xb after QKV GEMMs

    k_conv_x<<<MTOT * HID / 8 / 256, 256, 0, stream>>>(x, xb);
    { dim3 g(32, 32, 4);
      k_transpose_all<<<g, 256, 0, stream>>>(Wq, Wk, Wv, Wo, wqt, wkvt, wot); }

    k_gemm_q8<<<256, 512, 0, stream>>>(xb, wqt, qb8, cosp, sinp);
    { dim3 g(64, 8); k_gemm_kv<<<g, 256, 0, stream>>>(xb, wqt, kb8, vtb, cosp, sinp); }

    { dim3 g(NQT2 / 2, 16, BATCH); k_attn<<<g, 512, 0, stream>>>(qb8, kb8, vtb, aob); }

    k_gemm_o8<<<256, 512, 0, stream>>>(aob, wot, out);
}

// Round 16
// 300.312 us; speedup vs baseline: 1.5194x; 1.0630x over previous
//
#include <hip/hip_runtime.h>
#include <stdint.h>

#define S_LEN 2048
#define BATCH 4
#define HID   2048
#define HD    128
#define NKV   4
#define MTOT  (BATCH*S_LEN) // 8192
#define NQT2  (S_LEN/256)   // 8 q-tiles (256 rows) per (b,h)
#define QSCALE 0.08838834764831845f
#define LOG2E  1.4426950408889634f

// native v_exp_f32 (2^x)
#define EXP2F(x) __builtin_amdgcn_exp2f(x)

typedef float    f32x4  __attribute__((ext_vector_type(4)));
typedef __bf16   bf16x8 __attribute__((ext_vector_type(8)));
typedef __bf16   bf16x4 __attribute__((ext_vector_type(4)));
typedef unsigned u32x2  __attribute__((ext_vector_type(2)));

// async global->LDS, 16B per lane. LDS dest = wave-uniform base + lane*16.
__device__ __forceinline__ void gld16(const void* g, void* l) {
    __builtin_amdgcn_global_load_lds(
        (const __attribute__((address_space(1))) void*)g,
        (__attribute__((address_space(3))) void*)l, 16, 0, 0);
}

// ---------------- fp32 -> bf16 bulk convert (8 elems/thread) ----------------
__global__ void k_conv_x(const float* __restrict__ in, __bf16* __restrict__ out) {
    int i = blockIdx.x * blockDim.x + threadIdx.x;
    f32x4 a = ((const f32x4*)in)[2 * i];
    f32x4 b = ((const f32x4*)in)[2 * i + 1];
    bf16x8 o;
    o[0] = (__bf16)a[0]; o[1] = (__bf16)a[1]; o[2] = (__bf16)a[2]; o[3] = (__bf16)a[3];
    o[4] = (__bf16)b[0]; o[5] = (__bf16)b[1]; o[6] = (__bf16)b[2]; o[7] = (__bf16)b[3];
    ((bf16x8*)out)[i] = o;
}

// ---- ALL weight transposes in one launch: W [K][N] fp32 -> Wt [N][K] bf16 --
__global__ void k_transpose_all(const float* __restrict__ Wq,
                                const float* __restrict__ Wk,
                                const float* __restrict__ Wv,
                                const float* __restrict__ Wo,
                                __bf16* __restrict__ wqt,
                                __bf16* __restrict__ wkvt,
                                __bf16* __restrict__ wot) {
    const int z = blockIdx.z;
    const float* in; __bf16* out; int N;
    if      (z == 0) { in = Wq; out = wqt;  N = 2048; }
    else if (z == 1) { in = Wk; out = wkvt; N = 512;  }
    else if (z == 2) { in = Wv; out = wkvt + (size_t)512 * HID; N = 512; }
    else             { in = Wo; out = wot;  N = 2048; }
    int k0 = blockIdx.x * 64, n0 = blockIdx.y * 64;
    if (n0 >= N) return;
    __shared__ float tile[64][65];
    for (int e = threadIdx.x; e < 4096; e += 256) {
        int r = e >> 6, c = e & 63;
        tile[r][c] = in[(size_t)(k0 + r) * N + n0 + c];
    }
    __syncthreads();
    for (int e = threadIdx.x; e < 4096; e += 256) {
        int r = e >> 6, c = e & 63;
        out[(size_t)(n0 + r) * HID + k0 + c] = (__bf16)tile[c][r];
    }
}

// ============== 8-phase deep-pipeline K-loop (validated R13) ================
// Barriers MUST be memory-fenced asm ("s_barrier" ::: "memory"): the bare
// builtin is IntrNoMem and the compiler hoists ds_reads across it (R12 race).
#define BARM asm volatile("s_barrier" ::: "memory")
#define BAR1 do { BARM;                                                       \
                  asm volatile("s_waitcnt lgkmcnt(0)" ::: "memory");          \
                  __builtin_amdgcn_sched_barrier(0); } while (0)
#define BAR2 BARM
#define MM(qm, qn)                                                            \
    do {                                                                      \
        __builtin_amdgcn_s_setprio(1);                                        \
        _Pragma("unroll") for (int ks = 0; ks < 2; ks++)                      \
        _Pragma("unroll") for (int mf = 0; mf < 4; mf++)                      \
        _Pragma("unroll") for (int nf = 0; nf < 2; nf++)                      \
            acc[qm][qn][mf][nf] = __builtin_amdgcn_mfma_f32_16x16x32_bf16(    \
                af[mf][ks], bf[nf][ks], acc[qm][qn][mf][nf], 0, 0, 0);        \
        __builtin_amdgcn_s_setprio(0);                                        \
    } while (0)

// The shared 8-phase K-loop body (BM=BN=256, BK=64, 8 waves 2Mx4N, K=2048,
// LDS 128 KiB). Declares Ab/Bb/acc/af/bf and runs the full 16-iteration loop.
#define GEMM8_BODY(Aptr, Bptr)                                                \
    __shared__ __bf16 Ab[2][2][128 * 64];                                     \
    __shared__ __bf16 Bb[2][2][128 * 64];                                     \
    const int tid = threadIdx.x, lane = tid & 63, wave = tid >> 6;            \
    const int wm = wave >> 2, wn = wave & 3;                                  \
    const int lo = lane & 15, hi = lane >> 4;                                 \
    f32x4 acc[2][2][4][2] = {};                                               \
    const int srow = wave * 8 + (lane >> 3);                                  \
    const int sp   = lane & 7;                                                \
    auto STA = [&](int s, int h, int t) {                                     \
        _Pragma("unroll") for (int p = 0; p < 2; p++) {                       \
            int rr = p * 64 + srow;                                           \
            int c = sp ^ (rr & 7);                                            \
            gld16(Aptr + (size_t)(m0 + h * 128 + rr) * HID + t * 64 + c * 8,  \
                  &Ab[s][h][(p * 64 + wave * 8) * 64]);                       \
        }                                                                     \
    };                                                                        \
    auto STB = [&](int s, int h, int t) {                                     \
        _Pragma("unroll") for (int p = 0; p < 2; p++) {                       \
            int rr = p * 64 + srow;                                           \
            int c = sp ^ (rr & 7);                                            \
            gld16(Bptr + (size_t)(n0 + h * 128 + rr) * HID + t * 64 + c * 8,  \
                  &Bb[s][h][(p * 64 + wave * 8) * 64]);                       \
        }                                                                     \
    };                                                                        \
    bf16x8 af[4][2], bf[2][2];                                                \
    auto LDA = [&](int s, int qm) {                                           \
        _Pragma("unroll") for (int mf = 0; mf < 4; mf++) {                    \
            int rr = wm * 64 + mf * 16 + lo;                                  \
            _Pragma("unroll") for (int ks = 0; ks < 2; ks++) {                \
                int pp = (ks * 4 + hi) ^ (rr & 7);                            \
                af[mf][ks] = *(const bf16x8*)&Ab[s][qm][rr * 64 + pp * 8];    \
            }                                                                 \
        }                                                                     \
    };                                                                        \
    auto LDB = [&](int s, int qn) {                                           \
        _Pragma("unroll") for (int nf = 0; nf < 2; nf++) {                    \
            int rr = wn * 32 + nf * 16 + lo;                                  \
            _Pragma("unroll") for (int ks = 0; ks < 2; ks++) {                \
                int pp = (ks * 4 + hi) ^ (rr & 7);                            \
                bf[nf][ks] = *(const bf16x8*)&Bb[s][qn][rr * 64 + pp * 8];    \
            }                                                                 \
        }                                                                     \
    };                                                                        \
    STA(0, 0, 0); STB(0, 0, 0); STA(0, 1, 0); STB(0, 1, 0);                   \
    STA(1, 1, 1); STB(1, 1, 1);                                               \
    asm volatile("s_waitcnt vmcnt(4)" ::: "memory");                          \
    BARM;                                                                     \
    _Pragma("unroll 1")                                                       \
    for (int i = 0; i < 16; i++) {                                            \
        const int t0 = 2 * i, t1 = 2 * i + 1;                                 \
        const bool more = (i < 15);                                           \
        LDA(0, 0); LDB(0, 0);                                                 \
        STA(1, 0, t1); STB(1, 0, t1);                                         \
        BAR1; MM(0, 0); BAR2;                                                 \
        LDB(0, 1);                                                            \
        BAR1; MM(0, 1); BAR2;                                                 \
        LDA(0, 1); LDB(0, 0);                                                 \
        if (more) STA(0, 0, t0 + 2);                                          \
        BAR1; MM(1, 0); BAR2;                                                 \
        LDB(0, 1);                                                            \
        if (more) STB(0, 0, t0 + 2);                                          \
        BAR1; MM(1, 1);                                                       \
        if (more) { asm volatile("s_waitcnt vmcnt(4)" ::: "memory"); }        \
        else      { asm volatile("s_waitcnt vmcnt(0)" ::: "memory"); }        \
        BAR2;                                                                 \
        LDA(1, 1); LDB(1, 1);                                                 \
        if (more) { STA(0, 1, t0 + 2); STB(0, 1, t0 + 2); }                   \
        BAR1; MM(1, 1); BAR2;                                                 \
        LDB(1, 0);                                                            \
        BAR1; MM(1, 0); BAR2;                                                 \
        LDA(1, 0); LDB(1, 1);                                                 \
        if (more) STA(1, 1, t1 + 2);                                          \
        BAR1; MM(0, 1); BAR2;                                                 \
        LDB(1, 0);                                                            \
        if (more) STB(1, 1, t1 + 2);                                          \
        BAR1; MM(0, 0);                                                       \
        if (more) { asm volatile("s_waitcnt vmcnt(4)" ::: "memory"); }        \
        BAR2;                                                                 \
    }

// -------- Q-proj GEMM, 8-phase: qb8 fp8 = rope(xb*wqt^T)*QSCALE*log2e -------
// grid 256 = (m 32) x (n 8) = exactly 1 block/CU. log2e folded into the fp8
// scale so k_attn's softmax can use native exp2 (v_exp_f32).
__global__ __launch_bounds__(512) void k_gemm_q8(const __bf16* __restrict__ A,
                                                 const __bf16* __restrict__ Bt,
                                                 unsigned char* __restrict__ qb8,
                                                 const float* __restrict__ cosp,
                                                 const float* __restrict__ sinp) {
    const int m0 = (blockIdx.x >> 3) * 256;
    const int n0 = (blockIdx.x & 7) * 256;
    GEMM8_BODY(A, Bt)

    // epilogue: per-quadrant LDS stage -> rope + scale + fp8 -> store.
    __bf16* Cs = (__bf16*)&Ab[0][0][0];            // [128][132]
    const int crow = tid >> 4;                     // 0..31 (+32 per rep)
    const int cch  = tid & 15;                     // 8-col chunk
    const int d0 = cch * 8;
    const float QS2 = QSCALE * LOG2E;
#pragma unroll
    for (int qm = 0; qm < 2; qm++)
#pragma unroll
        for (int qn = 0; qn < 2; qn++) {
#pragma unroll
            for (int mf = 0; mf < 4; mf++)
#pragma unroll
                for (int nf = 0; nf < 2; nf++) {
                    int rl = wm * 64 + mf * 16 + hi * 4;
                    int cl = wn * 32 + nf * 16 + lo;
#pragma unroll
                    for (int r = 0; r < 4; r++)
                        Cs[(rl + r) * 132 + cl] = (__bf16)acc[qm][qn][mf][nf][r];
                }
            __syncthreads();
#pragma unroll
            for (int rep = 0; rep < 4; rep++) {
                int row = rep * 32 + crow;
                int rowg = m0 + qm * 128 + row;
                int colg = n0 + qn * 128 + cch * 8;
                bf16x8 v = *(const bf16x8*)&Cs[row * 132 + cch * 8];
                float f[8];
#pragma unroll
                for (int j = 0; j < 8; j++) f[j] = (float)v[j];
                int s = rowg & (S_LEN - 1);
                f32x4 c0 = *(const f32x4*)&cosp[s * HD + d0];
                f32x4 c1 = *(const f32x4*)&cosp[s * HD + d0 + 4];
                f32x4 s0 = *(const f32x4*)&sinp[s * HD + d0];
                f32x4 s1 = *(const f32x4*)&sinp[s * HD + d0 + 4];
                float cc[8] = {c0[0], c0[1], c0[2], c0[3], c1[0], c1[1], c1[2], c1[3]};
                float ss[8] = {s0[0], s0[1], s0[2], s0[3], s1[0], s1[1], s1[2], s1[3]};
#pragma unroll
                for (int p = 0; p < 4; p++) {
                    float e0 = f[2 * p], e1 = f[2 * p + 1];
                    f[2 * p]     = (e0 * cc[2 * p]     - e1 * ss[2 * p])     * QS2;
                    f[2 * p + 1] = (e1 * cc[2 * p + 1] + e0 * ss[2 * p + 1]) * QS2;
                }
                int u0 = __builtin_amdgcn_cvt_pk_fp8_f32(f[0], f[1], 0, false);
                u0     = __builtin_amdgcn_cvt_pk_fp8_f32(f[2], f[3], u0, true);
                int u1 = __builtin_amdgcn_cvt_pk_fp8_f32(f[4], f[5], 0, false);
                u1     = __builtin_amdgcn_cvt_pk_fp8_f32(f[6], f[7], u1, true);
                u32x2 pk; pk[0] = (unsigned)u0; pk[1] = (unsigned)u1;
                *(u32x2*)&qb8[(size_t)rowg * HID + colg] = pk;
            }
            __syncthreads();
        }
}

// -------- O-proj GEMM, 8-phase (validated R13): out[8192][2048] f32 ---------
__global__ __launch_bounds__(512) void k_gemm_o8(const __bf16* __restrict__ A,
                                                 const __bf16* __restrict__ Bt,
                                                 float* __restrict__ Cp) {
    const int m0 = (blockIdx.x >> 3) * 256;
    const int n0 = (blockIdx.x & 7) * 256;
    GEMM8_BODY(A, Bt)

#pragma unroll
    for (int qm = 0; qm < 2; qm++)
#pragma unroll
        for (int qn = 0; qn < 2; qn++)
#pragma unroll
            for (int mf = 0; mf < 4; mf++)
#pragma unroll
                for (int nf = 0; nf < 2; nf++) {
                    int row = m0 + qm * 128 + wm * 64 + mf * 16 + hi * 4;
                    int col = n0 + qn * 128 + wn * 32 + nf * 16 + lo;
#pragma unroll
                    for (int r = 0; r < 4; r++)
                        Cp[(size_t)(row + r) * HID + col] = acc[qm][qn][mf][nf][r];
                }
}

// ---- KV-proj GEMM (m97 structure): C[8192][1024] = xb * wkvt^T -------------
// grid (64, 8): n0 = 2048 + by*128. cols [2048,2560) -> k rope+fp8 -> kb8;
// [2560,3072) -> v transposed -> vtb. NOTE: K gets NO log2e (Q carries it).
__global__ __launch_bounds__(256) void k_gemm_kv(const __bf16* __restrict__ A,
                                                 const __bf16* __restrict__ Bt,
                                                 unsigned char* __restrict__ kb8,
                                                 __bf16* __restrict__ vtb,
                                                 const float* __restrict__ cosp,
                                                 const float* __restrict__ sinp) {
    __shared__ __align__(16) char smem[33792];
    __bf16* As = (__bf16*)smem;
    __bf16* Bs = (__bf16*)(smem + 16384);
    const int tid = threadIdx.x, lane = tid & 63, wave = tid >> 6;
    const int wm = wave >> 1, wn = wave & 1;
    const int m0 = blockIdx.x * 128;
    const int n0 = 2048 + blockIdx.y * 128;
    const int lo = lane & 15, hi = lane >> 4;
    f32x4 acc[4][4] = {};

    const int srow = wave * 8 + (lane >> 3);
    const int sp   = lane & 7;

    for (int kt = 0; kt < HID; kt += 64) {
#pragma unroll
        for (int r = 0; r < 4; r++) {
            int row = r * 32 + srow;
            int c = sp ^ (row & 7);
            gld16(A + (size_t)(m0 + row) * HID + kt + c * 8, &As[(r * 32 + wave * 8) * 64]);
        }
#pragma unroll
        for (int r = 0; r < 4; r++) {
            int row = r * 32 + srow;
            int c = sp ^ (row & 7);
            gld16(Bt + (size_t)(n0 + row) * HID + kt + c * 8, &Bs[(r * 32 + wave * 8) * 64]);
        }
        __syncthreads();
#pragma unroll
        for (int ks = 0; ks < 2; ks++) {
            bf16x8 af[4], bfr[4];
#pragma unroll
            for (int mt = 0; mt < 4; mt++) {
                int row = wm * 64 + mt * 16 + lo;
                int pp = (ks * 4 + hi) ^ (row & 7);
                af[mt] = *(const bf16x8*)&As[row * 64 + pp * 8];
            }
#pragma unroll
            for (int nt = 0; nt < 4; nt++) {
                int row = wn * 64 + nt * 16 + lo;
                int pp = (ks * 4 + hi) ^ (row & 7);
                bfr[nt] = *(const bf16x8*)&Bs[row * 64 + pp * 8];
            }
#pragma unroll
            for (int mt = 0; mt < 4; mt++)
#pragma unroll
                for (int nt = 0; nt < 4; nt++)
                    acc[mt][nt] = __builtin_amdgcn_mfma_f32_16x16x32_bf16(
                        af[mt], bfr[nt], acc[mt][nt], 0, 0, 0);
        }
        __syncthreads();
    }

    if (n0 < 2560) {
        __bf16* Cs = (__bf16*)smem;                 // [128][132]
#pragma unroll
        for (int mt = 0; mt < 4; mt++)
#pragma unroll
            for (int nt = 0; nt < 4; nt++) {
                int rl = wm * 64 + mt * 16 + hi * 4;
                int cl = wn * 64 + nt * 16 + lo;
#pragma unroll
                for (int r = 0; r < 4; r++)
                    Cs[(rl + r) * 132 + cl] = (__bf16)acc[mt][nt][r];
            }
        __syncthreads();

        const int crow = tid >> 4;
        const int cch  = tid & 15;
        const int colg = n0 + cch * 8;
        const int d0 = colg & (HD - 1);
#pragma unroll
        for (int rep = 0; rep < 8; rep++) {
            int row = rep * 16 + crow;
            int rowg = m0 + row;
            bf16x8 v = *(const bf16x8*)&Cs[row * 132 + cch * 8];
            float f[8];
#pragma unroll
            for (int j = 0; j < 8; j++) f[j] = (float)v[j];
            int s = rowg & (S_LEN - 1);
            f32x4 c0 = *(const f32x4*)&cosp[s * HD + d0];
            f32x4 c1 = *(const f32x4*)&cosp[s * HD + d0 + 4];
            f32x4 s0 = *(const f32x4*)&sinp[s * HD + d0];
            f32x4 s1 = *(const f32x4*)&sinp[s * HD + d0 + 4];
            float cc[8] = {c0[0], c0[1], c0[2], c0[3], c1[0], c1[1], c1[2], c1[3]};
            float ss[8] = {s0[0], s0[1], s0[2], s0[3], s1[0], s1[1], s1[2], s1[3]};
#pragma unroll
            for (int p = 0; p < 4; p++) {
                float e0 = f[2 * p], e1 = f[2 * p + 1];
                f[2 * p]     = e0 * cc[2 * p]     - e1 * ss[2 * p];
                f[2 * p + 1] = e1 * cc[2 * p + 1] + e0 * ss[2 * p + 1];
            }
            int u0 = __builtin_amdgcn_cvt_pk_fp8_f32(f[0], f[1], 0, false);
            u0     = __builtin_amdgcn_cvt_pk_fp8_f32(f[2], f[3], u0, true);
            int u1 = __builtin_amdgcn_cvt_pk_fp8_f32(f[4], f[5], 0, false);
            u1     = __builtin_amdgcn_cvt_pk_fp8_f32(f[6], f[7], u1, true);
            u32x2 pk; pk[0] = (unsigned)u0; pk[1] = (unsigned)u1;
            *(u32x2*)&kb8[(size_t)rowg * 512 + (colg - 2048)] = pk;
        }
    } else {
        __bf16* CsT = (__bf16*)smem;                // [128 cols][132 rows pad]
#pragma unroll
        for (int mt = 0; mt < 4; mt++)
#pragma unroll
            for (int nt = 0; nt < 4; nt++) {
                int cl = wn * 64 + nt * 16 + lo;
                int mrow = wm * 64 + mt * 16 + hi * 4;
                bf16x4 w;
#pragma unroll
                for (int r = 0; r < 4; r++) w[r] = (__bf16)acc[mt][nt][r];
                *(bf16x4*)&CsT[cl * 132 + mrow] = w;
            }
        __syncthreads();

        const int kvh = (n0 - 2560) >> 7;
        const int bb = m0 >> 11;
        const int s0 = m0 & (S_LEN - 1);
        __bf16* dst = vtb + (size_t)(bb * NKV + kvh) * HD * S_LEN;
        const int dloc = tid >> 4;
        const int sch  = tid & 15;
#pragma unroll
        for (int rep = 0; rep < 8; rep++) {
            int d = rep * 16 + dloc;
            bf16x8 v = *(const bf16x8*)&CsT[d * 132 + sch * 8];
            *(bf16x8*)&dst[(size_t)d * S_LEN + s0 + sch * 8] = v;
        }
    }
}

// ----------------------------- flash attention ------------------------------
// KVBLK=128 (halves barriers/reduces vs 64); QK^T fp8 (Q pre-scaled by
// QSCALE*log2e -> softmax uses native exp2 via __builtin_amdgcn_exp2f).
// PV bf16 in two 64-kv halves (Ps reused; lgkm+sched_barrier guards the WAR).
// Per wave: 32 q-rows (2 subtiles), all K/V LDS reads shared. Grid 256 = 1/CU.
// LDS: Ks8 2x16K + Vs 2x32K + Ps 32K = 128 KB.
__global__ __launch_bounds__(512) void k_attn(const unsigned char* __restrict__ qb8,
                                              const unsigned char* __restrict__ kb8,
                                              const __bf16* __restrict__ vtb,
                                              __bf16* __restrict__ ob) {
    __shared__ char   Ks8[2][128 * 128];  // [kv][128B fp8 d], 8-chunk XOR swz
    __shared__ __bf16 Vs[2][128 * 128];   // [d][kv 128] bf16, 16-chunk XOR swz
    __shared__ __bf16 Ps[8][2048];        // wave-private: 2 subtiles x 16x64
    const int tid = threadIdx.x, lane = tid & 63, wave = tid >> 6;
    const int pair = blockIdx.x, h = blockIdx.y, b = blockIdx.z;
    const int kvh = h >> 2;
    const int lo = lane & 15, hi = lane >> 4;
    char* PsW = (char*)&Ps[wave][0];

    const unsigned char* kbb = kb8 + (size_t)b * S_LEN * 512 + kvh * HD;
    const __bf16* vbb = vtb + (size_t)(b * NKV + kvh) * HD * S_LEN;

    const int krow_s = tid >> 3;                // 0..63 (+64 per round)
    const int kp_s   = tid & 7;
    const int vrow_s = tid >> 4;                // 0..31 (+32 per round)
    const int vp_s   = tid & 15;

    auto STAGE_K = [&](int buf, int t) {        // 16 KB: 2 gld16 rounds
#pragma unroll
        for (int r = 0; r < 2; r++) {
            int row = r * 64 + krow_s;
            int c = kp_s ^ (row & 7);
            gld16(kbb + (size_t)(t * 128 + row) * 512 + c * 16,
                  &Ks8[buf][(r * 64 + wave * 8) * 128]);
        }
    };
    auto STAGE_V = [&](int buf, int t) {        // 32 KB: 4 gld16 rounds
#pragma unroll
        for (int r = 0; r < 4; r++) {
            int row = r * 32 + vrow_s;          // d-row
            int c = vp_s ^ (row & 15);
            gld16(vbb + (size_t)row * S_LEN + t * 128 + c * 8,
                  &Vs[buf][(r * 32 + wave * 4) * 128]);
        }
    };

    // online softmax over 32 in-lane scores (exp2 domain; T13 defer thr=8)
    auto SM = [&](f32x4 (&sc)[8], float& Mr, float& Lr, f32x4 (&o)[8]) {
        float mloc = sc[0][0];
#pragma unroll
        for (int nt = 0; nt < 8; nt++)
#pragma unroll
            for (int r = 0; r < 4; r++) mloc = fmaxf(mloc, sc[nt][r]);
        mloc = fmaxf(mloc, __shfl_xor(mloc, 16, 64));
        mloc = fmaxf(mloc, __shfl_xor(mloc, 32, 64));
        float mn = (mloc <= Mr + 8.f) ? Mr : mloc;
        float sum = 0.f;
#pragma unroll
        for (int nt = 0; nt < 8; nt++)
#pragma unroll
            for (int r = 0; r < 4; r++) {
                float e = EXP2F(sc[nt][r] - mn);
                sc[nt][r] = e;
                sum += e;
            }
        sum += __shfl_xor(sum, 16, 64);
        sum += __shfl_xor(sum, 32, 64);
        if (mn != Mr) {
            float scl = EXP2F(Mr - mn);
            Lr = Lr * scl + sum;
            Mr = mn;
#pragma unroll
            for (int dt = 0; dt < 8; dt++) o[dt] *= scl;
        } else {
            Lr += sum;
        }
    };

#pragma unroll 1
    for (int pi = 0; pi < 2; pi++) {
        const int qt = pi ? (NQT2 - 1 - pair) : pair;  // 256-row q-tile index
        const int nkv = 2 * qt + 2;                    // kv tiles of 128 rows
        const int qbase = qt * 256 + wave * 32;        // this wave's 32 q-rows

        const unsigned char* qp0 = qb8 + (size_t)(b * S_LEN + qbase + lo) * HID + h * HD;
        const unsigned char* qp1 = qp0 + (size_t)16 * HID;
        long qa0[4], qa1[4];
#pragma unroll
        for (int kf = 0; kf < 4; kf++) {
            qa0[kf] = *(const long*)(qp0 + kf * 32 + hi * 8);
            qa1[kf] = *(const long*)(qp1 + kf * 32 + hi * 8);
        }

        f32x4 o0[8] = {}, o1[8] = {};
        float Mr0 = -3e30f, Lr0 = 0.f, Mr1 = -3e30f, Lr1 = 0.f;

        int cur = 0;
        if (pi == 1) __syncthreads();
        STAGE_K(0, 0);
        STAGE_V(0, 0);
        __syncthreads();

#pragma unroll 1
        for (int t = 0; t < nkv; t++) {
            if (t < nkv - 1) { STAGE_K(cur ^ 1, t + 1); STAGE_V(cur ^ 1, t + 1); }

            // S^T = K Q^T (fp8), 8 nt-rows of 16 kv, both subtiles share K
            f32x4 sc0[8], sc1[8];
            __builtin_amdgcn_s_setprio(1);
#pragma unroll
            for (int nt = 0; nt < 8; nt++) {
                f32x4 a = {0.f, 0.f, 0.f, 0.f}, bb = {0.f, 0.f, 0.f, 0.f};
#pragma unroll
                for (int kf = 0; kf < 4; kf++) {
                    int row = nt * 16 + lo;
                    int lch = 2 * kf + (hi >> 1);
                    long kf8 = *(const long*)&Ks8[cur][row * 128 +
                                ((lch ^ (row & 7)) * 16) + (hi & 1) * 8];
                    a  = __builtin_amdgcn_mfma_f32_16x16x32_fp8_fp8(kf8, qa0[kf], a, 0, 0, 0);
                    bb = __builtin_amdgcn_mfma_f32_16x16x32_fp8_fp8(kf8, qa1[kf], bb, 0, 0, 0);
                }
                sc0[nt] = a; sc1[nt] = bb;
            }
            __builtin_amdgcn_s_setprio(0);

            // causal mask (wave-uniform guard per subtile)
            if (t * 128 + 127 > qbase) {
                int qg = qbase + lo;
#pragma unroll
                for (int nt = 0; nt < 8; nt++)
#pragma unroll
                    for (int r = 0; r < 4; r++) {
                        int kg = t * 128 + nt * 16 + hi * 4 + r;
                        if (kg > qg) sc0[nt][r] = -1e30f;
                    }
            }
            if (t * 128 + 127 > qbase + 16) {
                int qg = qbase + 16 + lo;
#pragma unroll
                for (int nt = 0; nt < 8; nt++)
#pragma unroll
                    for (int r = 0; r < 4; r++) {
                        int kg = t * 128 + nt * 16 + hi * 4 + r;
                        if (kg > qg) sc1[nt][r] = -1e30f;
                    }
            }

            SM(sc0, Mr0, Lr0, o0);
            SM(sc1, Mr1, Lr1, o1);

            // PV in two 64-kv halves; Ps reused between halves (WAR guarded)
#pragma unroll
            for (int hh = 0; hh < 2; hh++) {
#pragma unroll
                for (int ntl = 0; ntl < 4; ntl++) {
                    int nt = hh * 4 + ntl;
                    bf16x4 p0, p1;
#pragma unroll
                    for (int r = 0; r < 4; r++) { p0[r] = (__bf16)sc0[nt][r]; p1[r] = (__bf16)sc1[nt][r]; }
                    int off = lo * 128 + ((ntl * 32 + hi * 8) ^ ((lo & 7) << 4));
                    *(bf16x4*)(PsW + off)        = p0;
                    *(bf16x4*)(PsW + 2048 + off) = p1;
                }
                asm volatile("s_waitcnt lgkmcnt(0)" ::: "memory");
                bf16x8 pf0[2], pf1[2];
#pragma unroll
                for (int c = 0; c < 2; c++) {
                    int off = lo * 128 + ((c * 64 + hi * 16) ^ ((lo & 7) << 4));
                    pf0[c] = *(const bf16x8*)(PsW + off);
                    pf1[c] = *(const bf16x8*)(PsW + 2048 + off);
                }
                // ensure pf reads complete before next half's Ps overwrite
                asm volatile("s_waitcnt lgkmcnt(0)" ::: "memory");
                __builtin_amdgcn_sched_barrier(0);
                __builtin_amdgcn_s_setprio(1);
#pragma unroll
                for (int dt = 0; dt < 8; dt++) {
                    int rowd = dt * 16 + lo;
#pragma unroll
                    for (int c = 0; c < 2; c++) {
                        int gch = hh * 8 + c * 4 + hi;   // chunk in 16-wide row
                        bf16x8 vv = *(const bf16x8*)&Vs[cur][rowd * 128 +
                                     (gch ^ (rowd & 15)) * 8];
                        o0[dt] = __builtin_amdgcn_mfma_f32_16x16x32_bf16(vv, pf0[c], o0[dt], 0, 0, 0);
                        o1[dt] = __builtin_amdgcn_mfma_f32_16x16x32_bf16(vv, pf1[c], o1[dt], 0, 0, 0);
                    }
                }
                __builtin_amdgcn_s_setprio(0);
            }
            __syncthreads();  // drains prefetch; protects both bufs before reuse
            cur ^= 1;
        }

        // epilogue per subtile: O^T -> Ps -> coalesced bf16x8 stores
        const int qe = lane >> 2, c4 = lane & 3;
#pragma unroll
        for (int sub = 0; sub < 2; sub++) {
            float rl = 1.0f / (sub ? Lr1 : Lr0);
            char* Pp = PsW + sub * 2048;
#pragma unroll
            for (int h2 = 0; h2 < 2; h2++) {
#pragma unroll
                for (int dt4 = 0; dt4 < 4; dt4++) {
                    f32x4 ov = sub ? o1[h2 * 4 + dt4] : o0[h2 * 4 + dt4];
                    bf16x4 w;
#pragma unroll
                    for (int r = 0; r < 4; r++) w[r] = (__bf16)(ov[r] * rl);
                    *(bf16x4*)(Pp + lo * 128 + ((dt4 * 32 + hi * 8) ^ ((lo & 7) << 4))) = w;
                }
                asm volatile("s_waitcnt lgkmcnt(0)" ::: "memory");
                __builtin_amdgcn_sched_barrier(0);
#pragma unroll
                for (int s2 = 0; s2 < 2; s2++) {
                    int ch = c4 + s2 * 4;
                    bf16x8 v = *(const bf16x8*)(Pp + qe * 128 + ((ch * 16) ^ ((qe & 7) << 4)));
                    int qg = qbase + sub * 16 + qe;
                    int col = h * HD + h2 * 64 + ch * 8;
                    *(bf16x8*)&ob[(size_t)(b * S_LEN + qg) * HID + col] = v;
                }
            }
        }
    }
}

// ----------------------------------- host -----------------------------------
extern "C" void kernel_launch(void* const* d_in, const int* in_sizes, int n_in,
                              void* d_out, int out_size, void* d_ws, size_t ws_size,
                              hipStream_t stream) {
    (void)in_sizes; (void)n_in; (void)out_size; (void)ws_size;
    const float* x    = (const float*)d_in[0];
    const float* cosp = (const float*)d_in[1];
    const float* sinp = (const float*)d_in[2];
    const float* Wq   = (const float*)d_in[3];
    const float* Wk   = (const float*)d_in[4];
    const float* Wv   = (const float*)d_in[5];
    const float* Wo   = (const float*)d_in[6];
    float* out = (float*)d_out;

    char* ws = (char*)d_ws;
    __bf16*        xb   = (__bf16*)(ws);               // [8192][2048] bf16  32 MB
    __bf16*        wqt  = (__bf16*)(ws + 33554432);    // [2048][2048]        8 MB
    __bf16*        wkvt = (__bf16*)(ws + 41943040);    // [1024][2048] (k|v)  4 MB (contig with wqt)
    __bf16*        wot  = (__bf16*)(ws + 46137344);    // [2048][2048]        8 MB
    unsigned char* qb8  = (unsigned char*)(ws + 54525952);  // [8192][2048] fp8 16 MB
    unsigned char* kb8  = (unsigned char*)(ws + 71303168);  // [8192][512]  fp8  4 MB
    __bf16*        vtb  = (__bf16*)(ws + 75497472);    // [16][128][2048] bf16 8 MB
    __bf16*        aob  = xb;                          // reuse xb after QKV GEMMs

    k_conv_x<<<MTOT * HID / 8 / 256, 256, 0, stream>>>(x, xb);
    { dim3 g(32, 32, 4);
      k_transpose_all<<<g, 256, 0, stream>>>(Wq, Wk, Wv, Wo, wqt, wkvt, wot); }

    k_gemm_q8<<<256, 512, 0, stream>>>(xb, wqt, qb8, cosp, sinp);
    { dim3 g(64, 8); k_gemm_kv<<<g, 256, 0, stream>>>(xb, wqt, kb8, vtb, cosp, sinp); }

    { dim3 g(NQT2 / 2, 16, BATCH); k_attn<<<g, 512, 0, stream>>>(qb8, kb8, vtb, aob); }

    k_gemm_o8<<<256, 512, 0, stream>>>(aob, wot, out);
}

// Round 17
// 299.636 us; speedup vs baseline: 1.5229x; 1.0023x over previous
//
#include <hip/hip_runtime.h>
#include <stdint.h>

#define S_LEN 2048
#define BATCH 4
#define HID   2048
#define HD    128
#define NKV   4
#define MTOT  (BATCH*S_LEN) // 8192
#define NQT2  (S_LEN/256)   // 8 q-tiles (256 rows) per (b,h)
#define QSCALE 0.08838834764831845f
#define LOG2E  1.4426950408889634f

// native v_exp_f32 (2^x)
#define EXP2F(x) __builtin_amdgcn_exp2f(x)

typedef float    f32x4  __attribute__((ext_vector_type(4)));
typedef __bf16   bf16x8 __attribute__((ext_vector_type(8)));
typedef __bf16   bf16x4 __attribute__((ext_vector_type(4)));
typedef unsigned u32x2  __attribute__((ext_vector_type(2)));

// async global->LDS, 16B per lane. LDS dest = wave-uniform base + lane*16.
__device__ __forceinline__ void gld16(const void* g, void* l) {
    __builtin_amdgcn_global_load_lds(
        (const __attribute__((address_space(1))) void*)g,
        (__attribute__((address_space(3))) void*)l, 16, 0, 0);
}

// ---------------- fp32 -> bf16 bulk convert (8 elems/thread) ----------------
__global__ void k_conv_x(const float* __restrict__ in, __bf16* __restrict__ out) {
    int i = blockIdx.x * blockDim.x + threadIdx.x;
    f32x4 a = ((const f32x4*)in)[2 * i];
    f32x4 b = ((const f32x4*)in)[2 * i + 1];
    bf16x8 o;
    o[0] = (__bf16)a[0]; o[1] = (__bf16)a[1]; o[2] = (__bf16)a[2]; o[3] = (__bf16)a[3];
    o[4] = (__bf16)b[0]; o[5] = (__bf16)b[1]; o[6] = (__bf16)b[2]; o[7] = (__bf16)b[3];
    ((bf16x8*)out)[i] = o;
}

// ---- ALL weight transposes in one launch: W [K][N] fp32 -> Wt [N][K] bf16 --
__global__ void k_transpose_all(const float* __restrict__ Wq,
                                const float* __restrict__ Wk,
                                const float* __restrict__ Wv,
                                const float* __restrict__ Wo,
                                __bf16* __restrict__ wqt,
                                __bf16* __restrict__ wkvt,
                                __bf16* __restrict__ wot) {
    const int z = blockIdx.z;
    const float* in; __bf16* out; int N;
    if      (z == 0) { in = Wq; out = wqt;  N = 2048; }
    else if (z == 1) { in = Wk; out = wkvt; N = 512;  }
    else if (z == 2) { in = Wv; out = wkvt + (size_t)512 * HID; N = 512; }
    else             { in = Wo; out = wot;  N = 2048; }
    int k0 = blockIdx.x * 64, n0 = blockIdx.y * 64;
    if (n0 >= N) return;
    __shared__ float tile[64][65];
    for (int e = threadIdx.x; e < 4096; e += 256) {
        int r = e >> 6, c = e & 63;
        tile[r][c] = in[(size_t)(k0 + r) * N + n0 + c];
    }
    __syncthreads();
    for (int e = threadIdx.x; e < 4096; e += 256) {
        int r = e >> 6, c = e & 63;
        out[(size_t)(n0 + r) * HID + k0 + c] = (__bf16)tile[c][r];
    }
}

// ============== 8-phase deep-pipeline K-loop (validated R13) ================
// Barriers MUST be memory-fenced asm ("s_barrier" ::: "memory"): the bare
// builtin is IntrNoMem and the compiler hoists ds_reads across it (R12 race).
#define BARM asm volatile("s_barrier" ::: "memory")
#define BAR1 do { BARM;                                                       \
                  asm volatile("s_waitcnt lgkmcnt(0)" ::: "memory");          \
                  __builtin_amdgcn_sched_barrier(0); } while (0)
#define BAR2 BARM
#define MM(qm, qn)                                                            \
    do {                                                                      \
        __builtin_amdgcn_s_setprio(1);                                        \
        _Pragma("unroll") for (int ks = 0; ks < 2; ks++)                      \
        _Pragma("unroll") for (int mf = 0; mf < 4; mf++)                      \
        _Pragma("unroll") for (int nf = 0; nf < 2; nf++)                      \
            acc[qm][qn][mf][nf] = __builtin_amdgcn_mfma_f32_16x16x32_bf16(    \
                af[mf][ks], bf[nf][ks], acc[qm][qn][mf][nf], 0, 0, 0);        \
        __builtin_amdgcn_s_setprio(0);                                        \
    } while (0)

// The shared 8-phase K-loop body (BM=BN=256, BK=64, 8 waves 2Mx4N, K=2048,
// LDS 128 KiB). Declares Ab/Bb/acc/af/bf and runs the full 16-iteration loop.
#define GEMM8_BODY(Aptr, Bptr)                                                \
    __shared__ __bf16 Ab[2][2][128 * 64];                                     \
    __shared__ __bf16 Bb[2][2][128 * 64];                                     \
    const int tid = threadIdx.x, lane = tid & 63, wave = tid >> 6;            \
    const int wm = wave >> 2, wn = wave & 3;                                  \
    const int lo = lane & 15, hi = lane >> 4;                                 \
    f32x4 acc[2][2][4][2] = {};                                               \
    const int srow = wave * 8 + (lane >> 3);                                  \
    const int sp   = lane & 7;                                                \
    auto STA = [&](int s, int h, int t) {                                     \
        _Pragma("unroll") for (int p = 0; p < 2; p++) {                       \
            int rr = p * 64 + srow;                                           \
            int c = sp ^ (rr & 7);                                            \
            gld16(Aptr + (size_t)(m0 + h * 128 + rr) * HID + t * 64 + c * 8,  \
                  &Ab[s][h][(p * 64 + wave * 8) * 64]);                       \
        }                                                                     \
    };                                                                        \
    auto STB = [&](int s, int h, int t) {                                     \
        _Pragma("unroll") for (int p = 0; p < 2; p++) {                       \
            int rr = p * 64 + srow;                                           \
            int c = sp ^ (rr & 7);                                            \
            gld16(Bptr + (size_t)(n0 + h * 128 + rr) * HID + t * 64 + c * 8,  \
                  &Bb[s][h][(p * 64 + wave * 8) * 64]);                       \
        }                                                                     \
    };                                                                        \
    bf16x8 af[4][2], bf[2][2];                                                \
    auto LDA = [&](int s, int qm) {                                           \
        _Pragma("unroll") for (int mf = 0; mf < 4; mf++) {                    \
            int rr = wm * 64 + mf * 16 + lo;                                  \
            _Pragma("unroll") for (int ks = 0; ks < 2; ks++) {                \
                int pp = (ks * 4 + hi) ^ (rr & 7);                            \
                af[mf][ks] = *(const bf16x8*)&Ab[s][qm][rr * 64 + pp * 8];    \
            }                                                                 \
        }                                                                     \
    };                                                                        \
    auto LDB = [&](int s, int qn) {                                           \
        _Pragma("unroll") for (int nf = 0; nf < 2; nf++) {                    \
            int rr = wn * 32 + nf * 16 + lo;                                  \
            _Pragma("unroll") for (int ks = 0; ks < 2; ks++) {                \
                int pp = (ks * 4 + hi) ^ (rr & 7);                            \
                bf[nf][ks] = *(const bf16x8*)&Bb[s][qn][rr * 64 + pp * 8];    \
            }                                                                 \
        }                                                                     \
    };                                                                        \
    STA(0, 0, 0); STB(0, 0, 0); STA(0, 1, 0); STB(0, 1, 0);                   \
    STA(1, 1, 1); STB(1, 1, 1);                                               \
    asm volatile("s_waitcnt vmcnt(4)" ::: "memory");                          \
    BARM;                                                                     \
    _Pragma("unroll 1")                                                       \
    for (int i = 0; i < 16; i++) {                                            \
        const int t0 = 2 * i, t1 = 2 * i + 1;                                 \
        const bool more = (i < 15);                                           \
        LDA(0, 0); LDB(0, 0);                                                 \
        STA(1, 0, t1); STB(1, 0, t1);                                         \
        BAR1; MM(0, 0); BAR2;                                                 \
        LDB(0, 1);                                                            \
        BAR1; MM(0, 1); BAR2;                                                 \
        LDA(0, 1); LDB(0, 0);                                                 \
        if (more) STA(0, 0, t0 + 2);                                          \
        BAR1; MM(1, 0); BAR2;                                                 \
        LDB(0, 1);                                                            \
        if (more) STB(0, 0, t0 + 2);                                          \
        BAR1; MM(1, 1);                                                       \
        if (more) { asm volatile("s_waitcnt vmcnt(4)" ::: "memory"); }        \
        else      { asm volatile("s_waitcnt vmcnt(0)" ::: "memory"); }        \
        BAR2;                                                                 \
        LDA(1, 1); LDB(1, 1);                                                 \
        if (more) { STA(0, 1, t0 + 2); STB(0, 1, t0 + 2); }                   \
        BAR1; MM(1, 1); BAR2;                                                 \
        LDB(1, 0);                                                            \
        BAR1; MM(1, 0); BAR2;                                                 \
        LDA(1, 0); LDB(1, 1);                                                 \
        if (more) STA(1, 1, t1 + 2);                                          \
        BAR1; MM(0, 1); BAR2;                                                 \
        LDB(1, 0);                                                            \
        if (more) STB(1, 1, t1 + 2);                                          \
        BAR1; MM(0, 0);                                                       \
        if (more) { asm volatile("s_waitcnt vmcnt(4)" ::: "memory"); }        \
        BAR2;                                                                 \
    }

// -------- Q-proj GEMM, 8-phase: qb8 fp8 = rope(xb*wqt^T)*QSCALE*log2e -------
// grid 256 = (m 32) x (n 8) = exactly 1 block/CU. log2e folded into the fp8
// scale so k_attn's softmax can use native exp2 (v_exp_f32).
__global__ __launch_bounds__(512) void k_gemm_q8(const __bf16* __restrict__ A,
                                                 const __bf16* __restrict__ Bt,
                                                 unsigned char* __restrict__ qb8,
                                                 const float* __restrict__ cosp,
                                                 const float* __restrict__ sinp) {
    const int m0 = (blockIdx.x >> 3) * 256;
    const int n0 = (blockIdx.x & 7) * 256;
    GEMM8_BODY(A, Bt)

    // epilogue: per-quadrant LDS stage -> rope + scale + fp8 -> store.
    __bf16* Cs = (__bf16*)&Ab[0][0][0];            // [128][132]
    const int crow = tid >> 4;                     // 0..31 (+32 per rep)
    const int cch  = tid & 15;                     // 8-col chunk
    const int d0 = cch * 8;
    const float QS2 = QSCALE * LOG2E;
#pragma unroll
    for (int qm = 0; qm < 2; qm++)
#pragma unroll
        for (int qn = 0; qn < 2; qn++) {
#pragma unroll
            for (int mf = 0; mf < 4; mf++)
#pragma unroll
                for (int nf = 0; nf < 2; nf++) {
                    int rl = wm * 64 + mf * 16 + hi * 4;
                    int cl = wn * 32 + nf * 16 + lo;
#pragma unroll
                    for (int r = 0; r < 4; r++)
                        Cs[(rl + r) * 132 + cl] = (__bf16)acc[qm][qn][mf][nf][r];
                }
            __syncthreads();
#pragma unroll
            for (int rep = 0; rep < 4; rep++) {
                int row = rep * 32 + crow;
                int rowg = m0 + qm * 128 + row;
                int colg = n0 + qn * 128 + cch * 8;
                bf16x8 v = *(const bf16x8*)&Cs[row * 132 + cch * 8];
                float f[8];
#pragma unroll
                for (int j = 0; j < 8; j++) f[j] = (float)v[j];
                int s = rowg & (S_LEN - 1);
                f32x4 c0 = *(const f32x4*)&cosp[s * HD + d0];
                f32x4 c1 = *(const f32x4*)&cosp[s * HD + d0 + 4];
                f32x4 s0 = *(const f32x4*)&sinp[s * HD + d0];
                f32x4 s1 = *(const f32x4*)&sinp[s * HD + d0 + 4];
                float cc[8] = {c0[0], c0[1], c0[2], c0[3], c1[0], c1[1], c1[2], c1[3]};
                float ss[8] = {s0[0], s0[1], s0[2], s0[3], s1[0], s1[1], s1[2], s1[3]};
#pragma unroll
                for (int p = 0; p < 4; p++) {
                    float e0 = f[2 * p], e1 = f[2 * p + 1];
                    f[2 * p]     = (e0 * cc[2 * p]     - e1 * ss[2 * p])     * QS2;
                    f[2 * p + 1] = (e1 * cc[2 * p + 1] + e0 * ss[2 * p + 1]) * QS2;
                }
                int u0 = __builtin_amdgcn_cvt_pk_fp8_f32(f[0], f[1], 0, false);
                u0     = __builtin_amdgcn_cvt_pk_fp8_f32(f[2], f[3], u0, true);
                int u1 = __builtin_amdgcn_cvt_pk_fp8_f32(f[4], f[5], 0, false);
                u1     = __builtin_amdgcn_cvt_pk_fp8_f32(f[6], f[7], u1, true);
                u32x2 pk; pk[0] = (unsigned)u0; pk[1] = (unsigned)u1;
                *(u32x2*)&qb8[(size_t)rowg * HID + colg] = pk;
            }
            __syncthreads();
        }
}

// -------- O-proj GEMM, 8-phase (validated R13): out[8192][2048] f32 ---------
__global__ __launch_bounds__(512) void k_gemm_o8(const __bf16* __restrict__ A,
                                                 const __bf16* __restrict__ Bt,
                                                 float* __restrict__ Cp) {
    const int m0 = (blockIdx.x >> 3) * 256;
    const int n0 = (blockIdx.x & 7) * 256;
    GEMM8_BODY(A, Bt)

#pragma unroll
    for (int qm = 0; qm < 2; qm++)
#pragma unroll
        for (int qn = 0; qn < 2; qn++)
#pragma unroll
            for (int mf = 0; mf < 4; mf++)
#pragma unroll
                for (int nf = 0; nf < 2; nf++) {
                    int row = m0 + qm * 128 + wm * 64 + mf * 16 + hi * 4;
                    int col = n0 + qn * 128 + wn * 32 + nf * 16 + lo;
#pragma unroll
                    for (int r = 0; r < 4; r++)
                        Cp[(size_t)(row + r) * HID + col] = acc[qm][qn][mf][nf][r];
                }
}

// ---- KV-proj GEMM (m97 structure): C[8192][1024] = xb * wkvt^T -------------
// grid (64, 8): n0 = 2048 + by*128. cols [2048,2560) -> k rope+fp8 -> kb8;
// [2560,3072) -> v transposed -> vtb. NOTE: K gets NO log2e (Q carries it).
__global__ __launch_bounds__(256) void k_gemm_kv(const __bf16* __restrict__ A,
                                                 const __bf16* __restrict__ Bt,
                                                 unsigned char* __restrict__ kb8,
                                                 __bf16* __restrict__ vtb,
                                                 const float* __restrict__ cosp,
                                                 const float* __restrict__ sinp) {
    __shared__ __align__(16) char smem[33792];
    __bf16* As = (__bf16*)smem;
    __bf16* Bs = (__bf16*)(smem + 16384);
    const int tid = threadIdx.x, lane = tid & 63, wave = tid >> 6;
    const int wm = wave >> 1, wn = wave & 1;
    const int m0 = blockIdx.x * 128;
    const int n0 = 2048 + blockIdx.y * 128;
    const int lo = lane & 15, hi = lane >> 4;
    f32x4 acc[4][4] = {};

    const int srow = wave * 8 + (lane >> 3);
    const int sp   = lane & 7;

    for (int kt = 0; kt < HID; kt += 64) {
#pragma unroll
        for (int r = 0; r < 4; r++) {
            int row = r * 32 + srow;
            int c = sp ^ (row & 7);
            gld16(A + (size_t)(m0 + row) * HID + kt + c * 8, &As[(r * 32 + wave * 8) * 64]);
        }
#pragma unroll
        for (int r = 0; r < 4; r++) {
            int row = r * 32 + srow;
            int c = sp ^ (row & 7);
            gld16(Bt + (size_t)(n0 + row) * HID + kt + c * 8, &Bs[(r * 32 + wave * 8) * 64]);
        }
        __syncthreads();
#pragma unroll
        for (int ks = 0; ks < 2; ks++) {
            bf16x8 af[4], bfr[4];
#pragma unroll
            for (int mt = 0; mt < 4; mt++) {
                int row = wm * 64 + mt * 16 + lo;
                int pp = (ks * 4 + hi) ^ (row & 7);
                af[mt] = *(const bf16x8*)&As[row * 64 + pp * 8];
            }
#pragma unroll
            for (int nt = 0; nt < 4; nt++) {
                int row = wn * 64 + nt * 16 + lo;
                int pp = (ks * 4 + hi) ^ (row & 7);
                bfr[nt] = *(const bf16x8*)&Bs[row * 64 + pp * 8];
            }
#pragma unroll
            for (int mt = 0; mt < 4; mt++)
#pragma unroll
                for (int nt = 0; nt < 4; nt++)
                    acc[mt][nt] = __builtin_amdgcn_mfma_f32_16x16x32_bf16(
                        af[mt], bfr[nt], acc[mt][nt], 0, 0, 0);
        }
        __syncthreads();
    }

    if (n0 < 2560) {
        __bf16* Cs = (__bf16*)smem;                 // [128][132]
#pragma unroll
        for (int mt = 0; mt < 4; mt++)
#pragma unroll
            for (int nt = 0; nt < 4; nt++) {
                int rl = wm * 64 + mt * 16 + hi * 4;
                int cl = wn * 64 + nt * 16 + lo;
#pragma unroll
                for (int r = 0; r < 4; r++)
                    Cs[(rl + r) * 132 + cl] = (__bf16)acc[mt][nt][r];
            }
        __syncthreads();

        const int crow = tid >> 4;
        const int cch  = tid & 15;
        const int colg = n0 + cch * 8;
        const int d0 = colg & (HD - 1);
#pragma unroll
        for (int rep = 0; rep < 8; rep++) {
            int row = rep * 16 + crow;
            int rowg = m0 + row;
            bf16x8 v = *(const bf16x8*)&Cs[row * 132 + cch * 8];
            float f[8];
#pragma unroll
            for (int j = 0; j < 8; j++) f[j] = (float)v[j];
            int s = rowg & (S_LEN - 1);
            f32x4 c0 = *(const f32x4*)&cosp[s * HD + d0];
            f32x4 c1 = *(const f32x4*)&cosp[s * HD + d0 + 4];
            f32x4 s0 = *(const f32x4*)&sinp[s * HD + d0];
            f32x4 s1 = *(const f32x4*)&sinp[s * HD + d0 + 4];
            float cc[8] = {c0[0], c0[1], c0[2], c0[3], c1[0], c1[1], c1[2], c1[3]};
            float ss[8] = {s0[0], s0[1], s0[2], s0[3], s1[0], s1[1], s1[2], s1[3]};
#pragma unroll
            for (int p = 0; p < 4; p++) {
                float e0 = f[2 * p], e1 = f[2 * p + 1];
                f[2 * p]     = e0 * cc[2 * p]     - e1 * ss[2 * p];
                f[2 * p + 1] = e1 * cc[2 * p + 1] + e0 * ss[2 * p + 1];
            }
            int u0 = __builtin_amdgcn_cvt_pk_fp8_f32(f[0], f[1], 0, false);
            u0     = __builtin_amdgcn_cvt_pk_fp8_f32(f[2], f[3], u0, true);
            int u1 = __builtin_amdgcn_cvt_pk_fp8_f32(f[4], f[5], 0, false);
            u1     = __builtin_amdgcn_cvt_pk_fp8_f32(f[6], f[7], u1, true);
            u32x2 pk; pk[0] = (unsigned)u0; pk[1] = (unsigned)u1;
            *(u32x2*)&kb8[(size_t)rowg * 512 + (colg - 2048)] = pk;
        }
    } else {
        __bf16* CsT = (__bf16*)smem;                // [128 cols][132 rows pad]
#pragma unroll
        for (int mt = 0; mt < 4; mt++)
#pragma unroll
            for (int nt = 0; nt < 4; nt++) {
                int cl = wn * 64 + nt * 16 + lo;
                int mrow = wm * 64 + mt * 16 + hi * 4;
                bf16x4 w;
#pragma unroll
                for (int r = 0; r < 4; r++) w[r] = (__bf16)acc[mt][nt][r];
                *(bf16x4*)&CsT[cl * 132 + mrow] = w;
            }
        __syncthreads();

        const int kvh = (n0 - 2560) >> 7;
        const int bb = m0 >> 11;
        const int s0 = m0 & (S_LEN - 1);
        __bf16* dst = vtb + (size_t)(bb * NKV + kvh) * HD * S_LEN;
        const int dloc = tid >> 4;
        const int sch  = tid & 15;
#pragma unroll
        for (int rep = 0; rep < 8; rep++) {
            int d = rep * 16 + dloc;
            bf16x8 v = *(const bf16x8*)&CsT[d * 132 + sch * 8];
            *(bf16x8*)&dst[(size_t)d * S_LEN + s0 + sch * 8] = v;
        }
    }
}

// ----------------------------- flash attention ------------------------------
// KVBLK=128; QK^T fp8 (Q pre-scaled by QSCALE*log2e -> native exp2 softmax).
// PV bf16 in two 64-kv halves via wave-private Ps. R17 change: removed ALL
// manual lgkmcnt(0)/sched_barrier serialization around the Ps round-trip —
// writes/reads are plain aliasing LDS accesses (compiler preserves order and
// inserts minimal counted waits) and per-wave LDS ops execute in order, so
// the manual full drains only blocked MFMA/VALU overlap between halves.
// LDS: Ks8 2x16K + Vs 2x32K + Ps 32K = 128 KB. Grid 256 = 1/CU.
__global__ __launch_bounds__(512) void k_attn(const unsigned char* __restrict__ qb8,
                                              const unsigned char* __restrict__ kb8,
                                              const __bf16* __restrict__ vtb,
                                              __bf16* __restrict__ ob) {
    __shared__ char   Ks8[2][128 * 128];  // [kv][128B fp8 d], 8-chunk XOR swz
    __shared__ __bf16 Vs[2][128 * 128];   // [d][kv 128] bf16, 16-chunk XOR swz
    __shared__ __bf16 Ps[8][2048];        // wave-private: 2 subtiles x 16x64
    const int tid = threadIdx.x, lane = tid & 63, wave = tid >> 6;
    const int pair = blockIdx.x, h = blockIdx.y, b = blockIdx.z;
    const int kvh = h >> 2;
    const int lo = lane & 15, hi = lane >> 4;
    char* PsW = (char*)&Ps[wave][0];

    const unsigned char* kbb = kb8 + (size_t)b * S_LEN * 512 + kvh * HD;
    const __bf16* vbb = vtb + (size_t)(b * NKV + kvh) * HD * S_LEN;

    const int krow_s = tid >> 3;                // 0..63 (+64 per round)
    const int kp_s   = tid & 7;
    const int vrow_s = tid >> 4;                // 0..31 (+32 per round)
    const int vp_s   = tid & 15;

    auto STAGE_K = [&](int buf, int t) {        // 16 KB: 2 gld16 rounds
#pragma unroll
        for (int r = 0; r < 2; r++) {
            int row = r * 64 + krow_s;
            int c = kp_s ^ (row & 7);
            gld16(kbb + (size_t)(t * 128 + row) * 512 + c * 16,
                  &Ks8[buf][(r * 64 + wave * 8) * 128]);
        }
    };
    auto STAGE_V = [&](int buf, int t) {        // 32 KB: 4 gld16 rounds
#pragma unroll
        for (int r = 0; r < 4; r++) {
            int row = r * 32 + vrow_s;          // d-row
            int c = vp_s ^ (row & 15);
            gld16(vbb + (size_t)row * S_LEN + t * 128 + c * 8,
                  &Vs[buf][(r * 32 + wave * 4) * 128]);
        }
    };

    // online softmax over 32 in-lane scores (exp2 domain; T13 defer thr=8)
    auto SM = [&](f32x4 (&sc)[8], float& Mr, float& Lr, f32x4 (&o)[8]) {
        float mloc = sc[0][0];
#pragma unroll
        for (int nt = 0; nt < 8; nt++)
#pragma unroll
            for (int r = 0; r < 4; r++) mloc = fmaxf(mloc, sc[nt][r]);
        mloc = fmaxf(mloc, __shfl_xor(mloc, 16, 64));
        mloc = fmaxf(mloc, __shfl_xor(mloc, 32, 64));
        float mn = (mloc <= Mr + 8.f) ? Mr : mloc;
        float sum = 0.f;
#pragma unroll
        for (int nt = 0; nt < 8; nt++)
#pragma unroll
            for (int r = 0; r < 4; r++) {
                float e = EXP2F(sc[nt][r] - mn);
                sc[nt][r] = e;
                sum += e;
            }
        sum += __shfl_xor(sum, 16, 64);
        sum += __shfl_xor(sum, 32, 64);
        if (mn != Mr) {
            float scl = EXP2F(Mr - mn);
            Lr = Lr * scl + sum;
            Mr = mn;
#pragma unroll
            for (int dt = 0; dt < 8; dt++) o[dt] *= scl;
        } else {
            Lr += sum;
        }
    };

#pragma unroll 1
    for (int pi = 0; pi < 2; pi++) {
        const int qt = pi ? (NQT2 - 1 - pair) : pair;  // 256-row q-tile index
        const int nkv = 2 * qt + 2;                    // kv tiles of 128 rows
        const int qbase = qt * 256 + wave * 32;        // this wave's 32 q-rows

        const unsigned char* qp0 = qb8 + (size_t)(b * S_LEN + qbase + lo) * HID + h * HD;
        const unsigned char* qp1 = qp0 + (size_t)16 * HID;
        long qa0[4], qa1[4];
#pragma unroll
        for (int kf = 0; kf < 4; kf++) {
            qa0[kf] = *(const long*)(qp0 + kf * 32 + hi * 8);
            qa1[kf] = *(const long*)(qp1 + kf * 32 + hi * 8);
        }

        f32x4 o0[8] = {}, o1[8] = {};
        float Mr0 = -3e30f, Lr0 = 0.f, Mr1 = -3e30f, Lr1 = 0.f;

        int cur = 0;
        if (pi == 1) __syncthreads();
        STAGE_K(0, 0);
        STAGE_V(0, 0);
        __syncthreads();

#pragma unroll 1
        for (int t = 0; t < nkv; t++) {
            if (t < nkv - 1) { STAGE_K(cur ^ 1, t + 1); STAGE_V(cur ^ 1, t + 1); }

            // S^T = K Q^T (fp8), 8 nt-rows of 16 kv, both subtiles share K
            f32x4 sc0[8], sc1[8];
            __builtin_amdgcn_s_setprio(1);
#pragma unroll
            for (int nt = 0; nt < 8; nt++) {
                f32x4 a = {0.f, 0.f, 0.f, 0.f}, bb = {0.f, 0.f, 0.f, 0.f};
#pragma unroll
                for (int kf = 0; kf < 4; kf++) {
                    int row = nt * 16 + lo;
                    int lch = 2 * kf + (hi >> 1);
                    long kf8 = *(const long*)&Ks8[cur][row * 128 +
                                ((lch ^ (row & 7)) * 16) + (hi & 1) * 8];
                    a  = __builtin_amdgcn_mfma_f32_16x16x32_fp8_fp8(kf8, qa0[kf], a, 0, 0, 0);
                    bb = __builtin_amdgcn_mfma_f32_16x16x32_fp8_fp8(kf8, qa1[kf], bb, 0, 0, 0);
                }
                sc0[nt] = a; sc1[nt] = bb;
            }
            __builtin_amdgcn_s_setprio(0);

            // causal mask (wave-uniform guard per subtile)
            if (t * 128 + 127 > qbase) {
                int qg = qbase + lo;
#pragma unroll
                for (int nt = 0; nt < 8; nt++)
#pragma unroll
                    for (int r = 0; r < 4; r++) {
                        int kg = t * 128 + nt * 16 + hi * 4 + r;
                        if (kg > qg) sc0[nt][r] = -1e30f;
                    }
            }
            if (t * 128 + 127 > qbase + 16) {
                int qg = qbase + 16 + lo;
#pragma unroll
                for (int nt = 0; nt < 8; nt++)
#pragma unroll
                    for (int r = 0; r < 4; r++) {
                        int kg = t * 128 + nt * 16 + hi * 4 + r;
                        if (kg > qg) sc1[nt][r] = -1e30f;
                    }
            }

            SM(sc0, Mr0, Lr0, o0);
            SM(sc1, Mr1, Lr1, o1);

            // PV in two 64-kv halves; Ps writes/reads are plain aliasing LDS
            // ops: compiler preserves order + inserts counted lgkm waits, and
            // per-wave LDS in-order execution covers the WAR on Ps reuse.
#pragma unroll
            for (int hh = 0; hh < 2; hh++) {
#pragma unroll
                for (int ntl = 0; ntl < 4; ntl++) {
                    int nt = hh * 4 + ntl;
                    bf16x4 p0, p1;
#pragma unroll
                    for (int r = 0; r < 4; r++) { p0[r] = (__bf16)sc0[nt][r]; p1[r] = (__bf16)sc1[nt][r]; }
                    int off = lo * 128 + ((ntl * 32 + hi * 8) ^ ((lo & 7) << 4));
                    *(bf16x4*)(PsW + off)        = p0;
                    *(bf16x4*)(PsW + 2048 + off) = p1;
                }
                bf16x8 pf0[2], pf1[2];
#pragma unroll
                for (int c = 0; c < 2; c++) {
                    int off = lo * 128 + ((c * 64 + hi * 16) ^ ((lo & 7) << 4));
                    pf0[c] = *(const bf16x8*)(PsW + off);
                    pf1[c] = *(const bf16x8*)(PsW + 2048 + off);
                }
                __builtin_amdgcn_s_setprio(1);
#pragma unroll
                for (int dt = 0; dt < 8; dt++) {
                    int rowd = dt * 16 + lo;
#pragma unroll
                    for (int c = 0; c < 2; c++) {
                        int gch = hh * 8 + c * 4 + hi;   // chunk in 16-wide row
                        bf16x8 vv = *(const bf16x8*)&Vs[cur][rowd * 128 +
                                     (gch ^ (rowd & 15)) * 8];
                        o0[dt] = __builtin_amdgcn_mfma_f32_16x16x32_bf16(vv, pf0[c], o0[dt], 0, 0, 0);
                        o1[dt] = __builtin_amdgcn_mfma_f32_16x16x32_bf16(vv, pf1[c], o1[dt], 0, 0, 0);
                    }
                }
                __builtin_amdgcn_s_setprio(0);
            }
            __syncthreads();  // drains prefetch; protects both bufs before reuse
            cur ^= 1;
        }

        // epilogue per subtile: O^T -> Ps -> coalesced bf16x8 stores
        const int qe = lane >> 2, c4 = lane & 3;
#pragma unroll
        for (int sub = 0; sub < 2; sub++) {
            float rl = 1.0f / (sub ? Lr1 : Lr0);
            char* Pp = PsW + sub * 2048;
#pragma unroll
            for (int h2 = 0; h2 < 2; h2++) {
#pragma unroll
                for (int dt4 = 0; dt4 < 4; dt4++) {
                    f32x4 ov = sub ? o1[h2 * 4 + dt4] : o0[h2 * 4 + dt4];
                    bf16x4 w;
#pragma unroll
                    for (int r = 0; r < 4; r++) w[r] = (__bf16)(ov[r] * rl);
                    *(bf16x4*)(Pp + lo * 128 + ((dt4 * 32 + hi * 8) ^ ((lo & 7) << 4))) = w;
                }
#pragma unroll
                for (int s2 = 0; s2 < 2; s2++) {
                    int ch = c4 + s2 * 4;
                    bf16x8 v = *(const bf16x8*)(Pp + qe * 128 + ((ch * 16) ^ ((qe & 7) << 4)));
                    int qg = qbase + sub * 16 + qe;
                    int col = h * HD + h2 * 64 + ch * 8;
                    *(bf16x8*)&ob[(size_t)(b * S_LEN + qg) * HID + col] = v;
                }
            }
        }
    }
}

// ----------------------------------- host -----------------------------------
extern "C" void kernel_launch(void* const* d_in, const int* in_sizes, int n_in,
                              void* d_out, int out_size, void* d_ws, size_t ws_size,
                              hipStream_t stream) {
    (void)in_sizes; (void)n_in; (void)out_size; (void)ws_size;
    const float* x    = (const float*)d_in[0];
    const float* cosp = (const float*)d_in[1];
    const float* sinp = (const float*)d_in[2];
    const float* Wq   = (const float*)d_in[3];
    const float* Wk   = (const float*)d_in[4];
    const float* Wv   = (const float*)d_in[5];
    const float* Wo   = (const float*)d_in[6];
    float* out = (float*)d_out;

    char* ws = (char*)d_ws;
    __bf16*        xb   = (__bf16*)(ws);               // [8192][2048] bf16  32 MB
    __bf16*        wqt  = (__bf16*)(ws + 33554432);    // [2048][2048]        8 MB
    __bf16*        wkvt = (__bf16*)(ws + 41943040);    // [1024][2048] (k|v)  4 MB (contig with wqt)
    __bf16*        wot  = (__bf16*)(ws + 46137344);    // [2048][2048]        8 MB
    unsigned char* qb8  = (unsigned char*)(ws + 54525952);  // [8192][2048] fp8 16 MB
    unsigned char* kb8  = (unsigned char*)(ws + 71303168);  // [8192][512]  fp8  4 MB
    __bf16*        vtb  = (__bf16*)(ws + 75497472);    // [16][128][2048] bf16 8 MB
    __bf16*        aob  = xb;                          // reuse xb after QKV GEMMs

    k_conv_x<<<MTOT * HID / 8 / 256, 256, 0, stream>>>(x, xb);
    { dim3 g(32, 32, 4);
      k_transpose_all<<<g, 256, 0, stream>>>(Wq, Wk, Wv, Wo, wqt, wkvt, wot); }

    k_gemm_q8<<<256, 512, 0, stream>>>(xb, wqt, qb8, cosp, sinp);
    { dim3 g(64, 8); k_gemm_kv<<<g, 256, 0, stream>>>(xb, wqt, kb8, vtb, cosp, sinp); }

    { dim3 g(NQT2 / 2, 16, BATCH); k_attn<<<g, 512, 0, stream>>>(qb8, kb8, vtb, aob); }

    k_gemm_o8<<<256, 512, 0, stream>>>(aob, wot, out);
}